// Round 1
// baseline (715.550 us; speedup 1.0000x reference)
//
#include <hip/hip_runtime.h>

// ---------- helpers ----------
typedef __attribute__((ext_vector_type(8))) short short8;   // 8 x bf16 fragment (4 VGPRs)
typedef __attribute__((ext_vector_type(4))) float floatx4;  // MFMA accumulator

static __device__ __forceinline__ unsigned short f2bf(float f) {
  unsigned int u = __builtin_bit_cast(unsigned int, f);
  u += 0x7FFFu + ((u >> 16) & 1u);   // RNE (finite inputs only)
  return (unsigned short)(u >> 16);
}
static __device__ __forceinline__ float bf2f(unsigned short s) {
  unsigned int u = ((unsigned int)s) << 16;
  return __builtin_bit_cast(float, u);
}

#define N_NODES_C 100000
#define E_EDGES_C 1600000

// ---------- CSR build ----------
__global__ void deg_kernel(const int* __restrict__ dst, int* __restrict__ deg, int E) {
  int i = blockIdx.x * blockDim.x + threadIdx.x;
  if (i < E) atomicAdd(&deg[dst[i]], 1);
}

// scan phase 1: per-block (1024 elems) exclusive scan, block sums out
__global__ __launch_bounds__(256) void scan1(const int* __restrict__ deg,
                                             int* __restrict__ rs,
                                             int* __restrict__ bsums, int n) {
  __shared__ int s[256];
  int t = threadIdx.x;
  int base = blockIdx.x * 1024 + t * 4;
  int v[4];
#pragma unroll
  for (int j = 0; j < 4; j++) v[j] = (base + j < n) ? deg[base + j] : 0;
  int tsum = v[0] + v[1] + v[2] + v[3];
  s[t] = tsum;
  __syncthreads();
  for (int off = 1; off < 256; off <<= 1) {
    int x = (t >= off) ? s[t - off] : 0;
    __syncthreads();
    s[t] += x;
    __syncthreads();
  }
  int toff = s[t] - tsum;   // exclusive offset of this thread within block
  if (t == 255) bsums[blockIdx.x] = s[255];
  int run = toff;
#pragma unroll
  for (int j = 0; j < 4; j++) {
    if (base + j < n) rs[base + j] = run;
    run += v[j];
  }
}

// scan phase 2: serial scan of block sums (98 entries), writes rs[n]=total
__global__ void scan2(int* __restrict__ bsums, int* __restrict__ boff, int nb,
                      int* __restrict__ rs_total) {
  if (threadIdx.x == 0 && blockIdx.x == 0) {
    int run = 0;
    for (int b = 0; b < nb; b++) { boff[b] = run; run += bsums[b]; }
    rs_total[0] = run;
  }
}

// scan phase 3: add block offsets; also init cursor
__global__ void scan3(int* __restrict__ rs, const int* __restrict__ boff,
                      int* __restrict__ cursor, int n) {
  int i = blockIdx.x * blockDim.x + threadIdx.x;
  if (i < n) {
    int v = rs[i] + boff[i >> 10];
    rs[i] = v;
    cursor[i] = v;
  }
}

__global__ void scatter_kernel(const int* __restrict__ src, const int* __restrict__ dst,
                               int* __restrict__ cursor, int* __restrict__ csr_src, int E) {
  int i = blockIdx.x * blockDim.x + threadIdx.x;
  if (i < E) {
    int pos = atomicAdd(&cursor[dst[i]], 1);
    csr_src[pos] = src[i];
  }
}

// ---------- weight / input conversion ----------
// W1t[n][k] (256x256): k<128 -> W1l[k][n], else W1r[k-128][n]
__global__ void convw1(const float* __restrict__ W1l, const float* __restrict__ W1r,
                       unsigned short* __restrict__ W1t) {
  int i = blockIdx.x * blockDim.x + threadIdx.x;
  if (i < 256 * 256) {
    int n = i >> 8, k = i & 255;
    float v = (k < 128) ? W1l[k * 256 + n] : W1r[(k - 128) * 256 + n];
    W1t[i] = f2bf(v);
  }
}
// W2t[n][k] (128x256): n<64 -> W2l[k][n], else W2r[k][n-64]
__global__ void convw2(const float* __restrict__ W2l, const float* __restrict__ W2r,
                       unsigned short* __restrict__ W2t) {
  int i = blockIdx.x * blockDim.x + threadIdx.x;
  if (i < 128 * 256) {
    int n = i >> 8, k = i & 255;
    float v = (n < 64) ? W2l[k * 64 + n] : W2r[k * 64 + (n - 64)];
    W2t[i] = f2bf(v);
  }
}
// x (fp32, [N][128]) -> right half of A1 (bf16, [N][256] cols 128..255)
__global__ void convx(const float* __restrict__ x, unsigned short* __restrict__ A1, int n_nodes) {
  int i = blockIdx.x * blockDim.x + threadIdx.x;
  if (i < n_nodes * 32) {
    int node = i >> 5, c4 = (i & 31) * 4;
    float4 v = *reinterpret_cast<const float4*>(x + (size_t)node * 128 + c4);
    unsigned short r[4] = { f2bf(v.x), f2bf(v.y), f2bf(v.z), f2bf(v.w) };
    *reinterpret_cast<uint2*>(A1 + (size_t)node * 256 + 128 + c4) =
        *reinterpret_cast<uint2*>(r);
  }
}

// ---------- layer-1 aggregation: one wave per node, 2 channels/lane ----------
__global__ __launch_bounds__(256) void agg1_kernel(const float* __restrict__ x,
                                                   const int* __restrict__ csr_src,
                                                   const int* __restrict__ rs,
                                                   unsigned short* __restrict__ A1,
                                                   int n_nodes) {
  int w = blockIdx.x * 4 + (threadIdx.x >> 6);
  if (w >= n_nodes) return;
  int lane = threadIdx.x & 63;
  int e0 = rs[w], e1 = rs[w + 1];
  float ax = 0.f, ay = 0.f;
  const float* xb = x + 2 * lane;
  for (int e = e0; e < e1; ++e) {
    int s = csr_src[e];
    float2 v = *reinterpret_cast<const float2*>(xb + (size_t)s * 128);
    ax += v.x; ay += v.y;
  }
  int d = e1 - e0; if (d < 1) d = 1;
  float scale = 1.0f / (float)d;
  unsigned int packed = (unsigned int)f2bf(ax * scale) |
                        ((unsigned int)f2bf(ay * scale) << 16);
  *reinterpret_cast<unsigned int*>(A1 + (size_t)w * 256 + 2 * lane) = packed;
}

// ---------- bf16 MFMA GEMM: C[M][N] = A[M][K] * Bt[N][K]^T, optional bias+relu ----------
#define BM 128
#define BN 128
#define BK 64
template <bool RELU_BIAS>
__global__ __launch_bounds__(256) void gemm_bf16(const unsigned short* __restrict__ A,
                                                 const unsigned short* __restrict__ Bt,
                                                 const float* __restrict__ bias,
                                                 unsigned short* __restrict__ C,
                                                 int M, int N, int K) {
  __shared__ unsigned short As[BM][BK + 8];  // +8 bf16 pad -> 144B row stride
  __shared__ unsigned short Bs[BN][BK + 8];
  const int tid = threadIdx.x;
  const int lane = tid & 63;
  const int wave = tid >> 6;
  const int m0 = blockIdx.x * BM;
  const int n0 = blockIdx.y * BN;
  const int wr = (wave >> 1) * 64;  // wave's row offset in block tile
  const int wc = (wave & 1) * 64;   // wave's col offset
  const int fm = lane & 15;
  const int fq = lane >> 4;

  floatx4 acc[4][4] = {};

  for (int k0 = 0; k0 < K; k0 += BK) {
    // stage A tile: 128 rows x 64 bf16 = 1024 16B-chunks
    for (int c = tid; c < BM * BK / 8; c += 256) {
      int row = c >> 3;
      int col = (c & 7) * 8;
      int gr = m0 + row; if (gr >= M) gr = M - 1;
      int4 v = *reinterpret_cast<const int4*>(A + (size_t)gr * K + k0 + col);
      *reinterpret_cast<int4*>(&As[row][col]) = v;
    }
    // stage B tile (Bt rows are N-dim)
    for (int c = tid; c < BN * BK / 8; c += 256) {
      int row = c >> 3;
      int col = (c & 7) * 8;
      int4 v = *reinterpret_cast<const int4*>(Bt + (size_t)(n0 + row) * K + k0 + col);
      *reinterpret_cast<int4*>(&Bs[row][col]) = v;
    }
    __syncthreads();
#pragma unroll
    for (int kk = 0; kk < BK; kk += 32) {
      short8 af[4], bfr[4];
#pragma unroll
      for (int i = 0; i < 4; i++)
        af[i] = *reinterpret_cast<const short8*>(&As[wr + i * 16 + fm][kk + fq * 8]);
#pragma unroll
      for (int i = 0; i < 4; i++)
        bfr[i] = *reinterpret_cast<const short8*>(&Bs[wc + i * 16 + fm][kk + fq * 8]);
#pragma unroll
      for (int mi = 0; mi < 4; mi++)
#pragma unroll
        for (int ni = 0; ni < 4; ni++)
          acc[mi][ni] = __builtin_amdgcn_mfma_f32_16x16x32_bf16(af[mi], bfr[ni],
                                                                acc[mi][ni], 0, 0, 0);
    }
    __syncthreads();
  }

  // epilogue: D row = fq*4 + r, col = fm (within each 16x16 tile)
#pragma unroll
  for (int mi = 0; mi < 4; mi++) {
#pragma unroll
    for (int ni = 0; ni < 4; ni++) {
#pragma unroll
      for (int r = 0; r < 4; r++) {
        int grow = m0 + wr + mi * 16 + fq * 4 + r;
        int gcol = n0 + wc + ni * 16 + fm;
        if (grow < M) {
          float v = acc[mi][ni][r];
          if (RELU_BIAS) {
            v += bias[gcol];
            v = v > 0.f ? v : 0.f;
          }
          C[(size_t)grow * N + gcol] = f2bf(v);
        }
      }
    }
  }
}

// ---------- layer-2 aggregation + epilogue: one wave per node, 1 channel/lane ----------
__global__ __launch_bounds__(256) void agg2_final(const unsigned short* __restrict__ zr,
                                                  const int* __restrict__ csr_src,
                                                  const int* __restrict__ rs,
                                                  const float* __restrict__ b2,
                                                  float* __restrict__ out, int n_nodes) {
  int w = blockIdx.x * 4 + (threadIdx.x >> 6);
  if (w >= n_nodes) return;
  int lane = threadIdx.x & 63;
  int e0 = rs[w], e1 = rs[w + 1];
  float acc = 0.f;
  for (int e = e0; e < e1; ++e) {
    int s = csr_src[e];
    acc += bf2f(zr[(size_t)s * 128 + lane]);   // z part: cols 0..63
  }
  int d = e1 - e0; if (d < 1) d = 1;
  float r = bf2f(zr[(size_t)w * 128 + 64 + lane]);  // r part: cols 64..127
  float v = acc / (float)d + r + b2[lane];
  out[(size_t)w * 64 + lane] = 1.0f / (1.0f + __expf(-v));
}

// ---------- launch ----------
extern "C" void kernel_launch(void* const* d_in, const int* in_sizes, int n_in,
                              void* d_out, int out_size, void* d_ws, size_t ws_size,
                              hipStream_t stream) {
  const float* x   = (const float*)d_in[0];
  const int*   ei  = (const int*)d_in[1];
  const float* W1l = (const float*)d_in[2];
  const float* W1r = (const float*)d_in[3];
  const float* b1  = (const float*)d_in[4];
  const float* W2l = (const float*)d_in[5];
  const float* W2r = (const float*)d_in[6];
  const float* b2  = (const float*)d_in[7];
  float* out = (float*)d_out;

  const int N = in_sizes[0] / 128;     // 100000
  const int E = in_sizes[1] / 2;       // 1600000
  const int* src = ei;
  const int* dst = ei + E;

  // workspace layout (512B aligned blocks)
  char* wsb = (char*)d_ws;
  size_t off = 0;
  auto alloc = [&](size_t bytes) -> void* {
    void* p = wsb + off;
    off += (bytes + 511) & ~(size_t)511;
    return p;
  };
  int* deg      = (int*)alloc((size_t)N * 4);
  int* rs       = (int*)alloc((size_t)(N + 1) * 4);
  int* cursor   = (int*)alloc((size_t)N * 4);
  int* bsums    = (int*)alloc(512);
  int* boff     = (int*)alloc(512);
  int* csr_src  = (int*)alloc((size_t)E * 4);
  unsigned short* W1t = (unsigned short*)alloc(256 * 256 * 2);
  unsigned short* W2t = (unsigned short*)alloc(128 * 256 * 2);
  unsigned short* A1  = (unsigned short*)alloc((size_t)N * 256 * 2);
  unsigned short* h   = (unsigned short*)alloc((size_t)N * 256 * 2);
  unsigned short* zr  = (unsigned short*)alloc((size_t)N * 128 * 2);
  (void)ws_size; (void)n_in; (void)out_size;

  const int NB = (N + 1023) / 1024;   // 98 scan blocks

  hipMemsetAsync(deg, 0, (size_t)N * 4, stream);
  deg_kernel<<<(E + 255) / 256, 256, 0, stream>>>(dst, deg, E);
  scan1<<<NB, 256, 0, stream>>>(deg, rs, bsums, N);
  scan2<<<1, 64, 0, stream>>>(bsums, boff, NB, rs + N);
  scan3<<<(N + 255) / 256, 256, 0, stream>>>(rs, boff, cursor, N);
  scatter_kernel<<<(E + 255) / 256, 256, 0, stream>>>(src, dst, cursor, csr_src, E);

  convw1<<<256, 256, 0, stream>>>(W1l, W1r, W1t);
  convw2<<<128, 256, 0, stream>>>(W2l, W2r, W2t);
  convx<<<(N * 32 + 255) / 256, 256, 0, stream>>>(x, A1, N);

  agg1_kernel<<<(N + 3) / 4, 256, 0, stream>>>(x, csr_src, rs, A1, N);

  dim3 g1((N + BM - 1) / BM, 256 / BN);
  gemm_bf16<true><<<g1, 256, 0, stream>>>(A1, W1t, b1, h, N, 256, 256);

  dim3 g2((N + BM - 1) / BM, 128 / BN);
  gemm_bf16<false><<<g2, 256, 0, stream>>>(h, W2t, nullptr, zr, N, 128, 256);

  agg2_final<<<(N + 3) / 4, 256, 0, stream>>>(zr, csr_src, rs, b2, out, N);
}

// Round 2
// 541.580 us; speedup vs baseline: 1.3212x; 1.3212x over previous
//
#include <hip/hip_runtime.h>

// ---------- helpers ----------
typedef __attribute__((ext_vector_type(8))) short short8;   // 8 x bf16 fragment (4 VGPRs)
typedef __attribute__((ext_vector_type(4))) float floatx4;  // MFMA accumulator

static __device__ __forceinline__ unsigned short f2bf(float f) {
  unsigned int u = __builtin_bit_cast(unsigned int, f);
  u += 0x7FFFu + ((u >> 16) & 1u);   // RNE (finite inputs only)
  return (unsigned short)(u >> 16);
}
static __device__ __forceinline__ float bf2f(unsigned short s) {
  unsigned int u = ((unsigned int)s) << 16;
  return __builtin_bit_cast(float, u);
}

// ---------- CSR build ----------
__global__ void deg_kernel(const int* __restrict__ dst, int* __restrict__ deg, int E) {
  int i = blockIdx.x * blockDim.x + threadIdx.x;
  if (i < E) atomicAdd(&deg[dst[i]], 1);
}

// scan phase 1: per-block (1024 elems) exclusive scan, block sums out
__global__ __launch_bounds__(256) void scan1(const int* __restrict__ deg,
                                             int* __restrict__ rs,
                                             int* __restrict__ bsums, int n) {
  __shared__ int s[256];
  int t = threadIdx.x;
  int base = blockIdx.x * 1024 + t * 4;
  int v[4];
#pragma unroll
  for (int j = 0; j < 4; j++) v[j] = (base + j < n) ? deg[base + j] : 0;
  int tsum = v[0] + v[1] + v[2] + v[3];
  s[t] = tsum;
  __syncthreads();
  for (int off = 1; off < 256; off <<= 1) {
    int x = (t >= off) ? s[t - off] : 0;
    __syncthreads();
    s[t] += x;
    __syncthreads();
  }
  int toff = s[t] - tsum;   // exclusive offset of this thread within block
  if (t == 255) bsums[blockIdx.x] = s[255];
  int run = toff;
#pragma unroll
  for (int j = 0; j < 4; j++) {
    if (base + j < n) rs[base + j] = run;
    run += v[j];
  }
}

// scan phase 2: serial scan of block sums (98 entries), writes rs[n]=total
__global__ void scan2(int* __restrict__ bsums, int* __restrict__ boff, int nb,
                      int* __restrict__ rs_total) {
  if (threadIdx.x == 0 && blockIdx.x == 0) {
    int run = 0;
    for (int b = 0; b < nb; b++) { boff[b] = run; run += bsums[b]; }
    rs_total[0] = run;
  }
}

// scan phase 3: add block offsets; also init cursor
__global__ void scan3(int* __restrict__ rs, const int* __restrict__ boff,
                      int* __restrict__ cursor, int n) {
  int i = blockIdx.x * blockDim.x + threadIdx.x;
  if (i < n) {
    int v = rs[i] + boff[i >> 10];
    rs[i] = v;
    cursor[i] = v;
  }
}

__global__ void scatter_kernel(const int* __restrict__ src, const int* __restrict__ dst,
                               int* __restrict__ cursor, int* __restrict__ csr_src, int E) {
  int i = blockIdx.x * blockDim.x + threadIdx.x;
  if (i < E) {
    int pos = atomicAdd(&cursor[dst[i]], 1);
    csr_src[pos] = src[i];
  }
}

// ---------- weight conversion (merged) ----------
// W1t[n][k] (256x256): k<128 -> W1l[k][n], else W1r[k-128][n]
// W2t[n][k] (128x256): n<64  -> W2l[k][n], else W2r[k][n-64]
__global__ void convw(const float* __restrict__ W1l, const float* __restrict__ W1r,
                      const float* __restrict__ W2l, const float* __restrict__ W2r,
                      unsigned short* __restrict__ W1t, unsigned short* __restrict__ W2t) {
  int i = blockIdx.x * blockDim.x + threadIdx.x;
  if (i < 256 * 256) {
    int n = i >> 8, k = i & 255;
    float v = (k < 128) ? W1l[k * 256 + n] : W1r[(k - 128) * 256 + n];
    W1t[i] = f2bf(v);
  } else if (i < 256 * 256 + 128 * 256) {
    int j = i - 256 * 256;
    int n = j >> 8, k = j & 255;
    float v = (n < 64) ? W2l[k * 64 + n] : W2r[k * 64 + (n - 64)];
    W2t[j] = f2bf(v);
  }
}

// x (fp32, [N][128]) -> right half of A1 (bf16, [N][256] cols 128..255)
__global__ void convx(const float* __restrict__ x, unsigned short* __restrict__ A1, int n_nodes) {
  int i = blockIdx.x * blockDim.x + threadIdx.x;
  if (i < n_nodes * 32) {
    int node = i >> 5, c4 = (i & 31) * 4;
    float4 v = *reinterpret_cast<const float4*>(x + (size_t)node * 128 + c4);
    unsigned short r[4] = { f2bf(v.x), f2bf(v.y), f2bf(v.z), f2bf(v.w) };
    *reinterpret_cast<uint2*>(A1 + (size_t)node * 256 + 128 + c4) =
        *reinterpret_cast<uint2*>(r);
  }
}

// ---------- layer-1 aggregation: one wave per node, 2 bf16 channels/lane ----------
// Gathers the bf16 copy of x living in A1's right half (256B rows), 4 edges in flight.
__global__ __launch_bounds__(256) void agg1_kernel(const int* __restrict__ csr_src,
                                                   const int* __restrict__ rs,
                                                   unsigned short* __restrict__ A1,
                                                   int n_nodes) {
  int w = blockIdx.x * 4 + (threadIdx.x >> 6);
  if (w >= n_nodes) return;
  int lane = threadIdx.x & 63;
  int e0 = rs[w], e1 = rs[w + 1];
  const unsigned short* xb = A1 + 128 + 2 * lane;   // bf16 x, row stride 256 elems
  float ax0 = 0.f, ay0 = 0.f, ax1 = 0.f, ay1 = 0.f;
  float ax2 = 0.f, ay2 = 0.f, ax3 = 0.f, ay3 = 0.f;
  int e = e0;
  for (; e + 4 <= e1; e += 4) {
    int s0 = csr_src[e + 0], s1 = csr_src[e + 1];
    int s2 = csr_src[e + 2], s3 = csr_src[e + 3];
    unsigned int p0 = *reinterpret_cast<const unsigned int*>(xb + (size_t)s0 * 256);
    unsigned int p1 = *reinterpret_cast<const unsigned int*>(xb + (size_t)s1 * 256);
    unsigned int p2 = *reinterpret_cast<const unsigned int*>(xb + (size_t)s2 * 256);
    unsigned int p3 = *reinterpret_cast<const unsigned int*>(xb + (size_t)s3 * 256);
    ax0 += bf2f((unsigned short)(p0 & 0xffff)); ay0 += bf2f((unsigned short)(p0 >> 16));
    ax1 += bf2f((unsigned short)(p1 & 0xffff)); ay1 += bf2f((unsigned short)(p1 >> 16));
    ax2 += bf2f((unsigned short)(p2 & 0xffff)); ay2 += bf2f((unsigned short)(p2 >> 16));
    ax3 += bf2f((unsigned short)(p3 & 0xffff)); ay3 += bf2f((unsigned short)(p3 >> 16));
  }
  for (; e < e1; ++e) {
    int s = csr_src[e];
    unsigned int p = *reinterpret_cast<const unsigned int*>(xb + (size_t)s * 256);
    ax0 += bf2f((unsigned short)(p & 0xffff)); ay0 += bf2f((unsigned short)(p >> 16));
  }
  float ax = (ax0 + ax1) + (ax2 + ax3);
  float ay = (ay0 + ay1) + (ay2 + ay3);
  int d = e1 - e0; if (d < 1) d = 1;
  float scale = 1.0f / (float)d;
  unsigned int packed = (unsigned int)f2bf(ax * scale) |
                        ((unsigned int)f2bf(ay * scale) << 16);
  *reinterpret_cast<unsigned int*>(A1 + (size_t)w * 256 + 2 * lane) = packed;
}

// ---------- bf16 MFMA GEMM: C[M][N] = A[M][K] * Bt[N][K]^T, optional bias+relu ----------
#define BM 128
#define BN 128
#define BK 64
template <bool RELU_BIAS>
__global__ __launch_bounds__(256) void gemm_bf16(const unsigned short* __restrict__ A,
                                                 const unsigned short* __restrict__ Bt,
                                                 const float* __restrict__ bias,
                                                 unsigned short* __restrict__ C,
                                                 int M, int N, int K) {
  __shared__ unsigned short As[BM][BK + 8];  // +8 bf16 pad -> 144B row stride
  __shared__ unsigned short Bs[BN][BK + 8];
  const int tid = threadIdx.x;
  const int lane = tid & 63;
  const int wave = tid >> 6;
  const int m0 = blockIdx.x * BM;
  const int n0 = blockIdx.y * BN;
  const int wr = (wave >> 1) * 64;  // wave's row offset in block tile
  const int wc = (wave & 1) * 64;   // wave's col offset
  const int fm = lane & 15;
  const int fq = lane >> 4;

  floatx4 acc[4][4] = {};

  for (int k0 = 0; k0 < K; k0 += BK) {
    for (int c = tid; c < BM * BK / 8; c += 256) {
      int row = c >> 3;
      int col = (c & 7) * 8;
      int gr = m0 + row; if (gr >= M) gr = M - 1;
      int4 v = *reinterpret_cast<const int4*>(A + (size_t)gr * K + k0 + col);
      *reinterpret_cast<int4*>(&As[row][col]) = v;
    }
    for (int c = tid; c < BN * BK / 8; c += 256) {
      int row = c >> 3;
      int col = (c & 7) * 8;
      int4 v = *reinterpret_cast<const int4*>(Bt + (size_t)(n0 + row) * K + k0 + col);
      *reinterpret_cast<int4*>(&Bs[row][col]) = v;
    }
    __syncthreads();
#pragma unroll
    for (int kk = 0; kk < BK; kk += 32) {
      short8 af[4], bfr[4];
#pragma unroll
      for (int i = 0; i < 4; i++)
        af[i] = *reinterpret_cast<const short8*>(&As[wr + i * 16 + fm][kk + fq * 8]);
#pragma unroll
      for (int i = 0; i < 4; i++)
        bfr[i] = *reinterpret_cast<const short8*>(&Bs[wc + i * 16 + fm][kk + fq * 8]);
#pragma unroll
      for (int mi = 0; mi < 4; mi++)
#pragma unroll
        for (int ni = 0; ni < 4; ni++)
          acc[mi][ni] = __builtin_amdgcn_mfma_f32_16x16x32_bf16(af[mi], bfr[ni],
                                                                acc[mi][ni], 0, 0, 0);
    }
    __syncthreads();
  }

  // epilogue: D row = fq*4 + r, col = fm (within each 16x16 tile)
#pragma unroll
  for (int mi = 0; mi < 4; mi++) {
#pragma unroll
    for (int ni = 0; ni < 4; ni++) {
#pragma unroll
      for (int r = 0; r < 4; r++) {
        int grow = m0 + wr + mi * 16 + fq * 4 + r;
        int gcol = n0 + wc + ni * 16 + fm;
        if (grow < M) {
          float v = acc[mi][ni][r];
          if (RELU_BIAS) {
            v += bias[gcol];
            v = v > 0.f ? v : 0.f;
          }
          C[(size_t)grow * N + gcol] = f2bf(v);
        }
      }
    }
  }
}

// ---------- layer-2 aggregation + epilogue: one wave per node, 1 channel/lane ----------
__global__ __launch_bounds__(256) void agg2_final(const unsigned short* __restrict__ zr,
                                                  const int* __restrict__ csr_src,
                                                  const int* __restrict__ rs,
                                                  const float* __restrict__ b2,
                                                  float* __restrict__ out, int n_nodes) {
  int w = blockIdx.x * 4 + (threadIdx.x >> 6);
  if (w >= n_nodes) return;
  int lane = threadIdx.x & 63;
  int e0 = rs[w], e1 = rs[w + 1];
  float a0 = 0.f, a1 = 0.f, a2 = 0.f, a3 = 0.f;
  int e = e0;
  for (; e + 4 <= e1; e += 4) {
    int s0 = csr_src[e + 0], s1 = csr_src[e + 1];
    int s2 = csr_src[e + 2], s3 = csr_src[e + 3];
    a0 += bf2f(zr[(size_t)s0 * 128 + lane]);
    a1 += bf2f(zr[(size_t)s1 * 128 + lane]);
    a2 += bf2f(zr[(size_t)s2 * 128 + lane]);
    a3 += bf2f(zr[(size_t)s3 * 128 + lane]);
  }
  for (; e < e1; ++e) {
    a0 += bf2f(zr[(size_t)csr_src[e] * 128 + lane]);
  }
  float acc = (a0 + a1) + (a2 + a3);
  int d = e1 - e0; if (d < 1) d = 1;
  float r = bf2f(zr[(size_t)w * 128 + 64 + lane]);  // r part: cols 64..127
  float v = acc / (float)d + r + b2[lane];
  out[(size_t)w * 64 + lane] = 1.0f / (1.0f + __expf(-v));
}

// ---------- launch ----------
extern "C" void kernel_launch(void* const* d_in, const int* in_sizes, int n_in,
                              void* d_out, int out_size, void* d_ws, size_t ws_size,
                              hipStream_t stream) {
  const float* x   = (const float*)d_in[0];
  const int*   ei  = (const int*)d_in[1];
  const float* W1l = (const float*)d_in[2];
  const float* W1r = (const float*)d_in[3];
  const float* b1  = (const float*)d_in[4];
  const float* W2l = (const float*)d_in[5];
  const float* W2r = (const float*)d_in[6];
  const float* b2  = (const float*)d_in[7];
  float* out = (float*)d_out;

  const int N = in_sizes[0] / 128;     // 100000
  const int E = in_sizes[1] / 2;       // 1600000
  const int* src = ei;
  const int* dst = ei + E;

  // workspace layout (512B aligned blocks)
  char* wsb = (char*)d_ws;
  size_t off = 0;
  auto alloc = [&](size_t bytes) -> void* {
    void* p = wsb + off;
    off += (bytes + 511) & ~(size_t)511;
    return p;
  };
  int* deg      = (int*)alloc((size_t)N * 4);
  int* rs       = (int*)alloc((size_t)(N + 1) * 4);
  int* cursor   = (int*)alloc((size_t)N * 4);
  int* bsums    = (int*)alloc(512);
  int* boff     = (int*)alloc(512);
  int* csr_src  = (int*)alloc((size_t)E * 4);
  unsigned short* W1t = (unsigned short*)alloc(256 * 256 * 2);
  unsigned short* W2t = (unsigned short*)alloc(128 * 256 * 2);
  unsigned short* A1  = (unsigned short*)alloc((size_t)N * 256 * 2);
  unsigned short* h   = (unsigned short*)alloc((size_t)N * 256 * 2);
  unsigned short* zr  = (unsigned short*)alloc((size_t)N * 128 * 2);
  (void)ws_size; (void)n_in; (void)out_size;

  const int NB = (N + 1023) / 1024;   // 98 scan blocks

  hipMemsetAsync(deg, 0, (size_t)N * 4, stream);
  deg_kernel<<<(E + 255) / 256, 256, 0, stream>>>(dst, deg, E);
  scan1<<<NB, 256, 0, stream>>>(deg, rs, bsums, N);
  scan2<<<1, 64, 0, stream>>>(bsums, boff, NB, rs + N);
  scan3<<<(N + 255) / 256, 256, 0, stream>>>(rs, boff, cursor, N);
  scatter_kernel<<<(E + 255) / 256, 256, 0, stream>>>(src, dst, cursor, csr_src, E);

  convw<<<(256 * 256 + 128 * 256 + 255) / 256, 256, 0, stream>>>(W1l, W1r, W2l, W2r, W1t, W2t);
  convx<<<(N * 32 + 255) / 256, 256, 0, stream>>>(x, A1, N);

  agg1_kernel<<<(N + 3) / 4, 256, 0, stream>>>(csr_src, rs, A1, N);

  dim3 g1((N + BM - 1) / BM, 256 / BN);
  gemm_bf16<true><<<g1, 256, 0, stream>>>(A1, W1t, b1, h, N, 256, 256);

  dim3 g2((N + BM - 1) / BM, 128 / BN);
  gemm_bf16<false><<<g2, 256, 0, stream>>>(h, W2t, nullptr, zr, N, 128, 256);

  agg2_final<<<(N + 3) / 4, 256, 0, stream>>>(zr, csr_src, rs, b2, out, N);
}

// Round 3
// 437.650 us; speedup vs baseline: 1.6350x; 1.2375x over previous
//
#include <hip/hip_runtime.h>

// ---------- helpers ----------
typedef __attribute__((ext_vector_type(8))) short short8;   // 8 x bf16 fragment (4 VGPRs)
typedef __attribute__((ext_vector_type(4))) float floatx4;  // MFMA accumulator

static __device__ __forceinline__ unsigned short f2bf(float f) {
  unsigned int u = __builtin_bit_cast(unsigned int, f);
  u += 0x7FFFu + ((u >> 16) & 1u);   // RNE (finite inputs only)
  return (unsigned short)(u >> 16);
}
static __device__ __forceinline__ float bf2f(unsigned short s) {
  unsigned int u = ((unsigned int)s) << 16;
  return __builtin_bit_cast(float, u);
}

#define NBUCK 128        // padded bucket count; real buckets = ceil(N/1024) = 98
#define BIN_CHUNK 8192   // edges per binscatter workgroup

// ---------- CSR build via two-level binning (avoids 16x write amplification) ----------

// bucket histogram: bucket = dst >> 10
__global__ __launch_bounds__(256) void bhist(const int* __restrict__ dst,
                                             int* __restrict__ bcnt, int E) {
  __shared__ int h[NBUCK];
  for (int i = threadIdx.x; i < NBUCK; i += 256) h[i] = 0;
  __syncthreads();
  int stride = gridDim.x * 256;
  for (int i = blockIdx.x * 256 + threadIdx.x; i < E; i += stride)
    atomicAdd(&h[dst[i] >> 10], 1);
  __syncthreads();
  for (int i = threadIdx.x; i < NBUCK; i += 256)
    if (h[i]) atomicAdd(&bcnt[i], h[i]);
}

// single-WG scan of bucket counts -> bases + cursors; also rs[N] = E
__global__ __launch_bounds__(128) void bscan(const int* __restrict__ bcnt,
                                             int* __restrict__ bbase,
                                             int* __restrict__ bcur,
                                             int* __restrict__ rs, int N, int E) {
  __shared__ int s[NBUCK];
  int t = threadIdx.x;
  int v = bcnt[t];
  s[t] = v;
  __syncthreads();
  for (int off = 1; off < NBUCK; off <<= 1) {
    int x = (t >= off) ? s[t - off] : 0;
    __syncthreads();
    s[t] += x;
    __syncthreads();
  }
  int excl = s[t] - v;
  bbase[t] = excl;
  bcur[t] = excl;
  if (t == 0) rs[N] = E;
}

// bin edges into bucket-grouped staging; packed word = (dst&1023)<<17 | src
__global__ __launch_bounds__(256) void binscatter(const int* __restrict__ src,
                                                  const int* __restrict__ dst,
                                                  int* __restrict__ bcur,
                                                  unsigned int* __restrict__ staging,
                                                  int E) {
  __shared__ int h[NBUCK];
  __shared__ int cur[NBUCK];
  for (int i = threadIdx.x; i < NBUCK; i += 256) h[i] = 0;
  __syncthreads();
  int base = blockIdx.x * BIN_CHUNK;
  int end = base + BIN_CHUNK; if (end > E) end = E;
  for (int i = base + threadIdx.x; i < end; i += 256)
    atomicAdd(&h[dst[i] >> 10], 1);
  __syncthreads();
  for (int i = threadIdx.x; i < NBUCK; i += 256)
    cur[i] = h[i] ? atomicAdd(&bcur[i], h[i]) : 0;
  __syncthreads();
  for (int i = base + threadIdx.x; i < end; i += 256) {
    int d = dst[i], s = src[i];
    int b = d >> 10;
    int pos = atomicAdd(&cur[b], 1);
    staging[pos] = ((unsigned int)(d & 1023) << 17) | (unsigned int)s;
  }
}

// one WG per bucket: node-level histogram + scan (writes rs) + scatter into csr.
// All csr writes land in this bucket's ~64KB slice -> XCD-local full-line writebacks.
__global__ __launch_bounds__(256) void bucketfinal(const unsigned int* __restrict__ staging,
                                                   const int* __restrict__ bbase,
                                                   const int* __restrict__ bcnt,
                                                   int* __restrict__ rs,
                                                   int* __restrict__ csr_src, int N) {
  int b = blockIdx.x;
  int base = bbase[b], cnt = bcnt[b];
  __shared__ int h[1024];
  __shared__ int ps[256];
  __shared__ int cur[1024];
  int t = threadIdx.x;
  for (int i = t; i < 1024; i += 256) h[i] = 0;
  __syncthreads();
  for (int i = t; i < cnt; i += 256)
    atomicAdd(&h[staging[base + i] >> 17], 1);
  __syncthreads();
  int a0 = h[4 * t], a1 = h[4 * t + 1], a2 = h[4 * t + 2], a3 = h[4 * t + 3];
  int tsum = a0 + a1 + a2 + a3;
  ps[t] = tsum;
  __syncthreads();
  for (int off = 1; off < 256; off <<= 1) {
    int x = (t >= off) ? ps[t - off] : 0;
    __syncthreads();
    ps[t] += x;
    __syncthreads();
  }
  int run = base + ps[t] - tsum;
  int node0 = b << 10;
  int va[4] = {a0, a1, a2, a3};
#pragma unroll
  for (int j = 0; j < 4; j++) {
    int w = node0 + 4 * t + j;
    cur[4 * t + j] = run;
    if (w < N) rs[w] = run;
    run += va[j];
  }
  __syncthreads();
  for (int i = t; i < cnt; i += 256) {
    unsigned int v = staging[base + i];
    int pos = atomicAdd(&cur[v >> 17], 1);
    csr_src[pos] = (int)(v & 0x1FFFFu);
  }
}

// ---------- weight conversion (merged) ----------
// W1t[n][k] (256x256): k<128 -> W1l[k][n], else W1r[k-128][n]
// W2t[n][k] (128x256): n<64  -> W2l[k][n], else W2r[k][n-64]
__global__ void convw(const float* __restrict__ W1l, const float* __restrict__ W1r,
                      const float* __restrict__ W2l, const float* __restrict__ W2r,
                      unsigned short* __restrict__ W1t, unsigned short* __restrict__ W2t) {
  int i = blockIdx.x * blockDim.x + threadIdx.x;
  if (i < 256 * 256) {
    int n = i >> 8, k = i & 255;
    float v = (k < 128) ? W1l[k * 256 + n] : W1r[(k - 128) * 256 + n];
    W1t[i] = f2bf(v);
  } else if (i < 256 * 256 + 128 * 256) {
    int j = i - 256 * 256;
    int n = j >> 8, k = j & 255;
    float v = (n < 64) ? W2l[k * 64 + n] : W2r[k * 64 + (n - 64)];
    W2t[j] = f2bf(v);
  }
}

// x (fp32, [N][128]) -> right half of A1 (bf16, [N][256] cols 128..255)
__global__ void convx(const float* __restrict__ x, unsigned short* __restrict__ A1, int n_nodes) {
  int i = blockIdx.x * blockDim.x + threadIdx.x;
  if (i < n_nodes * 32) {
    int node = i >> 5, c4 = (i & 31) * 4;
    float4 v = *reinterpret_cast<const float4*>(x + (size_t)node * 128 + c4);
    unsigned short r[4] = { f2bf(v.x), f2bf(v.y), f2bf(v.z), f2bf(v.w) };
    *reinterpret_cast<uint2*>(A1 + (size_t)node * 256 + 128 + c4) =
        *reinterpret_cast<uint2*>(r);
  }
}

// ---------- layer-1 aggregation: one wave per node, 2 bf16 channels/lane ----------
__global__ __launch_bounds__(256) void agg1_kernel(const int* __restrict__ csr_src,
                                                   const int* __restrict__ rs,
                                                   unsigned short* __restrict__ A1,
                                                   int n_nodes) {
  int w = blockIdx.x * 4 + (threadIdx.x >> 6);
  if (w >= n_nodes) return;
  int lane = threadIdx.x & 63;
  int e0 = rs[w], e1 = rs[w + 1];
  const unsigned short* xb = A1 + 128 + 2 * lane;   // bf16 x, row stride 256 elems
  float ax0 = 0.f, ay0 = 0.f, ax1 = 0.f, ay1 = 0.f;
  float ax2 = 0.f, ay2 = 0.f, ax3 = 0.f, ay3 = 0.f;
  int e = e0;
  for (; e + 4 <= e1; e += 4) {
    int s0 = csr_src[e + 0], s1 = csr_src[e + 1];
    int s2 = csr_src[e + 2], s3 = csr_src[e + 3];
    unsigned int p0 = *reinterpret_cast<const unsigned int*>(xb + (size_t)s0 * 256);
    unsigned int p1 = *reinterpret_cast<const unsigned int*>(xb + (size_t)s1 * 256);
    unsigned int p2 = *reinterpret_cast<const unsigned int*>(xb + (size_t)s2 * 256);
    unsigned int p3 = *reinterpret_cast<const unsigned int*>(xb + (size_t)s3 * 256);
    ax0 += bf2f((unsigned short)(p0 & 0xffff)); ay0 += bf2f((unsigned short)(p0 >> 16));
    ax1 += bf2f((unsigned short)(p1 & 0xffff)); ay1 += bf2f((unsigned short)(p1 >> 16));
    ax2 += bf2f((unsigned short)(p2 & 0xffff)); ay2 += bf2f((unsigned short)(p2 >> 16));
    ax3 += bf2f((unsigned short)(p3 & 0xffff)); ay3 += bf2f((unsigned short)(p3 >> 16));
  }
  for (; e < e1; ++e) {
    int s = csr_src[e];
    unsigned int p = *reinterpret_cast<const unsigned int*>(xb + (size_t)s * 256);
    ax0 += bf2f((unsigned short)(p & 0xffff)); ay0 += bf2f((unsigned short)(p >> 16));
  }
  float ax = (ax0 + ax1) + (ax2 + ax3);
  float ay = (ay0 + ay1) + (ay2 + ay3);
  int d = e1 - e0; if (d < 1) d = 1;
  float scale = 1.0f / (float)d;
  unsigned int packed = (unsigned int)f2bf(ax * scale) |
                        ((unsigned int)f2bf(ay * scale) << 16);
  *reinterpret_cast<unsigned int*>(A1 + (size_t)w * 256 + 2 * lane) = packed;
}

// ---------- bf16 MFMA GEMM: C[M][N] = A[M][K] * Bt[N][K]^T, optional bias+relu ----------
#define BM 128
#define BN 128
#define BK 64
template <bool RELU_BIAS>
__global__ __launch_bounds__(256) void gemm_bf16(const unsigned short* __restrict__ A,
                                                 const unsigned short* __restrict__ Bt,
                                                 const float* __restrict__ bias,
                                                 unsigned short* __restrict__ C,
                                                 int M, int N, int K) {
  __shared__ unsigned short As[BM][BK + 8];  // +8 bf16 pad -> 144B row stride
  __shared__ unsigned short Bs[BN][BK + 8];
  const int tid = threadIdx.x;
  const int lane = tid & 63;
  const int wave = tid >> 6;
  const int m0 = blockIdx.x * BM;
  const int n0 = blockIdx.y * BN;
  const int wr = (wave >> 1) * 64;  // wave's row offset in block tile
  const int wc = (wave & 1) * 64;   // wave's col offset
  const int fm = lane & 15;
  const int fq = lane >> 4;

  floatx4 acc[4][4] = {};

  for (int k0 = 0; k0 < K; k0 += BK) {
    for (int c = tid; c < BM * BK / 8; c += 256) {
      int row = c >> 3;
      int col = (c & 7) * 8;
      int gr = m0 + row; if (gr >= M) gr = M - 1;
      int4 v = *reinterpret_cast<const int4*>(A + (size_t)gr * K + k0 + col);
      *reinterpret_cast<int4*>(&As[row][col]) = v;
    }
    for (int c = tid; c < BN * BK / 8; c += 256) {
      int row = c >> 3;
      int col = (c & 7) * 8;
      int4 v = *reinterpret_cast<const int4*>(Bt + (size_t)(n0 + row) * K + k0 + col);
      *reinterpret_cast<int4*>(&Bs[row][col]) = v;
    }
    __syncthreads();
#pragma unroll
    for (int kk = 0; kk < BK; kk += 32) {
      short8 af[4], bfr[4];
#pragma unroll
      for (int i = 0; i < 4; i++)
        af[i] = *reinterpret_cast<const short8*>(&As[wr + i * 16 + fm][kk + fq * 8]);
#pragma unroll
      for (int i = 0; i < 4; i++)
        bfr[i] = *reinterpret_cast<const short8*>(&Bs[wc + i * 16 + fm][kk + fq * 8]);
#pragma unroll
      for (int mi = 0; mi < 4; mi++)
#pragma unroll
        for (int ni = 0; ni < 4; ni++)
          acc[mi][ni] = __builtin_amdgcn_mfma_f32_16x16x32_bf16(af[mi], bfr[ni],
                                                                acc[mi][ni], 0, 0, 0);
    }
    __syncthreads();
  }

  // epilogue: D row = fq*4 + r, col = fm (within each 16x16 tile)
#pragma unroll
  for (int mi = 0; mi < 4; mi++) {
#pragma unroll
    for (int ni = 0; ni < 4; ni++) {
#pragma unroll
      for (int r = 0; r < 4; r++) {
        int grow = m0 + wr + mi * 16 + fq * 4 + r;
        int gcol = n0 + wc + ni * 16 + fm;
        if (grow < M) {
          float v = acc[mi][ni][r];
          if (RELU_BIAS) {
            v += bias[gcol];
            v = v > 0.f ? v : 0.f;
          }
          C[(size_t)grow * N + gcol] = f2bf(v);
        }
      }
    }
  }
}

// ---------- layer-2 aggregation + epilogue: one wave per node, 1 channel/lane ----------
__global__ __launch_bounds__(256) void agg2_final(const unsigned short* __restrict__ zr,
                                                  const int* __restrict__ csr_src,
                                                  const int* __restrict__ rs,
                                                  const float* __restrict__ b2,
                                                  float* __restrict__ out, int n_nodes) {
  int w = blockIdx.x * 4 + (threadIdx.x >> 6);
  if (w >= n_nodes) return;
  int lane = threadIdx.x & 63;
  int e0 = rs[w], e1 = rs[w + 1];
  float a0 = 0.f, a1 = 0.f, a2 = 0.f, a3 = 0.f;
  int e = e0;
  for (; e + 4 <= e1; e += 4) {
    int s0 = csr_src[e + 0], s1 = csr_src[e + 1];
    int s2 = csr_src[e + 2], s3 = csr_src[e + 3];
    a0 += bf2f(zr[(size_t)s0 * 128 + lane]);
    a1 += bf2f(zr[(size_t)s1 * 128 + lane]);
    a2 += bf2f(zr[(size_t)s2 * 128 + lane]);
    a3 += bf2f(zr[(size_t)s3 * 128 + lane]);
  }
  for (; e < e1; ++e) {
    a0 += bf2f(zr[(size_t)csr_src[e] * 128 + lane]);
  }
  float acc = (a0 + a1) + (a2 + a3);
  int d = e1 - e0; if (d < 1) d = 1;
  float r = bf2f(zr[(size_t)w * 128 + 64 + lane]);  // r part: cols 64..127
  float v = acc / (float)d + r + b2[lane];
  out[(size_t)w * 64 + lane] = 1.0f / (1.0f + __expf(-v));
}

// ---------- launch ----------
extern "C" void kernel_launch(void* const* d_in, const int* in_sizes, int n_in,
                              void* d_out, int out_size, void* d_ws, size_t ws_size,
                              hipStream_t stream) {
  const float* x   = (const float*)d_in[0];
  const int*   ei  = (const int*)d_in[1];
  const float* W1l = (const float*)d_in[2];
  const float* W1r = (const float*)d_in[3];
  const float* b1  = (const float*)d_in[4];
  const float* W2l = (const float*)d_in[5];
  const float* W2r = (const float*)d_in[6];
  const float* b2  = (const float*)d_in[7];
  float* out = (float*)d_out;

  const int N = in_sizes[0] / 128;     // 100000
  const int E = in_sizes[1] / 2;       // 1600000
  const int* src = ei;
  const int* dst = ei + E;

  // workspace layout (512B aligned blocks)
  char* wsb = (char*)d_ws;
  size_t off = 0;
  auto alloc = [&](size_t bytes) -> void* {
    void* p = wsb + off;
    off += (bytes + 511) & ~(size_t)511;
    return p;
  };
  int* rs       = (int*)alloc((size_t)(N + 1) * 4);
  int* csr_src  = (int*)alloc((size_t)E * 4);
  int* bcnt     = (int*)alloc(NBUCK * 4);
  int* bbase    = (int*)alloc(NBUCK * 4);
  int* bcur     = (int*)alloc(NBUCK * 4);
  unsigned short* W1t = (unsigned short*)alloc(256 * 256 * 2);
  unsigned short* W2t = (unsigned short*)alloc(128 * 256 * 2);
  unsigned short* A1  = (unsigned short*)alloc((size_t)N * 256 * 2);
  unsigned short* h   = (unsigned short*)alloc((size_t)N * 256 * 2);
  unsigned short* zr  = (unsigned short*)alloc((size_t)N * 128 * 2);
  unsigned int* staging = (unsigned int*)h;   // alias: staging dead before gemm1 writes h
  (void)ws_size; (void)n_in; (void)out_size;

  const int nbuckReal = (N + 1023) / 1024;            // 98
  const int nchunks = (E + BIN_CHUNK - 1) / BIN_CHUNK; // 196

  hipMemsetAsync(bcnt, 0, NBUCK * 4, stream);
  bhist<<<256, 256, 0, stream>>>(dst, bcnt, E);
  bscan<<<1, 128, 0, stream>>>(bcnt, bbase, bcur, rs, N, E);
  binscatter<<<nchunks, 256, 0, stream>>>(src, dst, bcur, staging, E);
  bucketfinal<<<nbuckReal, 256, 0, stream>>>(staging, bbase, bcnt, rs, csr_src, N);

  convw<<<(256 * 256 + 128 * 256 + 255) / 256, 256, 0, stream>>>(W1l, W1r, W2l, W2r, W1t, W2t);
  convx<<<(N * 32 + 255) / 256, 256, 0, stream>>>(x, A1, N);

  agg1_kernel<<<(N + 3) / 4, 256, 0, stream>>>(csr_src, rs, A1, N);

  dim3 g1((N + BM - 1) / BM, 256 / BN);
  gemm_bf16<true><<<g1, 256, 0, stream>>>(A1, W1t, b1, h, N, 256, 256);

  dim3 g2((N + BM - 1) / BM, 128 / BN);
  gemm_bf16<false><<<g2, 256, 0, stream>>>(h, W2t, nullptr, zr, N, 128, 256);

  agg2_final<<<(N + 3) / 4, 256, 0, stream>>>(zr, csr_src, rs, b2, out, N);
}

// Round 4
// 379.479 us; speedup vs baseline: 1.8856x; 1.1533x over previous
//
#include <hip/hip_runtime.h>

// ---------- helpers ----------
typedef __attribute__((ext_vector_type(8))) short short8;   // 8 x bf16 fragment (4 VGPRs)
typedef __attribute__((ext_vector_type(4))) float floatx4;  // MFMA accumulator

static __device__ __forceinline__ unsigned short f2bf(float f) {
  unsigned int u = __builtin_bit_cast(unsigned int, f);
  u += 0x7FFFu + ((u >> 16) & 1u);   // RNE (finite inputs only)
  return (unsigned short)(u >> 16);
}
static __device__ __forceinline__ float bf2f(unsigned short s) {
  unsigned int u = ((unsigned int)s) << 16;
  return __builtin_bit_cast(float, u);
}

#define NBUCK 128        // padded bucket count; real buckets = ceil(N/1024) = 98
#define BIN_CHUNK 8192   // edges per binscatter workgroup

// ---------- CSR build via two-level binning (avoids 16x write amplification) ----------

__global__ __launch_bounds__(256) void bhist(const int* __restrict__ dst,
                                             int* __restrict__ bcnt, int E) {
  __shared__ int h[NBUCK];
  for (int i = threadIdx.x; i < NBUCK; i += 256) h[i] = 0;
  __syncthreads();
  int stride = gridDim.x * 256;
  for (int i = blockIdx.x * 256 + threadIdx.x; i < E; i += stride)
    atomicAdd(&h[dst[i] >> 10], 1);
  __syncthreads();
  for (int i = threadIdx.x; i < NBUCK; i += 256)
    if (h[i]) atomicAdd(&bcnt[i], h[i]);
}

__global__ __launch_bounds__(128) void bscan(const int* __restrict__ bcnt,
                                             int* __restrict__ bbase,
                                             int* __restrict__ bcur,
                                             int* __restrict__ rs, int N, int E) {
  __shared__ int s[NBUCK];
  int t = threadIdx.x;
  int v = bcnt[t];
  s[t] = v;
  __syncthreads();
  for (int off = 1; off < NBUCK; off <<= 1) {
    int x = (t >= off) ? s[t - off] : 0;
    __syncthreads();
    s[t] += x;
    __syncthreads();
  }
  int excl = s[t] - v;
  bbase[t] = excl;
  bcur[t] = excl;
  if (t == 0) rs[N] = E;
}

__global__ __launch_bounds__(256) void binscatter(const int* __restrict__ src,
                                                  const int* __restrict__ dst,
                                                  int* __restrict__ bcur,
                                                  unsigned int* __restrict__ staging,
                                                  int E) {
  __shared__ int h[NBUCK];
  __shared__ int cur[NBUCK];
  for (int i = threadIdx.x; i < NBUCK; i += 256) h[i] = 0;
  __syncthreads();
  int base = blockIdx.x * BIN_CHUNK;
  int end = base + BIN_CHUNK; if (end > E) end = E;
  for (int i = base + threadIdx.x; i < end; i += 256)
    atomicAdd(&h[dst[i] >> 10], 1);
  __syncthreads();
  for (int i = threadIdx.x; i < NBUCK; i += 256)
    cur[i] = h[i] ? atomicAdd(&bcur[i], h[i]) : 0;
  __syncthreads();
  for (int i = base + threadIdx.x; i < end; i += 256) {
    int d = dst[i], s = src[i];
    int b = d >> 10;
    int pos = atomicAdd(&cur[b], 1);
    staging[pos] = ((unsigned int)(d & 1023) << 17) | (unsigned int)s;
  }
}

__global__ __launch_bounds__(256) void bucketfinal(const unsigned int* __restrict__ staging,
                                                   const int* __restrict__ bbase,
                                                   const int* __restrict__ bcnt,
                                                   int* __restrict__ rs,
                                                   int* __restrict__ csr_src, int N) {
  int b = blockIdx.x;
  int base = bbase[b], cnt = bcnt[b];
  __shared__ int h[1024];
  __shared__ int ps[256];
  __shared__ int cur[1024];
  int t = threadIdx.x;
  for (int i = t; i < 1024; i += 256) h[i] = 0;
  __syncthreads();
  for (int i = t; i < cnt; i += 256)
    atomicAdd(&h[staging[base + i] >> 17], 1);
  __syncthreads();
  int a0 = h[4 * t], a1 = h[4 * t + 1], a2 = h[4 * t + 2], a3 = h[4 * t + 3];
  int tsum = a0 + a1 + a2 + a3;
  ps[t] = tsum;
  __syncthreads();
  for (int off = 1; off < 256; off <<= 1) {
    int x = (t >= off) ? ps[t - off] : 0;
    __syncthreads();
    ps[t] += x;
    __syncthreads();
  }
  int run = base + ps[t] - tsum;
  int node0 = b << 10;
  int va[4] = {a0, a1, a2, a3};
#pragma unroll
  for (int j = 0; j < 4; j++) {
    int w = node0 + 4 * t + j;
    cur[4 * t + j] = run;
    if (w < N) rs[w] = run;
    run += va[j];
  }
  __syncthreads();
  for (int i = t; i < cnt; i += 256) {
    unsigned int v = staging[base + i];
    int pos = atomicAdd(&cur[v >> 17], 1);
    csr_src[pos] = (int)(v & 0x1FFFFu);
  }
}

// ---------- weight conversion (merged) ----------
// W1t[n][k] (256x256): k<128 -> W1l[k][n], else W1r[k-128][n]
// W2t[n][k] (128x256): n<64  -> W2l[k][n], else W2r[k][n-64]
__global__ void convw(const float* __restrict__ W1l, const float* __restrict__ W1r,
                      const float* __restrict__ W2l, const float* __restrict__ W2r,
                      unsigned short* __restrict__ W1t, unsigned short* __restrict__ W2t) {
  int i = blockIdx.x * blockDim.x + threadIdx.x;
  if (i < 256 * 256) {
    int n = i >> 8, k = i & 255;
    float v = (k < 128) ? W1l[k * 256 + n] : W1r[(k - 128) * 256 + n];
    W1t[i] = f2bf(v);
  } else if (i < 256 * 256 + 128 * 256) {
    int j = i - 256 * 256;
    int n = j >> 8, k = j & 255;
    float v = (n < 64) ? W2l[k * 64 + n] : W2r[k * 64 + (n - 64)];
    W2t[j] = f2bf(v);
  }
}

// x (fp32, [N][128]) -> right half of A1 (bf16, [N][256] cols 128..255)
__global__ void convx(const float* __restrict__ x, unsigned short* __restrict__ A1, int n_nodes) {
  int i = blockIdx.x * blockDim.x + threadIdx.x;
  if (i < n_nodes * 32) {
    int node = i >> 5, c4 = (i & 31) * 4;
    float4 v = *reinterpret_cast<const float4*>(x + (size_t)node * 128 + c4);
    unsigned short r[4] = { f2bf(v.x), f2bf(v.y), f2bf(v.z), f2bf(v.w) };
    *reinterpret_cast<uint2*>(A1 + (size_t)node * 256 + 128 + c4) =
        *reinterpret_cast<uint2*>(r);
  }
}

// ---------- layer-1 aggregation: one wave per node, 2 bf16 channels/lane ----------
__global__ __launch_bounds__(256) void agg1_kernel(const int* __restrict__ csr_src,
                                                   const int* __restrict__ rs,
                                                   unsigned short* __restrict__ A1,
                                                   int n_nodes) {
  int w = blockIdx.x * 4 + (threadIdx.x >> 6);
  if (w >= n_nodes) return;
  int lane = threadIdx.x & 63;
  int e0 = rs[w], e1 = rs[w + 1];
  const unsigned short* xb = A1 + 128 + 2 * lane;   // bf16 x, row stride 256 elems
  float ax0 = 0.f, ay0 = 0.f, ax1 = 0.f, ay1 = 0.f;
  float ax2 = 0.f, ay2 = 0.f, ax3 = 0.f, ay3 = 0.f;
  int e = e0;
  for (; e + 4 <= e1; e += 4) {
    int s0 = csr_src[e + 0], s1 = csr_src[e + 1];
    int s2 = csr_src[e + 2], s3 = csr_src[e + 3];
    unsigned int p0 = *reinterpret_cast<const unsigned int*>(xb + (size_t)s0 * 256);
    unsigned int p1 = *reinterpret_cast<const unsigned int*>(xb + (size_t)s1 * 256);
    unsigned int p2 = *reinterpret_cast<const unsigned int*>(xb + (size_t)s2 * 256);
    unsigned int p3 = *reinterpret_cast<const unsigned int*>(xb + (size_t)s3 * 256);
    ax0 += bf2f((unsigned short)(p0 & 0xffff)); ay0 += bf2f((unsigned short)(p0 >> 16));
    ax1 += bf2f((unsigned short)(p1 & 0xffff)); ay1 += bf2f((unsigned short)(p1 >> 16));
    ax2 += bf2f((unsigned short)(p2 & 0xffff)); ay2 += bf2f((unsigned short)(p2 >> 16));
    ax3 += bf2f((unsigned short)(p3 & 0xffff)); ay3 += bf2f((unsigned short)(p3 >> 16));
  }
  for (; e < e1; ++e) {
    int s = csr_src[e];
    unsigned int p = *reinterpret_cast<const unsigned int*>(xb + (size_t)s * 256);
    ax0 += bf2f((unsigned short)(p & 0xffff)); ay0 += bf2f((unsigned short)(p >> 16));
  }
  float ax = (ax0 + ax1) + (ax2 + ax3);
  float ay = (ay0 + ay1) + (ay2 + ay3);
  int d = e1 - e0; if (d < 1) d = 1;
  float scale = 1.0f / (float)d;
  unsigned int packed = (unsigned int)f2bf(ax * scale) |
                        ((unsigned int)f2bf(ay * scale) << 16);
  *reinterpret_cast<unsigned int*>(A1 + (size_t)w * 256 + 2 * lane) = packed;
}

// ---------- fused MLP: zr[M][128] = [h@W2l | h@W2r], h = relu(A1@W1 + b1) ----------
// Per block: 128 rows. A1 tile resident in LDS (staged once, no per-K barriers);
// weight fragments streamed from global (L2-resident, reused by all 782 blocks);
// h lives only in LDS (no HBM round-trip).
#define LDSW 264   // padded row stride in shorts (528 B -> (fm+fq)%8 uniform banks)
__global__ __launch_bounds__(256, 2) void gemm_fused(const unsigned short* __restrict__ A1,
                                                     const unsigned short* __restrict__ W1t,
                                                     const unsigned short* __restrict__ W2t,
                                                     const float* __restrict__ b1,
                                                     unsigned short* __restrict__ zr,
                                                     int M) {
  __shared__ unsigned short smem[128 * LDSW];   // 67584 B -> 2 blocks/CU
  const int tid = threadIdx.x;
  const int lane = tid & 63;
  const int wave = tid >> 6;
  const int m0 = blockIdx.x * 128;
  const int fm = lane & 15;
  const int fq = lane >> 4;
  const int wr = (wave >> 1) * 64;   // wave's row range
  const int wc1 = (wave & 1) * 128;  // gemm1 col range (h cols)
  const int wc2 = (wave & 1) * 64;   // gemm2 col range (zr cols)

  // ---- stage A1 tile 128x256 bf16 into padded LDS (coalesced, 16 int4/thread) ----
#pragma unroll
  for (int j = 0; j < 16; j++) {
    int c = j * 256 + tid;
    int row = c >> 5, ch = c & 31;
    int gr = m0 + row; if (gr >= M) gr = M - 1;
    int4 v = *reinterpret_cast<const int4*>(A1 + (size_t)gr * 256 + ch * 8);
    *reinterpret_cast<int4*>(&smem[row * LDSW + ch * 8]) = v;
  }

  // bias for this lane's 8 output columns of gemm1
  float bb[8];
#pragma unroll
  for (int ni = 0; ni < 8; ni++) bb[ni] = b1[wc1 + ni * 16 + fm];

  __syncthreads();

  // ---- gemm1: h(128x256) partial = A1_tile @ W1t^T ----
  floatx4 acc1[4][8] = {};
#pragma unroll 2
  for (int kk = 0; kk < 8; kk++) {
    short8 af[4], bfr[8];
#pragma unroll
    for (int mi = 0; mi < 4; mi++)
      af[mi] = *reinterpret_cast<const short8*>(
          &smem[(wr + mi * 16 + fm) * LDSW + kk * 32 + fq * 8]);
#pragma unroll
    for (int ni = 0; ni < 8; ni++)
      bfr[ni] = *reinterpret_cast<const short8*>(
          W1t + (size_t)(wc1 + ni * 16 + fm) * 256 + kk * 32 + fq * 8);
#pragma unroll
    for (int mi = 0; mi < 4; mi++)
#pragma unroll
      for (int ni = 0; ni < 8; ni++)
        acc1[mi][ni] = __builtin_amdgcn_mfma_f32_16x16x32_bf16(af[mi], bfr[ni],
                                                               acc1[mi][ni], 0, 0, 0);
  }

  __syncthreads();   // all A-tile reads complete before overwrite

  // ---- bias + relu -> bf16 h tile into same LDS region ----
#pragma unroll
  for (int mi = 0; mi < 4; mi++)
#pragma unroll
    for (int ni = 0; ni < 8; ni++)
#pragma unroll
      for (int r = 0; r < 4; r++) {
        float v = acc1[mi][ni][r] + bb[ni];
        v = v > 0.f ? v : 0.f;
        smem[(wr + mi * 16 + fq * 4 + r) * LDSW + wc1 + ni * 16 + fm] = f2bf(v);
      }
  __syncthreads();

  // ---- gemm2: zr(128x128) = h_tile @ W2t^T ----
  floatx4 acc2[4][4] = {};
#pragma unroll 2
  for (int kk = 0; kk < 8; kk++) {
    short8 hf[4], wf[4];
#pragma unroll
    for (int mi = 0; mi < 4; mi++)
      hf[mi] = *reinterpret_cast<const short8*>(
          &smem[(wr + mi * 16 + fm) * LDSW + kk * 32 + fq * 8]);
#pragma unroll
    for (int ni = 0; ni < 4; ni++)
      wf[ni] = *reinterpret_cast<const short8*>(
          W2t + (size_t)(wc2 + ni * 16 + fm) * 256 + kk * 32 + fq * 8);
#pragma unroll
    for (int mi = 0; mi < 4; mi++)
#pragma unroll
      for (int ni = 0; ni < 4; ni++)
        acc2[mi][ni] = __builtin_amdgcn_mfma_f32_16x16x32_bf16(hf[mi], wf[ni],
                                                               acc2[mi][ni], 0, 0, 0);
  }

  // ---- store zr ----
#pragma unroll
  for (int mi = 0; mi < 4; mi++)
#pragma unroll
    for (int ni = 0; ni < 4; ni++)
#pragma unroll
      for (int r = 0; r < 4; r++) {
        int grow = m0 + wr + mi * 16 + fq * 4 + r;
        if (grow < M)
          zr[(size_t)grow * 128 + wc2 + ni * 16 + fm] = f2bf(acc2[mi][ni][r]);
      }
}

// ---------- layer-2 aggregation + epilogue: one wave per node, 1 channel/lane ----------
__global__ __launch_bounds__(256) void agg2_final(const unsigned short* __restrict__ zr,
                                                  const int* __restrict__ csr_src,
                                                  const int* __restrict__ rs,
                                                  const float* __restrict__ b2,
                                                  float* __restrict__ out, int n_nodes) {
  int w = blockIdx.x * 4 + (threadIdx.x >> 6);
  if (w >= n_nodes) return;
  int lane = threadIdx.x & 63;
  int e0 = rs[w], e1 = rs[w + 1];
  float a0 = 0.f, a1 = 0.f, a2 = 0.f, a3 = 0.f;
  int e = e0;
  for (; e + 4 <= e1; e += 4) {
    int s0 = csr_src[e + 0], s1 = csr_src[e + 1];
    int s2 = csr_src[e + 2], s3 = csr_src[e + 3];
    a0 += bf2f(zr[(size_t)s0 * 128 + lane]);
    a1 += bf2f(zr[(size_t)s1 * 128 + lane]);
    a2 += bf2f(zr[(size_t)s2 * 128 + lane]);
    a3 += bf2f(zr[(size_t)s3 * 128 + lane]);
  }
  for (; e < e1; ++e) {
    a0 += bf2f(zr[(size_t)csr_src[e] * 128 + lane]);
  }
  float acc = (a0 + a1) + (a2 + a3);
  int d = e1 - e0; if (d < 1) d = 1;
  float r = bf2f(zr[(size_t)w * 128 + 64 + lane]);  // r part: cols 64..127
  float v = acc / (float)d + r + b2[lane];
  out[(size_t)w * 64 + lane] = 1.0f / (1.0f + __expf(-v));
}

// ---------- launch ----------
extern "C" void kernel_launch(void* const* d_in, const int* in_sizes, int n_in,
                              void* d_out, int out_size, void* d_ws, size_t ws_size,
                              hipStream_t stream) {
  const float* x   = (const float*)d_in[0];
  const int*   ei  = (const int*)d_in[1];
  const float* W1l = (const float*)d_in[2];
  const float* W1r = (const float*)d_in[3];
  const float* b1  = (const float*)d_in[4];
  const float* W2l = (const float*)d_in[5];
  const float* W2r = (const float*)d_in[6];
  const float* b2  = (const float*)d_in[7];
  float* out = (float*)d_out;

  const int N = in_sizes[0] / 128;     // 100000
  const int E = in_sizes[1] / 2;       // 1600000
  const int* src = ei;
  const int* dst = ei + E;

  // workspace layout (512B aligned blocks)
  char* wsb = (char*)d_ws;
  size_t off = 0;
  auto alloc = [&](size_t bytes) -> void* {
    void* p = wsb + off;
    off += (bytes + 511) & ~(size_t)511;
    return p;
  };
  int* rs       = (int*)alloc((size_t)(N + 1) * 4);
  int* csr_src  = (int*)alloc((size_t)E * 4);
  int* bcnt     = (int*)alloc(NBUCK * 4);
  int* bbase    = (int*)alloc(NBUCK * 4);
  int* bcur     = (int*)alloc(NBUCK * 4);
  unsigned int* staging = (unsigned int*)alloc((size_t)E * 4);
  unsigned short* W1t = (unsigned short*)alloc(256 * 256 * 2);
  unsigned short* W2t = (unsigned short*)alloc(128 * 256 * 2);
  unsigned short* A1  = (unsigned short*)alloc((size_t)N * 256 * 2);
  unsigned short* zr  = (unsigned short*)alloc((size_t)N * 128 * 2);
  (void)ws_size; (void)n_in; (void)out_size;

  const int nbuckReal = (N + 1023) / 1024;            // 98
  const int nchunks = (E + BIN_CHUNK - 1) / BIN_CHUNK; // 196

  hipMemsetAsync(bcnt, 0, NBUCK * 4, stream);
  bhist<<<256, 256, 0, stream>>>(dst, bcnt, E);
  bscan<<<1, 128, 0, stream>>>(bcnt, bbase, bcur, rs, N, E);
  binscatter<<<nchunks, 256, 0, stream>>>(src, dst, bcur, staging, E);
  bucketfinal<<<nbuckReal, 256, 0, stream>>>(staging, bbase, bcnt, rs, csr_src, N);

  convw<<<(256 * 256 + 128 * 256 + 255) / 256, 256, 0, stream>>>(W1l, W1r, W2l, W2r, W1t, W2t);
  convx<<<(N * 32 + 255) / 256, 256, 0, stream>>>(x, A1, N);

  agg1_kernel<<<(N + 3) / 4, 256, 0, stream>>>(csr_src, rs, A1, N);

  gemm_fused<<<(N + 127) / 128, 256, 0, stream>>>(A1, W1t, W2t, b1, zr, N);

  agg2_final<<<(N + 3) / 4, 256, 0, stream>>>(zr, csr_src, rs, b2, out, N);
}

// Round 5
// 362.457 us; speedup vs baseline: 1.9742x; 1.0470x over previous
//
#include <hip/hip_runtime.h>

// ---------- helpers ----------
typedef __attribute__((ext_vector_type(8))) short short8;   // 8 x bf16 fragment (4 VGPRs)
typedef __attribute__((ext_vector_type(4))) float floatx4;  // MFMA accumulator
typedef __attribute__((ext_vector_type(2))) float floatx2;

static __device__ __forceinline__ unsigned short f2bf(float f) {
  unsigned int u = __builtin_bit_cast(unsigned int, f);
  u += 0x7FFFu + ((u >> 16) & 1u);   // RNE (finite inputs only)
  return (unsigned short)(u >> 16);
}
static __device__ __forceinline__ float bf2f(unsigned short s) {
  unsigned int u = ((unsigned int)s) << 16;
  return __builtin_bit_cast(float, u);
}
// fp8 e4m3 (OCP on gfx950) via HW cvt — encode/decode both on-device, self-consistent
static __device__ __forceinline__ unsigned int pk4_fp8(float a, float b, float c, float d) {
  int lo = __builtin_amdgcn_cvt_pk_fp8_f32(a, b, 0, false);
  int hi = __builtin_amdgcn_cvt_pk_fp8_f32(c, d, 0, false);
  return (unsigned int)((lo & 0xffff) | ((hi & 0xffff) << 16));
}
static __device__ __forceinline__ floatx4 unpk4_fp8(unsigned int p) {
  floatx2 lo = __builtin_amdgcn_cvt_pk_f32_fp8((int)p, false);
  floatx2 hi = __builtin_amdgcn_cvt_pk_f32_fp8((int)p, true);
  floatx4 r = {lo.x, lo.y, hi.x, hi.y};
  return r;
}

#define NBUCK 128        // padded bucket count; real buckets = ceil(N/1024) = 98
#define BIN_CHUNK 8192   // edges per binscatter workgroup

// ---------- CSR build via two-level binning (avoids 16x write amplification) ----------

__global__ __launch_bounds__(256) void bhist(const int* __restrict__ dst,
                                             int* __restrict__ bcnt, int E) {
  __shared__ int h[NBUCK];
  for (int i = threadIdx.x; i < NBUCK; i += 256) h[i] = 0;
  __syncthreads();
  int stride = gridDim.x * 256;
  for (int i = blockIdx.x * 256 + threadIdx.x; i < E; i += stride)
    atomicAdd(&h[dst[i] >> 10], 1);
  __syncthreads();
  for (int i = threadIdx.x; i < NBUCK; i += 256)
    if (h[i]) atomicAdd(&bcnt[i], h[i]);
}

__global__ __launch_bounds__(128) void bscan(const int* __restrict__ bcnt,
                                             int* __restrict__ bbase,
                                             int* __restrict__ bcur,
                                             int* __restrict__ rs, int N, int E) {
  __shared__ int s[NBUCK];
  int t = threadIdx.x;
  int v = bcnt[t];
  s[t] = v;
  __syncthreads();
  for (int off = 1; off < NBUCK; off <<= 1) {
    int x = (t >= off) ? s[t - off] : 0;
    __syncthreads();
    s[t] += x;
    __syncthreads();
  }
  int excl = s[t] - v;
  bbase[t] = excl;
  bcur[t] = excl;
  if (t == 0) rs[N] = E;
}

__global__ __launch_bounds__(256) void binscatter(const int* __restrict__ src,
                                                  const int* __restrict__ dst,
                                                  int* __restrict__ bcur,
                                                  unsigned int* __restrict__ staging,
                                                  int E) {
  __shared__ int h[NBUCK];
  __shared__ int cur[NBUCK];
  for (int i = threadIdx.x; i < NBUCK; i += 256) h[i] = 0;
  __syncthreads();
  int base = blockIdx.x * BIN_CHUNK;
  int end = base + BIN_CHUNK; if (end > E) end = E;
  for (int i = base + threadIdx.x; i < end; i += 256)
    atomicAdd(&h[dst[i] >> 10], 1);
  __syncthreads();
  for (int i = threadIdx.x; i < NBUCK; i += 256)
    cur[i] = h[i] ? atomicAdd(&bcur[i], h[i]) : 0;
  __syncthreads();
  for (int i = base + threadIdx.x; i < end; i += 256) {
    int d = dst[i], s = src[i];
    int b = d >> 10;
    int pos = atomicAdd(&cur[b], 1);
    staging[pos] = ((unsigned int)(d & 1023) << 17) | (unsigned int)s;
  }
}

__global__ __launch_bounds__(256) void bucketfinal(const unsigned int* __restrict__ staging,
                                                   const int* __restrict__ bbase,
                                                   const int* __restrict__ bcnt,
                                                   int* __restrict__ rs,
                                                   int* __restrict__ csr_src, int N) {
  int b = blockIdx.x;
  int base = bbase[b], cnt = bcnt[b];
  __shared__ int h[1024];
  __shared__ int ps[256];
  __shared__ int cur[1024];
  int t = threadIdx.x;
  for (int i = t; i < 1024; i += 256) h[i] = 0;
  __syncthreads();
  for (int i = t; i < cnt; i += 256)
    atomicAdd(&h[staging[base + i] >> 17], 1);
  __syncthreads();
  int a0 = h[4 * t], a1 = h[4 * t + 1], a2 = h[4 * t + 2], a3 = h[4 * t + 3];
  int tsum = a0 + a1 + a2 + a3;
  ps[t] = tsum;
  __syncthreads();
  for (int off = 1; off < 256; off <<= 1) {
    int x = (t >= off) ? ps[t - off] : 0;
    __syncthreads();
    ps[t] += x;
    __syncthreads();
  }
  int run = base + ps[t] - tsum;
  int node0 = b << 10;
  int va[4] = {a0, a1, a2, a3};
#pragma unroll
  for (int j = 0; j < 4; j++) {
    int w = node0 + 4 * t + j;
    cur[4 * t + j] = run;
    if (w < N) rs[w] = run;
    run += va[j];
  }
  __syncthreads();
  for (int i = t; i < cnt; i += 256) {
    unsigned int v = staging[base + i];
    int pos = atomicAdd(&cur[v >> 17], 1);
    csr_src[pos] = (int)(v & 0x1FFFFu);
  }
}

// ---------- weight conversion (merged) ----------
__global__ void convw(const float* __restrict__ W1l, const float* __restrict__ W1r,
                      const float* __restrict__ W2l, const float* __restrict__ W2r,
                      unsigned short* __restrict__ W1t, unsigned short* __restrict__ W2t) {
  int i = blockIdx.x * blockDim.x + threadIdx.x;
  if (i < 256 * 256) {
    int n = i >> 8, k = i & 255;
    float v = (k < 128) ? W1l[k * 256 + n] : W1r[(k - 128) * 256 + n];
    W1t[i] = f2bf(v);
  } else if (i < 256 * 256 + 128 * 256) {
    int j = i - 256 * 256;
    int n = j >> 8, k = j & 255;
    float v = (n < 64) ? W2l[k * 64 + n] : W2r[k * 64 + (n - 64)];
    W2t[j] = f2bf(v);
  }
}

// x (fp32, [N][128]) -> bf16 right half of A1 (self path) + fp8 xq (gather path)
__global__ void convx(const float* __restrict__ x, unsigned short* __restrict__ A1,
                      unsigned int* __restrict__ xq, int n_nodes) {
  int i = blockIdx.x * blockDim.x + threadIdx.x;
  if (i < n_nodes * 32) {
    int node = i >> 5, c4 = (i & 31) * 4;
    float4 v = *reinterpret_cast<const float4*>(x + (size_t)node * 128 + c4);
    unsigned short r[4] = { f2bf(v.x), f2bf(v.y), f2bf(v.z), f2bf(v.w) };
    *reinterpret_cast<uint2*>(A1 + (size_t)node * 256 + 128 + c4) =
        *reinterpret_cast<uint2*>(r);
    xq[node * 32 + (i & 31)] = pk4_fp8(v.x, v.y, v.z, v.w);
  }
}

// ---------- layer-1 aggregation: one wave per node, 2 edges/wave-iter ----------
// lanes 0-31 handle even edges, 32-63 odd; each lane covers 4 fp8 channels (uint load).
__global__ __launch_bounds__(256) void agg1_kernel(const int* __restrict__ csr_src,
                                                   const int* __restrict__ rs,
                                                   const unsigned int* __restrict__ xq,
                                                   unsigned short* __restrict__ A1,
                                                   int n_nodes) {
  int w = blockIdx.x * 4 + (threadIdx.x >> 6);
  if (w >= n_nodes) return;
  int lane = threadIdx.x & 63;
  int half = lane >> 5;         // 0/1: which edge of the pair
  int ch4 = lane & 31;          // channel quad (4 fp8 = 1 uint)
  int e0 = rs[w], e1 = rs[w + 1];
  floatx4 a0 = {0.f, 0.f, 0.f, 0.f}, a1 = {0.f, 0.f, 0.f, 0.f};
  int e = e0 + half;
  // 2-deep unroll over the wave's pair-stride (up to 4 edges in flight per wave)
  for (; e + 2 < e1; e += 4) {
    int s0 = csr_src[e], s1 = csr_src[e + 2];
    unsigned int p0 = xq[(size_t)s0 * 32 + ch4];
    unsigned int p1 = xq[(size_t)s1 * 32 + ch4];
    floatx4 v0 = unpk4_fp8(p0), v1 = unpk4_fp8(p1);
    a0.x += v0.x; a0.y += v0.y; a0.z += v0.z; a0.w += v0.w;
    a1.x += v1.x; a1.y += v1.y; a1.z += v1.z; a1.w += v1.w;
  }
  for (; e < e1; e += 2) {
    int s = csr_src[e];
    floatx4 v = unpk4_fp8(xq[(size_t)s * 32 + ch4]);
    a0.x += v.x; a0.y += v.y; a0.z += v.z; a0.w += v.w;
  }
  floatx4 acc = {a0.x + a1.x, a0.y + a1.y, a0.z + a1.z, a0.w + a1.w};
  // merge the two halves (lane ^ 32 holds the other edge-parity partial)
  acc.x += __shfl_xor(acc.x, 32);
  acc.y += __shfl_xor(acc.y, 32);
  acc.z += __shfl_xor(acc.z, 32);
  acc.w += __shfl_xor(acc.w, 32);
  if (half == 0) {
    int d = e1 - e0; if (d < 1) d = 1;
    float sc = 1.0f / (float)d;
    unsigned short r[4] = { f2bf(acc.x * sc), f2bf(acc.y * sc),
                            f2bf(acc.z * sc), f2bf(acc.w * sc) };
    *reinterpret_cast<uint2*>(A1 + (size_t)w * 256 + ch4 * 4) =
        *reinterpret_cast<uint2*>(r);
  }
}

// ---------- fused MLP: h = relu(A1@W1+b1); z=h@W2l -> fp8 zq; r=h@W2r -> bf16 rb ----------
#define LDSW 264   // padded row stride in shorts (528 B)
__global__ __launch_bounds__(256, 2) void gemm_fused(const unsigned short* __restrict__ A1,
                                                     const unsigned short* __restrict__ W1t,
                                                     const unsigned short* __restrict__ W2t,
                                                     const float* __restrict__ b1,
                                                     unsigned char* __restrict__ zq,
                                                     unsigned short* __restrict__ rb,
                                                     int M) {
  __shared__ unsigned short smem[128 * LDSW];   // 67584 B -> 2 blocks/CU
  const int tid = threadIdx.x;
  const int lane = tid & 63;
  const int wave = tid >> 6;
  const int m0 = blockIdx.x * 128;
  const int fm = lane & 15;
  const int fq = lane >> 4;
  const int wr = (wave >> 1) * 64;   // wave's row range
  const int wc1 = (wave & 1) * 128;  // gemm1 col range (h cols)
  const int wc2 = (wave & 1) * 64;   // gemm2 col range (z|r cols)

  // ---- stage A1 tile 128x256 bf16 into padded LDS ----
#pragma unroll
  for (int j = 0; j < 16; j++) {
    int c = j * 256 + tid;
    int row = c >> 5, ch = c & 31;
    int gr = m0 + row; if (gr >= M) gr = M - 1;
    int4 v = *reinterpret_cast<const int4*>(A1 + (size_t)gr * 256 + ch * 8);
    *reinterpret_cast<int4*>(&smem[row * LDSW + ch * 8]) = v;
  }

  float bb[8];
#pragma unroll
  for (int ni = 0; ni < 8; ni++) bb[ni] = b1[wc1 + ni * 16 + fm];

  __syncthreads();

  // ---- gemm1: h(128x256) = A1_tile @ W1t^T (B streamed from L2) ----
  floatx4 acc1[4][8] = {};
#pragma unroll 2
  for (int kk = 0; kk < 8; kk++) {
    short8 af[4], bfr[8];
#pragma unroll
    for (int mi = 0; mi < 4; mi++)
      af[mi] = *reinterpret_cast<const short8*>(
          &smem[(wr + mi * 16 + fm) * LDSW + kk * 32 + fq * 8]);
#pragma unroll
    for (int ni = 0; ni < 8; ni++)
      bfr[ni] = *reinterpret_cast<const short8*>(
          W1t + (size_t)(wc1 + ni * 16 + fm) * 256 + kk * 32 + fq * 8);
#pragma unroll
    for (int mi = 0; mi < 4; mi++)
#pragma unroll
      for (int ni = 0; ni < 8; ni++)
        acc1[mi][ni] = __builtin_amdgcn_mfma_f32_16x16x32_bf16(af[mi], bfr[ni],
                                                               acc1[mi][ni], 0, 0, 0);
  }

  __syncthreads();   // all A-tile reads complete before overwrite

  // ---- bias + relu -> bf16 h tile into same LDS region ----
#pragma unroll
  for (int mi = 0; mi < 4; mi++)
#pragma unroll
    for (int ni = 0; ni < 8; ni++)
#pragma unroll
      for (int r = 0; r < 4; r++) {
        float v = acc1[mi][ni][r] + bb[ni];
        v = v > 0.f ? v : 0.f;
        smem[(wr + mi * 16 + fq * 4 + r) * LDSW + wc1 + ni * 16 + fm] = f2bf(v);
      }
  __syncthreads();

  // ---- gemm2: (128x128) = h_tile @ W2t^T ----
  floatx4 acc2[4][4] = {};
#pragma unroll 2
  for (int kk = 0; kk < 8; kk++) {
    short8 hf[4], wf[4];
#pragma unroll
    for (int mi = 0; mi < 4; mi++)
      hf[mi] = *reinterpret_cast<const short8*>(
          &smem[(wr + mi * 16 + fm) * LDSW + kk * 32 + fq * 8]);
#pragma unroll
    for (int ni = 0; ni < 4; ni++)
      wf[ni] = *reinterpret_cast<const short8*>(
          W2t + (size_t)(wc2 + ni * 16 + fm) * 256 + kk * 32 + fq * 8);
#pragma unroll
    for (int mi = 0; mi < 4; mi++)
#pragma unroll
      for (int ni = 0; ni < 4; ni++)
        acc2[mi][ni] = __builtin_amdgcn_mfma_f32_16x16x32_bf16(hf[mi], wf[ni],
                                                               acc2[mi][ni], 0, 0, 0);
  }

  // ---- store: cols 0-63 -> fp8 zq (gathered many times); cols 64-127 -> bf16 rb ----
#pragma unroll
  for (int mi = 0; mi < 4; mi++)
#pragma unroll
    for (int ni = 0; ni < 4; ni++)
#pragma unroll
      for (int r = 0; r < 4; r++) {
        int grow = m0 + wr + mi * 16 + fq * 4 + r;
        if (grow < M) {
          float v = acc2[mi][ni][r];
          int col = ni * 16 + fm;
          if ((wave & 1) == 0) {
            int b8 = __builtin_amdgcn_cvt_pk_fp8_f32(v, v, 0, false);
            zq[(size_t)grow * 64 + col] = (unsigned char)(b8 & 0xff);
          } else {
            rb[(size_t)grow * 64 + col] = f2bf(v);
          }
        }
      }
}

// ---------- layer-2 aggregation + epilogue: one wave per node, 4 edges/wave-iter ----------
// lane group (lane>>4) = edge slot, ch quad = lane&15 (4 fp8 channels of 64).
__global__ __launch_bounds__(256) void agg2_final(const unsigned int* __restrict__ zq,
                                                  const unsigned short* __restrict__ rb,
                                                  const int* __restrict__ csr_src,
                                                  const int* __restrict__ rs,
                                                  const float* __restrict__ b2,
                                                  float* __restrict__ out, int n_nodes) {
  int w = blockIdx.x * 4 + (threadIdx.x >> 6);
  if (w >= n_nodes) return;
  int lane = threadIdx.x & 63;
  int grp = lane >> 4;
  int ch4 = lane & 15;
  int e0 = rs[w], e1 = rs[w + 1];
  floatx4 a0 = {0.f, 0.f, 0.f, 0.f}, a1 = {0.f, 0.f, 0.f, 0.f};
  int e = e0 + grp;
  for (; e + 4 < e1; e += 8) {
    int s0 = csr_src[e], s1 = csr_src[e + 4];
    floatx4 v0 = unpk4_fp8(zq[(size_t)s0 * 16 + ch4]);
    floatx4 v1 = unpk4_fp8(zq[(size_t)s1 * 16 + ch4]);
    a0.x += v0.x; a0.y += v0.y; a0.z += v0.z; a0.w += v0.w;
    a1.x += v1.x; a1.y += v1.y; a1.z += v1.z; a1.w += v1.w;
  }
  for (; e < e1; e += 4) {
    floatx4 v = unpk4_fp8(zq[(size_t)csr_src[e] * 16 + ch4]);
    a0.x += v.x; a0.y += v.y; a0.z += v.z; a0.w += v.w;
  }
  floatx4 acc = {a0.x + a1.x, a0.y + a1.y, a0.z + a1.z, a0.w + a1.w};
  // reduce the 4 edge slots (xor 16 then 32 leaves every lane with the total)
  acc.x += __shfl_xor(acc.x, 16); acc.y += __shfl_xor(acc.y, 16);
  acc.z += __shfl_xor(acc.z, 16); acc.w += __shfl_xor(acc.w, 16);
  acc.x += __shfl_xor(acc.x, 32); acc.y += __shfl_xor(acc.y, 32);
  acc.z += __shfl_xor(acc.z, 32); acc.w += __shfl_xor(acc.w, 32);
  if (grp == 0) {
    int d = e1 - e0; if (d < 1) d = 1;
    float sc = 1.0f / (float)d;
    uint2 rr = *reinterpret_cast<const uint2*>(rb + (size_t)w * 64 + ch4 * 4);
    float4 bv = *reinterpret_cast<const float4*>(b2 + ch4 * 4);
    float r0 = bf2f((unsigned short)(rr.x & 0xffff));
    float r1 = bf2f((unsigned short)(rr.x >> 16));
    float r2 = bf2f((unsigned short)(rr.y & 0xffff));
    float r3 = bf2f((unsigned short)(rr.y >> 16));
    float4 o;
    o.x = 1.0f / (1.0f + __expf(-(acc.x * sc + r0 + bv.x)));
    o.y = 1.0f / (1.0f + __expf(-(acc.y * sc + r1 + bv.y)));
    o.z = 1.0f / (1.0f + __expf(-(acc.z * sc + r2 + bv.z)));
    o.w = 1.0f / (1.0f + __expf(-(acc.w * sc + r3 + bv.w)));
    *reinterpret_cast<float4*>(out + (size_t)w * 64 + ch4 * 4) = o;
  }
}

// ---------- launch ----------
extern "C" void kernel_launch(void* const* d_in, const int* in_sizes, int n_in,
                              void* d_out, int out_size, void* d_ws, size_t ws_size,
                              hipStream_t stream) {
  const float* x   = (const float*)d_in[0];
  const int*   ei  = (const int*)d_in[1];
  const float* W1l = (const float*)d_in[2];
  const float* W1r = (const float*)d_in[3];
  const float* b1  = (const float*)d_in[4];
  const float* W2l = (const float*)d_in[5];
  const float* W2r = (const float*)d_in[6];
  const float* b2  = (const float*)d_in[7];
  float* out = (float*)d_out;

  const int N = in_sizes[0] / 128;     // 100000
  const int E = in_sizes[1] / 2;       // 1600000
  const int* src = ei;
  const int* dst = ei + E;

  // workspace layout (512B aligned blocks)
  char* wsb = (char*)d_ws;
  size_t off = 0;
  auto alloc = [&](size_t bytes) -> void* {
    void* p = wsb + off;
    off += (bytes + 511) & ~(size_t)511;
    return p;
  };
  int* rs       = (int*)alloc((size_t)(N + 1) * 4);
  int* csr_src  = (int*)alloc((size_t)E * 4 + 64);   // +64: 2-edge stride may probe 1 past
  int* bcnt     = (int*)alloc(NBUCK * 4);
  int* bbase    = (int*)alloc(NBUCK * 4);
  int* bcur     = (int*)alloc(NBUCK * 4);
  unsigned int* staging = (unsigned int*)alloc((size_t)E * 4);
  unsigned short* W1t = (unsigned short*)alloc(256 * 256 * 2);
  unsigned short* W2t = (unsigned short*)alloc(128 * 256 * 2);
  unsigned short* A1  = (unsigned short*)alloc((size_t)N * 256 * 2);
  unsigned int* xq    = (unsigned int*)alloc((size_t)N * 128);      // fp8 x, 128 B/row
  unsigned char* zq   = (unsigned char*)alloc((size_t)N * 64);      // fp8 z, 64 B/row
  unsigned short* rb  = (unsigned short*)alloc((size_t)N * 64 * 2); // bf16 r
  (void)ws_size; (void)n_in; (void)out_size;

  const int nbuckReal = (N + 1023) / 1024;             // 98
  const int nchunks = (E + BIN_CHUNK - 1) / BIN_CHUNK; // 196

  hipMemsetAsync(bcnt, 0, NBUCK * 4, stream);
  bhist<<<256, 256, 0, stream>>>(dst, bcnt, E);
  bscan<<<1, 128, 0, stream>>>(bcnt, bbase, bcur, rs, N, E);
  binscatter<<<nchunks, 256, 0, stream>>>(src, dst, bcur, staging, E);
  bucketfinal<<<nbuckReal, 256, 0, stream>>>(staging, bbase, bcnt, rs, csr_src, N);

  convw<<<(256 * 256 + 128 * 256 + 255) / 256, 256, 0, stream>>>(W1l, W1r, W2l, W2r, W1t, W2t);
  convx<<<(N * 32 + 255) / 256, 256, 0, stream>>>(x, A1, xq, N);

  agg1_kernel<<<(N + 3) / 4, 256, 0, stream>>>(csr_src, rs, xq, A1, N);

  gemm_fused<<<(N + 127) / 128, 256, 0, stream>>>(A1, W1t, W2t, b1, zq, rb, N);

  agg2_final<<<(N + 3) / 4, 256, 0, stream>>>((const unsigned int*)zq, rb, csr_src, rs, b2, out, N);
}

// Round 6
// 344.493 us; speedup vs baseline: 2.0771x; 1.0521x over previous
//
#include <hip/hip_runtime.h>

// ---------- helpers ----------
typedef __attribute__((ext_vector_type(8))) short short8;   // 8 x bf16 fragment (4 VGPRs)
typedef __attribute__((ext_vector_type(4))) float floatx4;  // MFMA accumulator
typedef __attribute__((ext_vector_type(2))) float floatx2;

static __device__ __forceinline__ unsigned short f2bf(float f) {
  unsigned int u = __builtin_bit_cast(unsigned int, f);
  u += 0x7FFFu + ((u >> 16) & 1u);   // RNE (finite inputs only)
  return (unsigned short)(u >> 16);
}
static __device__ __forceinline__ float bf2f(unsigned short s) {
  unsigned int u = ((unsigned int)s) << 16;
  return __builtin_bit_cast(float, u);
}
// fp8 e4m3 (OCP on gfx950) via HW cvt — encode/decode both on-device, self-consistent
static __device__ __forceinline__ unsigned int pk4_fp8(float a, float b, float c, float d) {
  int lo = __builtin_amdgcn_cvt_pk_fp8_f32(a, b, 0, false);
  int hi = __builtin_amdgcn_cvt_pk_fp8_f32(c, d, 0, false);
  return (unsigned int)((lo & 0xffff) | ((hi & 0xffff) << 16));
}
static __device__ __forceinline__ floatx4 unpk4_fp8(unsigned int p) {
  floatx2 lo = __builtin_amdgcn_cvt_pk_f32_fp8((int)p, false);
  floatx2 hi = __builtin_amdgcn_cvt_pk_f32_fp8((int)p, true);
  floatx4 r = {lo.x, lo.y, hi.x, hi.y};
  return r;
}

#define NBUCK 128        // padded bucket count; real buckets = ceil(N/1024) = 98
#define BIN_CHUNK 8192   // edges per binscatter workgroup

// ---------- CSR build via two-level binning (avoids 16x write amplification) ----------

__global__ __launch_bounds__(256) void bhist(const int* __restrict__ dst,
                                             int* __restrict__ bcnt, int E) {
  __shared__ int h[NBUCK];
  for (int i = threadIdx.x; i < NBUCK; i += 256) h[i] = 0;
  __syncthreads();
  int stride = gridDim.x * 256;
  for (int i = blockIdx.x * 256 + threadIdx.x; i < E; i += stride)
    atomicAdd(&h[dst[i] >> 10], 1);
  __syncthreads();
  for (int i = threadIdx.x; i < NBUCK; i += 256)
    if (h[i]) atomicAdd(&bcnt[i], h[i]);
}

__global__ __launch_bounds__(128) void bscan(const int* __restrict__ bcnt,
                                             int* __restrict__ bbase,
                                             int* __restrict__ bcur,
                                             int* __restrict__ rs, int N, int E) {
  __shared__ int s[NBUCK];
  int t = threadIdx.x;
  int v = bcnt[t];
  s[t] = v;
  __syncthreads();
  for (int off = 1; off < NBUCK; off <<= 1) {
    int x = (t >= off) ? s[t - off] : 0;
    __syncthreads();
    s[t] += x;
    __syncthreads();
  }
  int excl = s[t] - v;
  bbase[t] = excl;
  bcur[t] = excl;
  if (t == 0) rs[N] = E;
}

__global__ __launch_bounds__(256) void binscatter(const int* __restrict__ src,
                                                  const int* __restrict__ dst,
                                                  int* __restrict__ bcur,
                                                  unsigned int* __restrict__ staging,
                                                  int E) {
  __shared__ int h[NBUCK];
  __shared__ int cur[NBUCK];
  for (int i = threadIdx.x; i < NBUCK; i += 256) h[i] = 0;
  __syncthreads();
  int base = blockIdx.x * BIN_CHUNK;
  int end = base + BIN_CHUNK; if (end > E) end = E;
  for (int i = base + threadIdx.x; i < end; i += 256)
    atomicAdd(&h[dst[i] >> 10], 1);
  __syncthreads();
  for (int i = threadIdx.x; i < NBUCK; i += 256)
    cur[i] = h[i] ? atomicAdd(&bcur[i], h[i]) : 0;
  __syncthreads();
  for (int i = base + threadIdx.x; i < end; i += 256) {
    int d = dst[i], s = src[i];
    int b = d >> 10;
    int pos = atomicAdd(&cur[b], 1);
    staging[pos] = ((unsigned int)(d & 1023) << 17) | (unsigned int)s;
  }
}

__global__ __launch_bounds__(256) void bucketfinal(const unsigned int* __restrict__ staging,
                                                   const int* __restrict__ bbase,
                                                   const int* __restrict__ bcnt,
                                                   int* __restrict__ rs,
                                                   int* __restrict__ csr_src, int N) {
  int b = blockIdx.x;
  int base = bbase[b], cnt = bcnt[b];
  __shared__ int h[1024];
  __shared__ int ps[256];
  __shared__ int cur[1024];
  int t = threadIdx.x;
  for (int i = t; i < 1024; i += 256) h[i] = 0;
  __syncthreads();
  for (int i = t; i < cnt; i += 256)
    atomicAdd(&h[staging[base + i] >> 17], 1);
  __syncthreads();
  int a0 = h[4 * t], a1 = h[4 * t + 1], a2 = h[4 * t + 2], a3 = h[4 * t + 3];
  int tsum = a0 + a1 + a2 + a3;
  ps[t] = tsum;
  __syncthreads();
  for (int off = 1; off < 256; off <<= 1) {
    int x = (t >= off) ? ps[t - off] : 0;
    __syncthreads();
    ps[t] += x;
    __syncthreads();
  }
  int run = base + ps[t] - tsum;
  int node0 = b << 10;
  int va[4] = {a0, a1, a2, a3};
#pragma unroll
  for (int j = 0; j < 4; j++) {
    int w = node0 + 4 * t + j;
    cur[4 * t + j] = run;
    if (w < N) rs[w] = run;
    run += va[j];
  }
  __syncthreads();
  for (int i = t; i < cnt; i += 256) {
    unsigned int v = staging[base + i];
    int pos = atomicAdd(&cur[v >> 17], 1);
    csr_src[pos] = (int)(v & 0x1FFFFu);
  }
}

// ---------- weight conversion (merged) ----------
__global__ void convw(const float* __restrict__ W1l, const float* __restrict__ W1r,
                      const float* __restrict__ W2l, const float* __restrict__ W2r,
                      unsigned short* __restrict__ W1t, unsigned short* __restrict__ W2t) {
  int i = blockIdx.x * blockDim.x + threadIdx.x;
  if (i < 256 * 256) {
    int n = i >> 8, k = i & 255;
    float v = (k < 128) ? W1l[k * 256 + n] : W1r[(k - 128) * 256 + n];
    W1t[i] = f2bf(v);
  } else if (i < 256 * 256 + 128 * 256) {
    int j = i - 256 * 256;
    int n = j >> 8, k = j & 255;
    float v = (n < 64) ? W2l[k * 64 + n] : W2r[k * 64 + (n - 64)];
    W2t[j] = f2bf(v);
  }
}

// x (fp32, [N][128]) -> bf16 right half of A1 (self path) + fp8 xq (gather path)
__global__ void convx(const float* __restrict__ x, unsigned short* __restrict__ A1,
                      unsigned int* __restrict__ xq, int n_nodes) {
  int i = blockIdx.x * blockDim.x + threadIdx.x;
  if (i < n_nodes * 32) {
    int node = i >> 5, c4 = (i & 31) * 4;
    float4 v = *reinterpret_cast<const float4*>(x + (size_t)node * 128 + c4);
    unsigned short r[4] = { f2bf(v.x), f2bf(v.y), f2bf(v.z), f2bf(v.w) };
    *reinterpret_cast<uint2*>(A1 + (size_t)node * 256 + 128 + c4) =
        *reinterpret_cast<uint2*>(r);
    xq[node * 32 + (i & 31)] = pk4_fp8(v.x, v.y, v.z, v.w);
  }
}

// ---------- layer-1 aggregation: one wave per node, 2 edges/wave-iter ----------
__global__ __launch_bounds__(256) void agg1_kernel(const int* __restrict__ csr_src,
                                                   const int* __restrict__ rs,
                                                   const unsigned int* __restrict__ xq,
                                                   unsigned short* __restrict__ A1,
                                                   int n_nodes) {
  int w = blockIdx.x * 4 + (threadIdx.x >> 6);
  if (w >= n_nodes) return;
  int lane = threadIdx.x & 63;
  int half = lane >> 5;         // 0/1: which edge of the pair
  int ch4 = lane & 31;          // channel quad (4 fp8 = 1 uint)
  int e0 = rs[w], e1 = rs[w + 1];
  floatx4 a0 = {0.f, 0.f, 0.f, 0.f}, a1 = {0.f, 0.f, 0.f, 0.f};
  int e = e0 + half;
  for (; e + 2 < e1; e += 4) {
    int s0 = csr_src[e], s1 = csr_src[e + 2];
    unsigned int p0 = xq[(size_t)s0 * 32 + ch4];
    unsigned int p1 = xq[(size_t)s1 * 32 + ch4];
    floatx4 v0 = unpk4_fp8(p0), v1 = unpk4_fp8(p1);
    a0.x += v0.x; a0.y += v0.y; a0.z += v0.z; a0.w += v0.w;
    a1.x += v1.x; a1.y += v1.y; a1.z += v1.z; a1.w += v1.w;
  }
  for (; e < e1; e += 2) {
    int s = csr_src[e];
    floatx4 v = unpk4_fp8(xq[(size_t)s * 32 + ch4]);
    a0.x += v.x; a0.y += v.y; a0.z += v.z; a0.w += v.w;
  }
  floatx4 acc = {a0.x + a1.x, a0.y + a1.y, a0.z + a1.z, a0.w + a1.w};
  acc.x += __shfl_xor(acc.x, 32);
  acc.y += __shfl_xor(acc.y, 32);
  acc.z += __shfl_xor(acc.z, 32);
  acc.w += __shfl_xor(acc.w, 32);
  if (half == 0) {
    int d = e1 - e0; if (d < 1) d = 1;
    float sc = 1.0f / (float)d;
    unsigned short r[4] = { f2bf(acc.x * sc), f2bf(acc.y * sc),
                            f2bf(acc.z * sc), f2bf(acc.w * sc) };
    *reinterpret_cast<uint2*>(A1 + (size_t)w * 256 + ch4 * 4) =
        *reinterpret_cast<uint2*>(r);
  }
}

// ---------- fused MLP (64-row tiles, 4 blocks/CU) ----------
// h = relu(A1@W1+b1) in LDS; z=h@W2l -> fp8 zq; r=h@W2r -> bf16 rb.
// gemm1: each wave owns all 64 rows x 64 cols (acc1[4][4], B-frags 4/kk -> fits 128 VGPR).
// gemm2: wave owns 32 of 128 cols; waves 0-1 emit fp8 z, 2-3 emit bf16 r.
#define LDSW 264   // padded row stride in shorts (528 B)
__global__ __launch_bounds__(256, 4) void gemm_fused(const unsigned short* __restrict__ A1,
                                                     const unsigned short* __restrict__ W1t,
                                                     const unsigned short* __restrict__ W2t,
                                                     const float* __restrict__ b1,
                                                     unsigned char* __restrict__ zq,
                                                     unsigned short* __restrict__ rb,
                                                     int M) {
  __shared__ unsigned short smem[64 * LDSW];   // 33792 B -> 4 blocks/CU
  const int tid = threadIdx.x;
  const int lane = tid & 63;
  const int wave = tid >> 6;
  const int m0 = blockIdx.x * 64;
  const int fm = lane & 15;
  const int fq = lane >> 4;

  // ---- stage A1 tile 64x256 bf16 into padded LDS (8 int4/thread, coalesced) ----
#pragma unroll
  for (int j = 0; j < 8; j++) {
    int c = j * 256 + tid;
    int row = c >> 5, ch = c & 31;
    int gr = m0 + row; if (gr >= M) gr = M - 1;
    int4 v = *reinterpret_cast<const int4*>(A1 + (size_t)gr * 256 + ch * 8);
    *reinterpret_cast<int4*>(&smem[row * LDSW + ch * 8]) = v;
  }

  float bb[4];
#pragma unroll
  for (int ni = 0; ni < 4; ni++) bb[ni] = b1[wave * 64 + ni * 16 + fm];

  __syncthreads();

  // ---- gemm1: h(64x256) = A1_tile @ W1t^T; wave -> cols [wave*64, wave*64+64) ----
  floatx4 acc1[4][4] = {};
#pragma unroll 2
  for (int kk = 0; kk < 8; kk++) {
    short8 af[4], bfr[4];
#pragma unroll
    for (int mi = 0; mi < 4; mi++)
      af[mi] = *reinterpret_cast<const short8*>(
          &smem[(mi * 16 + fm) * LDSW + kk * 32 + fq * 8]);
#pragma unroll
    for (int ni = 0; ni < 4; ni++)
      bfr[ni] = *reinterpret_cast<const short8*>(
          W1t + (size_t)(wave * 64 + ni * 16 + fm) * 256 + kk * 32 + fq * 8);
#pragma unroll
    for (int mi = 0; mi < 4; mi++)
#pragma unroll
      for (int ni = 0; ni < 4; ni++)
        acc1[mi][ni] = __builtin_amdgcn_mfma_f32_16x16x32_bf16(af[mi], bfr[ni],
                                                               acc1[mi][ni], 0, 0, 0);
  }

  __syncthreads();   // all A-tile reads complete before overwrite

  // ---- bias + relu -> bf16 h tile into same LDS region ----
#pragma unroll
  for (int mi = 0; mi < 4; mi++)
#pragma unroll
    for (int ni = 0; ni < 4; ni++)
#pragma unroll
      for (int r = 0; r < 4; r++) {
        float v = acc1[mi][ni][r] + bb[ni];
        v = v > 0.f ? v : 0.f;
        smem[(mi * 16 + fq * 4 + r) * LDSW + wave * 64 + ni * 16 + fm] = f2bf(v);
      }
  __syncthreads();

  // ---- gemm2: (64x128) = h_tile @ W2t^T; wave -> W2t rows [wave*32, wave*32+32) ----
  floatx4 acc2[4][2] = {};
#pragma unroll 2
  for (int kk = 0; kk < 8; kk++) {
    short8 hf[4], wf[2];
#pragma unroll
    for (int mi = 0; mi < 4; mi++)
      hf[mi] = *reinterpret_cast<const short8*>(
          &smem[(mi * 16 + fm) * LDSW + kk * 32 + fq * 8]);
#pragma unroll
    for (int ni = 0; ni < 2; ni++)
      wf[ni] = *reinterpret_cast<const short8*>(
          W2t + (size_t)(wave * 32 + ni * 16 + fm) * 256 + kk * 32 + fq * 8);
#pragma unroll
    for (int mi = 0; mi < 4; mi++)
#pragma unroll
      for (int ni = 0; ni < 2; ni++)
        acc2[mi][ni] = __builtin_amdgcn_mfma_f32_16x16x32_bf16(hf[mi], wf[ni],
                                                               acc2[mi][ni], 0, 0, 0);
  }

  // ---- store: waves 0-1 -> fp8 zq cols 0..63; waves 2-3 -> bf16 rb cols 0..63 ----
#pragma unroll
  for (int mi = 0; mi < 4; mi++)
#pragma unroll
    for (int ni = 0; ni < 2; ni++)
#pragma unroll
      for (int r = 0; r < 4; r++) {
        int grow = m0 + mi * 16 + fq * 4 + r;
        if (grow < M) {
          float v = acc2[mi][ni][r];
          int col = (wave & 1) * 32 + ni * 16 + fm;
          if (wave < 2) {
            int b8 = __builtin_amdgcn_cvt_pk_fp8_f32(v, v, 0, false);
            zq[(size_t)grow * 64 + col] = (unsigned char)(b8 & 0xff);
          } else {
            rb[(size_t)grow * 64 + col] = f2bf(v);
          }
        }
      }
}

// ---------- layer-2 aggregation + epilogue: one wave per node, 4 edges/wave-iter ----------
__global__ __launch_bounds__(256) void agg2_final(const unsigned int* __restrict__ zq,
                                                  const unsigned short* __restrict__ rb,
                                                  const int* __restrict__ csr_src,
                                                  const int* __restrict__ rs,
                                                  const float* __restrict__ b2,
                                                  float* __restrict__ out, int n_nodes) {
  int w = blockIdx.x * 4 + (threadIdx.x >> 6);
  if (w >= n_nodes) return;
  int lane = threadIdx.x & 63;
  int grp = lane >> 4;
  int ch4 = lane & 15;
  int e0 = rs[w], e1 = rs[w + 1];
  floatx4 a0 = {0.f, 0.f, 0.f, 0.f}, a1 = {0.f, 0.f, 0.f, 0.f};
  int e = e0 + grp;
  for (; e + 4 < e1; e += 8) {
    int s0 = csr_src[e], s1 = csr_src[e + 4];
    floatx4 v0 = unpk4_fp8(zq[(size_t)s0 * 16 + ch4]);
    floatx4 v1 = unpk4_fp8(zq[(size_t)s1 * 16 + ch4]);
    a0.x += v0.x; a0.y += v0.y; a0.z += v0.z; a0.w += v0.w;
    a1.x += v1.x; a1.y += v1.y; a1.z += v1.z; a1.w += v1.w;
  }
  for (; e < e1; e += 4) {
    floatx4 v = unpk4_fp8(zq[(size_t)csr_src[e] * 16 + ch4]);
    a0.x += v.x; a0.y += v.y; a0.z += v.z; a0.w += v.w;
  }
  floatx4 acc = {a0.x + a1.x, a0.y + a1.y, a0.z + a1.z, a0.w + a1.w};
  acc.x += __shfl_xor(acc.x, 16); acc.y += __shfl_xor(acc.y, 16);
  acc.z += __shfl_xor(acc.z, 16); acc.w += __shfl_xor(acc.w, 16);
  acc.x += __shfl_xor(acc.x, 32); acc.y += __shfl_xor(acc.y, 32);
  acc.z += __shfl_xor(acc.z, 32); acc.w += __shfl_xor(acc.w, 32);
  if (grp == 0) {
    int d = e1 - e0; if (d < 1) d = 1;
    float sc = 1.0f / (float)d;
    uint2 rr = *reinterpret_cast<const uint2*>(rb + (size_t)w * 64 + ch4 * 4);
    float4 bv = *reinterpret_cast<const float4*>(b2 + ch4 * 4);
    float r0 = bf2f((unsigned short)(rr.x & 0xffff));
    float r1 = bf2f((unsigned short)(rr.x >> 16));
    float r2 = bf2f((unsigned short)(rr.y & 0xffff));
    float r3 = bf2f((unsigned short)(rr.y >> 16));
    float4 o;
    o.x = 1.0f / (1.0f + __expf(-(acc.x * sc + r0 + bv.x)));
    o.y = 1.0f / (1.0f + __expf(-(acc.y * sc + r1 + bv.y)));
    o.z = 1.0f / (1.0f + __expf(-(acc.z * sc + r2 + bv.z)));
    o.w = 1.0f / (1.0f + __expf(-(acc.w * sc + r3 + bv.w)));
    *reinterpret_cast<float4*>(out + (size_t)w * 64 + ch4 * 4) = o;
  }
}

// ---------- launch ----------
extern "C" void kernel_launch(void* const* d_in, const int* in_sizes, int n_in,
                              void* d_out, int out_size, void* d_ws, size_t ws_size,
                              hipStream_t stream) {
  const float* x   = (const float*)d_in[0];
  const int*   ei  = (const int*)d_in[1];
  const float* W1l = (const float*)d_in[2];
  const float* W1r = (const float*)d_in[3];
  const float* b1  = (const float*)d_in[4];
  const float* W2l = (const float*)d_in[5];
  const float* W2r = (const float*)d_in[6];
  const float* b2  = (const float*)d_in[7];
  float* out = (float*)d_out;

  const int N = in_sizes[0] / 128;     // 100000
  const int E = in_sizes[1] / 2;       // 1600000
  const int* src = ei;
  const int* dst = ei + E;

  // workspace layout (512B aligned blocks)
  char* wsb = (char*)d_ws;
  size_t off = 0;
  auto alloc = [&](size_t bytes) -> void* {
    void* p = wsb + off;
    off += (bytes + 511) & ~(size_t)511;
    return p;
  };
  int* rs       = (int*)alloc((size_t)(N + 1) * 4);
  int* csr_src  = (int*)alloc((size_t)E * 4 + 64);   // +64: strided edge loop may probe past
  int* bcnt     = (int*)alloc(NBUCK * 4);
  int* bbase    = (int*)alloc(NBUCK * 4);
  int* bcur     = (int*)alloc(NBUCK * 4);
  unsigned int* staging = (unsigned int*)alloc((size_t)E * 4);
  unsigned short* W1t = (unsigned short*)alloc(256 * 256 * 2);
  unsigned short* W2t = (unsigned short*)alloc(128 * 256 * 2);
  unsigned short* A1  = (unsigned short*)alloc((size_t)N * 256 * 2);
  unsigned int* xq    = (unsigned int*)alloc((size_t)N * 128);      // fp8 x, 128 B/row
  unsigned char* zq   = (unsigned char*)alloc((size_t)N * 64);      // fp8 z, 64 B/row
  unsigned short* rb  = (unsigned short*)alloc((size_t)N * 64 * 2); // bf16 r
  (void)ws_size; (void)n_in; (void)out_size;

  const int nbuckReal = (N + 1023) / 1024;             // 98
  const int nchunks = (E + BIN_CHUNK - 1) / BIN_CHUNK; // 196

  hipMemsetAsync(bcnt, 0, NBUCK * 4, stream);
  bhist<<<256, 256, 0, stream>>>(dst, bcnt, E);
  bscan<<<1, 128, 0, stream>>>(bcnt, bbase, bcur, rs, N, E);
  binscatter<<<nchunks, 256, 0, stream>>>(src, dst, bcur, staging, E);
  bucketfinal<<<nbuckReal, 256, 0, stream>>>(staging, bbase, bcnt, rs, csr_src, N);

  convw<<<(256 * 256 + 128 * 256 + 255) / 256, 256, 0, stream>>>(W1l, W1r, W2l, W2r, W1t, W2t);
  convx<<<(N * 32 + 255) / 256, 256, 0, stream>>>(x, A1, xq, N);

  agg1_kernel<<<(N + 3) / 4, 256, 0, stream>>>(csr_src, rs, xq, A1, N);

  gemm_fused<<<(N + 63) / 64, 256, 0, stream>>>(A1, W1t, W2t, b1, zq, rb, N);

  agg2_final<<<(N + 3) / 4, 256, 0, stream>>>((const unsigned int*)zq, rb, csr_src, rs, b2, out, N);
}

// Round 7
// 336.228 us; speedup vs baseline: 2.1282x; 1.0246x over previous
//
#include <hip/hip_runtime.h>

// ---------- helpers ----------
typedef __attribute__((ext_vector_type(8))) short short8;   // 8 x bf16 fragment (4 VGPRs)
typedef __attribute__((ext_vector_type(4))) float floatx4;  // MFMA accumulator
typedef __attribute__((ext_vector_type(2))) float floatx2;

static __device__ __forceinline__ unsigned short f2bf(float f) {
  unsigned int u = __builtin_bit_cast(unsigned int, f);
  u += 0x7FFFu + ((u >> 16) & 1u);   // RNE (finite inputs only)
  return (unsigned short)(u >> 16);
}
static __device__ __forceinline__ float bf2f(unsigned short s) {
  unsigned int u = ((unsigned int)s) << 16;
  return __builtin_bit_cast(float, u);
}
// fp8 e4m3 (OCP on gfx950) via HW cvt — encode/decode both on-device, self-consistent
static __device__ __forceinline__ unsigned int pk4_fp8(float a, float b, float c, float d) {
  int lo = __builtin_amdgcn_cvt_pk_fp8_f32(a, b, 0, false);
  int hi = __builtin_amdgcn_cvt_pk_fp8_f32(c, d, 0, false);
  return (unsigned int)((lo & 0xffff) | ((hi & 0xffff) << 16));
}
static __device__ __forceinline__ floatx4 unpk4_fp8(unsigned int p) {
  floatx2 lo = __builtin_amdgcn_cvt_pk_f32_fp8((int)p, false);
  floatx2 hi = __builtin_amdgcn_cvt_pk_f32_fp8((int)p, true);
  floatx4 r = {lo.x, lo.y, hi.x, hi.y};
  return r;
}

#define NBUCK 128        // padded bucket count; real buckets = ceil(N/1024) = 98
#define BIN_CHUNK 8192   // edges per binscatter workgroup

// ---------- CSR build via two-level binning (avoids 16x write amplification) ----------

__global__ __launch_bounds__(256) void bhist(const int* __restrict__ dst,
                                             int* __restrict__ bcnt, int E) {
  __shared__ int h[NBUCK];
  for (int i = threadIdx.x; i < NBUCK; i += 256) h[i] = 0;
  __syncthreads();
  int stride = gridDim.x * 256;
  for (int i = blockIdx.x * 256 + threadIdx.x; i < E; i += stride)
    atomicAdd(&h[dst[i] >> 10], 1);
  __syncthreads();
  for (int i = threadIdx.x; i < NBUCK; i += 256)
    if (h[i]) atomicAdd(&bcnt[i], h[i]);
}

__global__ __launch_bounds__(128) void bscan(const int* __restrict__ bcnt,
                                             int* __restrict__ bbase,
                                             int* __restrict__ bcur,
                                             int* __restrict__ rs, int N, int E) {
  __shared__ int s[NBUCK];
  int t = threadIdx.x;
  int v = bcnt[t];
  s[t] = v;
  __syncthreads();
  for (int off = 1; off < NBUCK; off <<= 1) {
    int x = (t >= off) ? s[t - off] : 0;
    __syncthreads();
    s[t] += x;
    __syncthreads();
  }
  int excl = s[t] - v;
  bbase[t] = excl;
  bcur[t] = excl;
  if (t == 0) rs[N] = E;
}

__global__ __launch_bounds__(256) void binscatter(const int* __restrict__ src,
                                                  const int* __restrict__ dst,
                                                  int* __restrict__ bcur,
                                                  unsigned int* __restrict__ staging,
                                                  int E) {
  __shared__ int h[NBUCK];
  __shared__ int cur[NBUCK];
  for (int i = threadIdx.x; i < NBUCK; i += 256) h[i] = 0;
  __syncthreads();
  int base = blockIdx.x * BIN_CHUNK;
  int end = base + BIN_CHUNK; if (end > E) end = E;
  for (int i = base + threadIdx.x; i < end; i += 256)
    atomicAdd(&h[dst[i] >> 10], 1);
  __syncthreads();
  for (int i = threadIdx.x; i < NBUCK; i += 256)
    cur[i] = h[i] ? atomicAdd(&bcur[i], h[i]) : 0;
  __syncthreads();
  for (int i = base + threadIdx.x; i < end; i += 256) {
    int d = dst[i], s = src[i];
    int b = d >> 10;
    int pos = atomicAdd(&cur[b], 1);
    staging[pos] = ((unsigned int)(d & 1023) << 17) | (unsigned int)s;
  }
}

__global__ __launch_bounds__(256) void bucketfinal(const unsigned int* __restrict__ staging,
                                                   const int* __restrict__ bbase,
                                                   const int* __restrict__ bcnt,
                                                   int* __restrict__ rs,
                                                   int* __restrict__ csr_src, int N) {
  int b = blockIdx.x;
  int base = bbase[b], cnt = bcnt[b];
  __shared__ int h[1024];
  __shared__ int ps[256];
  __shared__ int cur[1024];
  int t = threadIdx.x;
  for (int i = t; i < 1024; i += 256) h[i] = 0;
  __syncthreads();
  for (int i = t; i < cnt; i += 256)
    atomicAdd(&h[staging[base + i] >> 17], 1);
  __syncthreads();
  int a0 = h[4 * t], a1 = h[4 * t + 1], a2 = h[4 * t + 2], a3 = h[4 * t + 3];
  int tsum = a0 + a1 + a2 + a3;
  ps[t] = tsum;
  __syncthreads();
  for (int off = 1; off < 256; off <<= 1) {
    int x = (t >= off) ? ps[t - off] : 0;
    __syncthreads();
    ps[t] += x;
    __syncthreads();
  }
  int run = base + ps[t] - tsum;
  int node0 = b << 10;
  int va[4] = {a0, a1, a2, a3};
#pragma unroll
  for (int j = 0; j < 4; j++) {
    int w = node0 + 4 * t + j;
    cur[4 * t + j] = run;
    if (w < N) rs[w] = run;
    run += va[j];
  }
  __syncthreads();
  for (int i = t; i < cnt; i += 256) {
    unsigned int v = staging[base + i];
    int pos = atomicAdd(&cur[v >> 17], 1);
    csr_src[pos] = (int)(v & 0x1FFFFu);
  }
}

// ---------- weight conversion (merged) ----------
__global__ void convw(const float* __restrict__ W1l, const float* __restrict__ W1r,
                      const float* __restrict__ W2l, const float* __restrict__ W2r,
                      unsigned short* __restrict__ W1t, unsigned short* __restrict__ W2t) {
  int i = blockIdx.x * blockDim.x + threadIdx.x;
  if (i < 256 * 256) {
    int n = i >> 8, k = i & 255;
    float v = (k < 128) ? W1l[k * 256 + n] : W1r[(k - 128) * 256 + n];
    W1t[i] = f2bf(v);
  } else if (i < 256 * 256 + 128 * 256) {
    int j = i - 256 * 256;
    int n = j >> 8, k = j & 255;
    float v = (n < 64) ? W2l[k * 64 + n] : W2r[k * 64 + (n - 64)];
    W2t[j] = f2bf(v);
  }
}

// x (fp32, [N][128]) -> bf16 right half of A1 (self path) + fp8 xq (gather path)
__global__ void convx(const float* __restrict__ x, unsigned short* __restrict__ A1,
                      unsigned int* __restrict__ xq, int n_nodes) {
  int i = blockIdx.x * blockDim.x + threadIdx.x;
  if (i < n_nodes * 32) {
    int node = i >> 5, c4 = (i & 31) * 4;
    float4 v = *reinterpret_cast<const float4*>(x + (size_t)node * 128 + c4);
    unsigned short r[4] = { f2bf(v.x), f2bf(v.y), f2bf(v.z), f2bf(v.w) };
    *reinterpret_cast<uint2*>(A1 + (size_t)node * 256 + 128 + c4) =
        *reinterpret_cast<uint2*>(r);
    xq[node * 32 + (i & 31)] = pk4_fp8(v.x, v.y, v.z, v.w);
  }
}

// ---------- layer-1 aggregation: one wave per node, 4 edges/wave-iter, x2 unroll ----------
// 16 lanes per edge, uint2 (8 fp8 ch) per lane -> 8 gather loads in flight per wave.
__global__ __launch_bounds__(256) void agg1_kernel(const int* __restrict__ csr_src,
                                                   const int* __restrict__ rs,
                                                   const uint2* __restrict__ xq,
                                                   unsigned short* __restrict__ A1,
                                                   int n_nodes) {
  int w = blockIdx.x * 4 + (threadIdx.x >> 6);
  if (w >= n_nodes) return;
  int lane = threadIdx.x & 63;
  int grp = lane >> 4;          // edge slot 0..3
  int ch2 = lane & 15;          // uint2 index (8 fp8 channels)
  int e0 = rs[w], e1 = rs[w + 1];
  floatx4 aA0 = {0,0,0,0}, aB0 = {0,0,0,0};   // slot 0 of unroll
  floatx4 aA1 = {0,0,0,0}, aB1 = {0,0,0,0};   // slot 1 of unroll
  int e = e0 + grp;
  for (; e + 4 < e1; e += 8) {
    int s0 = csr_src[e], s1 = csr_src[e + 4];
    uint2 p0 = xq[(size_t)s0 * 16 + ch2];
    uint2 p1 = xq[(size_t)s1 * 16 + ch2];
    floatx4 vA0 = unpk4_fp8(p0.x), vB0 = unpk4_fp8(p0.y);
    floatx4 vA1 = unpk4_fp8(p1.x), vB1 = unpk4_fp8(p1.y);
    aA0.x += vA0.x; aA0.y += vA0.y; aA0.z += vA0.z; aA0.w += vA0.w;
    aB0.x += vB0.x; aB0.y += vB0.y; aB0.z += vB0.z; aB0.w += vB0.w;
    aA1.x += vA1.x; aA1.y += vA1.y; aA1.z += vA1.z; aA1.w += vA1.w;
    aB1.x += vB1.x; aB1.y += vB1.y; aB1.z += vB1.z; aB1.w += vB1.w;
  }
  for (; e < e1; e += 4) {
    uint2 p = xq[(size_t)csr_src[e] * 16 + ch2];
    floatx4 vA = unpk4_fp8(p.x), vB = unpk4_fp8(p.y);
    aA0.x += vA.x; aA0.y += vA.y; aA0.z += vA.z; aA0.w += vA.w;
    aB0.x += vB.x; aB0.y += vB.y; aB0.z += vB.z; aB0.w += vB.w;
  }
  floatx4 aA = {aA0.x + aA1.x, aA0.y + aA1.y, aA0.z + aA1.z, aA0.w + aA1.w};
  floatx4 aB = {aB0.x + aB1.x, aB0.y + aB1.y, aB0.z + aB1.z, aB0.w + aB1.w};
  // reduce across the 4 edge slots
#pragma unroll
  for (int m = 16; m <= 32; m <<= 1) {
    aA.x += __shfl_xor(aA.x, m); aA.y += __shfl_xor(aA.y, m);
    aA.z += __shfl_xor(aA.z, m); aA.w += __shfl_xor(aA.w, m);
    aB.x += __shfl_xor(aB.x, m); aB.y += __shfl_xor(aB.y, m);
    aB.z += __shfl_xor(aB.z, m); aB.w += __shfl_xor(aB.w, m);
  }
  if (grp == 0) {
    int d = e1 - e0; if (d < 1) d = 1;
    float sc = 1.0f / (float)d;
    unsigned short r[8] = { f2bf(aA.x * sc), f2bf(aA.y * sc), f2bf(aA.z * sc), f2bf(aA.w * sc),
                            f2bf(aB.x * sc), f2bf(aB.y * sc), f2bf(aB.z * sc), f2bf(aB.w * sc) };
    *reinterpret_cast<uint4*>(A1 + (size_t)w * 256 + ch2 * 8) =
        *reinterpret_cast<uint4*>(r);
  }
}

// ---------- fused MLP (64-row tiles, 4 blocks/CU) ----------
#define LDSW 264   // padded row stride in shorts (528 B)
__global__ __launch_bounds__(256, 4) void gemm_fused(const unsigned short* __restrict__ A1,
                                                     const unsigned short* __restrict__ W1t,
                                                     const unsigned short* __restrict__ W2t,
                                                     const float* __restrict__ b1,
                                                     unsigned char* __restrict__ zq,
                                                     unsigned short* __restrict__ rb,
                                                     int M) {
  __shared__ unsigned short smem[64 * LDSW];   // 33792 B -> 4 blocks/CU
  const int tid = threadIdx.x;
  const int lane = tid & 63;
  const int wave = tid >> 6;
  const int m0 = blockIdx.x * 64;
  const int fm = lane & 15;
  const int fq = lane >> 4;

#pragma unroll
  for (int j = 0; j < 8; j++) {
    int c = j * 256 + tid;
    int row = c >> 5, ch = c & 31;
    int gr = m0 + row; if (gr >= M) gr = M - 1;
    int4 v = *reinterpret_cast<const int4*>(A1 + (size_t)gr * 256 + ch * 8);
    *reinterpret_cast<int4*>(&smem[row * LDSW + ch * 8]) = v;
  }

  float bb[4];
#pragma unroll
  for (int ni = 0; ni < 4; ni++) bb[ni] = b1[wave * 64 + ni * 16 + fm];

  __syncthreads();

  floatx4 acc1[4][4] = {};
#pragma unroll 2
  for (int kk = 0; kk < 8; kk++) {
    short8 af[4], bfr[4];
#pragma unroll
    for (int mi = 0; mi < 4; mi++)
      af[mi] = *reinterpret_cast<const short8*>(
          &smem[(mi * 16 + fm) * LDSW + kk * 32 + fq * 8]);
#pragma unroll
    for (int ni = 0; ni < 4; ni++)
      bfr[ni] = *reinterpret_cast<const short8*>(
          W1t + (size_t)(wave * 64 + ni * 16 + fm) * 256 + kk * 32 + fq * 8);
#pragma unroll
    for (int mi = 0; mi < 4; mi++)
#pragma unroll
      for (int ni = 0; ni < 4; ni++)
        acc1[mi][ni] = __builtin_amdgcn_mfma_f32_16x16x32_bf16(af[mi], bfr[ni],
                                                               acc1[mi][ni], 0, 0, 0);
  }

  __syncthreads();

#pragma unroll
  for (int mi = 0; mi < 4; mi++)
#pragma unroll
    for (int ni = 0; ni < 4; ni++)
#pragma unroll
      for (int r = 0; r < 4; r++) {
        float v = acc1[mi][ni][r] + bb[ni];
        v = v > 0.f ? v : 0.f;
        smem[(mi * 16 + fq * 4 + r) * LDSW + wave * 64 + ni * 16 + fm] = f2bf(v);
      }
  __syncthreads();

  floatx4 acc2[4][2] = {};
#pragma unroll 2
  for (int kk = 0; kk < 8; kk++) {
    short8 hf[4], wf[2];
#pragma unroll
    for (int mi = 0; mi < 4; mi++)
      hf[mi] = *reinterpret_cast<const short8*>(
          &smem[(mi * 16 + fm) * LDSW + kk * 32 + fq * 8]);
#pragma unroll
    for (int ni = 0; ni < 2; ni++)
      wf[ni] = *reinterpret_cast<const short8*>(
          W2t + (size_t)(wave * 32 + ni * 16 + fm) * 256 + kk * 32 + fq * 8);
#pragma unroll
    for (int mi = 0; mi < 4; mi++)
#pragma unroll
      for (int ni = 0; ni < 2; ni++)
        acc2[mi][ni] = __builtin_amdgcn_mfma_f32_16x16x32_bf16(hf[mi], wf[ni],
                                                               acc2[mi][ni], 0, 0, 0);
  }

#pragma unroll
  for (int mi = 0; mi < 4; mi++)
#pragma unroll
    for (int ni = 0; ni < 2; ni++)
#pragma unroll
      for (int r = 0; r < 4; r++) {
        int grow = m0 + mi * 16 + fq * 4 + r;
        if (grow < M) {
          float v = acc2[mi][ni][r];
          int col = (wave & 1) * 32 + ni * 16 + fm;
          if (wave < 2) {
            int b8 = __builtin_amdgcn_cvt_pk_fp8_f32(v, v, 0, false);
            zq[(size_t)grow * 64 + col] = (unsigned char)(b8 & 0xff);
          } else {
            rb[(size_t)grow * 64 + col] = f2bf(v);
          }
        }
      }
}

// ---------- layer-2 aggregation + epilogue: 8 edges/wave-iter, x2 unroll ----------
// 8 lanes per edge, uint2 (8 fp8 ch) per lane -> 16 gather loads in flight per wave.
__global__ __launch_bounds__(256) void agg2_final(const uint2* __restrict__ zq,
                                                  const unsigned short* __restrict__ rb,
                                                  const int* __restrict__ csr_src,
                                                  const int* __restrict__ rs,
                                                  const float* __restrict__ b2,
                                                  float* __restrict__ out, int n_nodes) {
  int w = blockIdx.x * 4 + (threadIdx.x >> 6);
  if (w >= n_nodes) return;
  int lane = threadIdx.x & 63;
  int grp = lane >> 3;          // edge slot 0..7
  int ch2 = lane & 7;           // uint2 index (8 fp8 channels of 64)
  int e0 = rs[w], e1 = rs[w + 1];
  floatx4 aA0 = {0,0,0,0}, aB0 = {0,0,0,0};
  floatx4 aA1 = {0,0,0,0}, aB1 = {0,0,0,0};
  int e = e0 + grp;
  for (; e + 8 < e1; e += 16) {
    int s0 = csr_src[e], s1 = csr_src[e + 8];
    uint2 p0 = zq[(size_t)s0 * 8 + ch2];
    uint2 p1 = zq[(size_t)s1 * 8 + ch2];
    floatx4 vA0 = unpk4_fp8(p0.x), vB0 = unpk4_fp8(p0.y);
    floatx4 vA1 = unpk4_fp8(p1.x), vB1 = unpk4_fp8(p1.y);
    aA0.x += vA0.x; aA0.y += vA0.y; aA0.z += vA0.z; aA0.w += vA0.w;
    aB0.x += vB0.x; aB0.y += vB0.y; aB0.z += vB0.z; aB0.w += vB0.w;
    aA1.x += vA1.x; aA1.y += vA1.y; aA1.z += vA1.z; aA1.w += vA1.w;
    aB1.x += vB1.x; aB1.y += vB1.y; aB1.z += vB1.z; aB1.w += vB1.w;
  }
  for (; e < e1; e += 8) {
    uint2 p = zq[(size_t)csr_src[e] * 8 + ch2];
    floatx4 vA = unpk4_fp8(p.x), vB = unpk4_fp8(p.y);
    aA0.x += vA.x; aA0.y += vA.y; aA0.z += vA.z; aA0.w += vA.w;
    aB0.x += vB.x; aB0.y += vB.y; aB0.z += vB.z; aB0.w += vB.w;
  }
  floatx4 aA = {aA0.x + aA1.x, aA0.y + aA1.y, aA0.z + aA1.z, aA0.w + aA1.w};
  floatx4 aB = {aB0.x + aB1.x, aB0.y + aB1.y, aB0.z + aB1.z, aB0.w + aB1.w};
#pragma unroll
  for (int m = 8; m <= 32; m <<= 1) {
    aA.x += __shfl_xor(aA.x, m); aA.y += __shfl_xor(aA.y, m);
    aA.z += __shfl_xor(aA.z, m); aA.w += __shfl_xor(aA.w, m);
    aB.x += __shfl_xor(aB.x, m); aB.y += __shfl_xor(aB.y, m);
    aB.z += __shfl_xor(aB.z, m); aB.w += __shfl_xor(aB.w, m);
  }
  if (grp == 0) {
    int d = e1 - e0; if (d < 1) d = 1;
    float sc = 1.0f / (float)d;
    uint4 rr = *reinterpret_cast<const uint4*>(rb + (size_t)w * 64 + ch2 * 8);
    float4 bv0 = *reinterpret_cast<const float4*>(b2 + ch2 * 8);
    float4 bv1 = *reinterpret_cast<const float4*>(b2 + ch2 * 8 + 4);
    float r0 = bf2f((unsigned short)(rr.x & 0xffff)), r1 = bf2f((unsigned short)(rr.x >> 16));
    float r2 = bf2f((unsigned short)(rr.y & 0xffff)), r3 = bf2f((unsigned short)(rr.y >> 16));
    float r4 = bf2f((unsigned short)(rr.z & 0xffff)), r5 = bf2f((unsigned short)(rr.z >> 16));
    float r6 = bf2f((unsigned short)(rr.w & 0xffff)), r7 = bf2f((unsigned short)(rr.w >> 16));
    float4 o0, o1;
    o0.x = 1.0f / (1.0f + __expf(-(aA.x * sc + r0 + bv0.x)));
    o0.y = 1.0f / (1.0f + __expf(-(aA.y * sc + r1 + bv0.y)));
    o0.z = 1.0f / (1.0f + __expf(-(aA.z * sc + r2 + bv0.z)));
    o0.w = 1.0f / (1.0f + __expf(-(aA.w * sc + r3 + bv0.w)));
    o1.x = 1.0f / (1.0f + __expf(-(aB.x * sc + r4 + bv1.x)));
    o1.y = 1.0f / (1.0f + __expf(-(aB.y * sc + r5 + bv1.y)));
    o1.z = 1.0f / (1.0f + __expf(-(aB.z * sc + r6 + bv1.z)));
    o1.w = 1.0f / (1.0f + __expf(-(aB.w * sc + r7 + bv1.w)));
    *reinterpret_cast<float4*>(out + (size_t)w * 64 + ch2 * 8) = o0;
    *reinterpret_cast<float4*>(out + (size_t)w * 64 + ch2 * 8 + 4) = o1;
  }
}

// ---------- launch ----------
extern "C" void kernel_launch(void* const* d_in, const int* in_sizes, int n_in,
                              void* d_out, int out_size, void* d_ws, size_t ws_size,
                              hipStream_t stream) {
  const float* x   = (const float*)d_in[0];
  const int*   ei  = (const int*)d_in[1];
  const float* W1l = (const float*)d_in[2];
  const float* W1r = (const float*)d_in[3];
  const float* b1  = (const float*)d_in[4];
  const float* W2l = (const float*)d_in[5];
  const float* W2r = (const float*)d_in[6];
  const float* b2  = (const float*)d_in[7];
  float* out = (float*)d_out;

  const int N = in_sizes[0] / 128;     // 100000
  const int E = in_sizes[1] / 2;       // 1600000
  const int* src = ei;
  const int* dst = ei + E;

  // workspace layout (512B aligned blocks)
  char* wsb = (char*)d_ws;
  size_t off = 0;
  auto alloc = [&](size_t bytes) -> void* {
    void* p = wsb + off;
    off += (bytes + 511) & ~(size_t)511;
    return p;
  };
  int* rs       = (int*)alloc((size_t)(N + 1) * 4);
  int* csr_src  = (int*)alloc((size_t)E * 4 + 64);
  int* bcnt     = (int*)alloc(NBUCK * 4);
  int* bbase    = (int*)alloc(NBUCK * 4);
  int* bcur     = (int*)alloc(NBUCK * 4);
  unsigned int* staging = (unsigned int*)alloc((size_t)E * 4);
  unsigned short* W1t = (unsigned short*)alloc(256 * 256 * 2);
  unsigned short* W2t = (unsigned short*)alloc(128 * 256 * 2);
  unsigned short* A1  = (unsigned short*)alloc((size_t)N * 256 * 2);
  unsigned int* xq    = (unsigned int*)alloc((size_t)N * 128);      // fp8 x, 128 B/row
  unsigned char* zq   = (unsigned char*)alloc((size_t)N * 64);      // fp8 z, 64 B/row
  unsigned short* rb  = (unsigned short*)alloc((size_t)N * 64 * 2); // bf16 r
  (void)ws_size; (void)n_in; (void)out_size;

  const int nbuckReal = (N + 1023) / 1024;             // 98
  const int nchunks = (E + BIN_CHUNK - 1) / BIN_CHUNK; // 196

  hipMemsetAsync(bcnt, 0, NBUCK * 4, stream);
  bhist<<<256, 256, 0, stream>>>(dst, bcnt, E);
  bscan<<<1, 128, 0, stream>>>(bcnt, bbase, bcur, rs, N, E);
  binscatter<<<nchunks, 256, 0, stream>>>(src, dst, bcur, staging, E);
  bucketfinal<<<nbuckReal, 256, 0, stream>>>(staging, bbase, bcnt, rs, csr_src, N);

  convw<<<(256 * 256 + 128 * 256 + 255) / 256, 256, 0, stream>>>(W1l, W1r, W2l, W2r, W1t, W2t);
  convx<<<(N * 32 + 255) / 256, 256, 0, stream>>>(x, A1, xq, N);

  agg1_kernel<<<(N + 3) / 4, 256, 0, stream>>>(csr_src, rs, (const uint2*)xq, A1, N);

  gemm_fused<<<(N + 63) / 64, 256, 0, stream>>>(A1, W1t, W2t, b1, zq, rb, N);

  agg2_final<<<(N + 3) / 4, 256, 0, stream>>>((const uint2*)zq, rb, csr_src, rs, b2, out, N);
}

// Round 8
// 321.242 us; speedup vs baseline: 2.2275x; 1.0467x over previous
//
#include <hip/hip_runtime.h>

// ---------- helpers ----------
typedef __attribute__((ext_vector_type(8))) short short8;   // 8 x bf16 fragment (4 VGPRs)
typedef __attribute__((ext_vector_type(4))) float floatx4;  // MFMA accumulator
typedef __attribute__((ext_vector_type(2))) float floatx2;

static __device__ __forceinline__ unsigned short f2bf(float f) {
  unsigned int u = __builtin_bit_cast(unsigned int, f);
  u += 0x7FFFu + ((u >> 16) & 1u);   // RNE (finite inputs only)
  return (unsigned short)(u >> 16);
}
static __device__ __forceinline__ float bf2f(unsigned short s) {
  unsigned int u = ((unsigned int)s) << 16;
  return __builtin_bit_cast(float, u);
}
// fp8 e4m3 (OCP on gfx950) via HW cvt — encode/decode both on-device, self-consistent
static __device__ __forceinline__ unsigned int pk4_fp8(float a, float b, float c, float d) {
  int lo = __builtin_amdgcn_cvt_pk_fp8_f32(a, b, 0, false);
  int hi = __builtin_amdgcn_cvt_pk_fp8_f32(c, d, 0, false);
  return (unsigned int)((lo & 0xffff) | ((hi & 0xffff) << 16));
}
static __device__ __forceinline__ floatx4 unpk4_fp8(unsigned int p) {
  floatx2 lo = __builtin_amdgcn_cvt_pk_f32_fp8((int)p, false);
  floatx2 hi = __builtin_amdgcn_cvt_pk_f32_fp8((int)p, true);
  floatx4 r = {lo.x, lo.y, hi.x, hi.y};
  return r;
}

#define NBUCK 128        // padded bucket count; real buckets = ceil(N/1024) = 98
#define BIN_CHUNK 8192   // edges per binscatter workgroup

// ---------- CSR build via two-level binning (avoids 16x write amplification) ----------

__global__ __launch_bounds__(256) void bhist(const int* __restrict__ dst,
                                             int* __restrict__ bcnt, int E) {
  __shared__ int h[NBUCK];
  for (int i = threadIdx.x; i < NBUCK; i += 256) h[i] = 0;
  __syncthreads();
  int stride = gridDim.x * 256;
  for (int i = blockIdx.x * 256 + threadIdx.x; i < E; i += stride)
    atomicAdd(&h[dst[i] >> 10], 1);
  __syncthreads();
  for (int i = threadIdx.x; i < NBUCK; i += 256)
    if (h[i]) atomicAdd(&bcnt[i], h[i]);
}

__global__ __launch_bounds__(128) void bscan(const int* __restrict__ bcnt,
                                             int* __restrict__ bbase,
                                             int* __restrict__ bcur,
                                             int* __restrict__ rs, int N, int E) {
  __shared__ int s[NBUCK];
  int t = threadIdx.x;
  int v = bcnt[t];
  s[t] = v;
  __syncthreads();
  for (int off = 1; off < NBUCK; off <<= 1) {
    int x = (t >= off) ? s[t - off] : 0;
    __syncthreads();
    s[t] += x;
    __syncthreads();
  }
  int excl = s[t] - v;
  bbase[t] = excl;
  bcur[t] = excl;
  if (t == 0) rs[N] = E;
}

__global__ __launch_bounds__(256) void binscatter(const int* __restrict__ src,
                                                  const int* __restrict__ dst,
                                                  int* __restrict__ bcur,
                                                  unsigned int* __restrict__ staging,
                                                  int E) {
  __shared__ int h[NBUCK];
  __shared__ int cur[NBUCK];
  for (int i = threadIdx.x; i < NBUCK; i += 256) h[i] = 0;
  __syncthreads();
  int base = blockIdx.x * BIN_CHUNK;
  int end = base + BIN_CHUNK; if (end > E) end = E;
  for (int i = base + threadIdx.x; i < end; i += 256)
    atomicAdd(&h[dst[i] >> 10], 1);
  __syncthreads();
  for (int i = threadIdx.x; i < NBUCK; i += 256)
    cur[i] = h[i] ? atomicAdd(&bcur[i], h[i]) : 0;
  __syncthreads();
  for (int i = base + threadIdx.x; i < end; i += 256) {
    int d = dst[i], s = src[i];
    int b = d >> 10;
    int pos = atomicAdd(&cur[b], 1);
    staging[pos] = ((unsigned int)(d & 1023) << 17) | (unsigned int)s;
  }
}

__global__ __launch_bounds__(256) void bucketfinal(const unsigned int* __restrict__ staging,
                                                   const int* __restrict__ bbase,
                                                   const int* __restrict__ bcnt,
                                                   int* __restrict__ rs,
                                                   int* __restrict__ csr_src, int N) {
  int b = blockIdx.x;
  int base = bbase[b], cnt = bcnt[b];
  __shared__ int h[1024];
  __shared__ int ps[256];
  __shared__ int cur[1024];
  int t = threadIdx.x;
  for (int i = t; i < 1024; i += 256) h[i] = 0;
  __syncthreads();
  for (int i = t; i < cnt; i += 256)
    atomicAdd(&h[staging[base + i] >> 17], 1);
  __syncthreads();
  int a0 = h[4 * t], a1 = h[4 * t + 1], a2 = h[4 * t + 2], a3 = h[4 * t + 3];
  int tsum = a0 + a1 + a2 + a3;
  ps[t] = tsum;
  __syncthreads();
  for (int off = 1; off < 256; off <<= 1) {
    int x = (t >= off) ? ps[t - off] : 0;
    __syncthreads();
    ps[t] += x;
    __syncthreads();
  }
  int run = base + ps[t] - tsum;
  int node0 = b << 10;
  int va[4] = {a0, a1, a2, a3};
#pragma unroll
  for (int j = 0; j < 4; j++) {
    int w = node0 + 4 * t + j;
    cur[4 * t + j] = run;
    if (w < N) rs[w] = run;
    run += va[j];
  }
  __syncthreads();
  for (int i = t; i < cnt; i += 256) {
    unsigned int v = staging[base + i];
    int pos = atomicAdd(&cur[v >> 17], 1);
    csr_src[pos] = (int)(v & 0x1FFFFu);
  }
}

// ---------- weight conversion: fragment-major packing ----------
// W1p granule index: ((wave*8 + kk)*4 + ni)*64 + lane  (short8 each)
//   holds W1t[(wave*64 + ni*16 + fm)][kk*32 + fq*8 + j], fm=lane&15, fq=lane>>4
//   where W1t[n][k] = k<128 ? W1l[k][n] : W1r[k-128][n]
// W2p granule index: ((wave*8 + kk)*2 + ni)*64 + lane
//   holds W2t[(wave*32 + ni*16 + fm)][kk*32 + fq*8 + j]
//   where W2t[n][k] = n<64 ? W2l[k][n] : W2r[k][n-64]
__global__ void convw(const float* __restrict__ W1l, const float* __restrict__ W1r,
                      const float* __restrict__ W2l, const float* __restrict__ W2r,
                      unsigned short* __restrict__ W1p, unsigned short* __restrict__ W2p) {
  int i = blockIdx.x * blockDim.x + threadIdx.x;
  if (i < 8192) {
    int lane = i & 63, ni = (i >> 6) & 3, kk = (i >> 8) & 7, w = i >> 11;
    int fm = lane & 15, fq = lane >> 4;
    int n = w * 64 + ni * 16 + fm;
    int k0 = kk * 32 + fq * 8;
    unsigned short r[8];
#pragma unroll
    for (int j = 0; j < 8; j++) {
      int k = k0 + j;
      float v = (k < 128) ? W1l[k * 256 + n] : W1r[(k - 128) * 256 + n];
      r[j] = f2bf(v);
    }
    *reinterpret_cast<uint4*>(W1p + (size_t)i * 8) = *reinterpret_cast<uint4*>(r);
  } else if (i < 8192 + 4096) {
    int j2 = i - 8192;
    int lane = j2 & 63, ni = (j2 >> 6) & 1, kk = (j2 >> 7) & 7, w = j2 >> 10;
    int fm = lane & 15, fq = lane >> 4;
    int n = w * 32 + ni * 16 + fm;
    int k0 = kk * 32 + fq * 8;
    unsigned short r[8];
#pragma unroll
    for (int j = 0; j < 8; j++) {
      int k = k0 + j;
      float v = (n < 64) ? W2l[k * 64 + n] : W2r[k * 64 + (n - 64)];
      r[j] = f2bf(v);
    }
    *reinterpret_cast<uint4*>(W2p + (size_t)j2 * 8) = *reinterpret_cast<uint4*>(r);
  }
}

// x (fp32, [N][128]) -> bf16 right half of A1 (self path) + fp8 xq (gather path)
__global__ void convx(const float* __restrict__ x, unsigned short* __restrict__ A1,
                      unsigned int* __restrict__ xq, int n_nodes) {
  int i = blockIdx.x * blockDim.x + threadIdx.x;
  if (i < n_nodes * 32) {
    int node = i >> 5, c4 = (i & 31) * 4;
    float4 v = *reinterpret_cast<const float4*>(x + (size_t)node * 128 + c4);
    unsigned short r[4] = { f2bf(v.x), f2bf(v.y), f2bf(v.z), f2bf(v.w) };
    *reinterpret_cast<uint2*>(A1 + (size_t)node * 256 + 128 + c4) =
        *reinterpret_cast<uint2*>(r);
    xq[node * 32 + (i & 31)] = pk4_fp8(v.x, v.y, v.z, v.w);
  }
}

// ---------- layer-1 aggregation: one wave per node, 4 edges/wave-iter, x2 unroll ----------
// 16 lanes per edge, uint2 (8 fp8 ch) per lane; 32-bit offsets.
__global__ __launch_bounds__(256) void agg1_kernel(const int* __restrict__ csr_src,
                                                   const int* __restrict__ rs,
                                                   const uint2* __restrict__ xq,
                                                   unsigned short* __restrict__ A1,
                                                   int n_nodes) {
  int w = blockIdx.x * 4 + (threadIdx.x >> 6);
  if (w >= n_nodes) return;
  int lane = threadIdx.x & 63;
  int grp = lane >> 4;          // edge slot 0..3
  int ch2 = lane & 15;          // uint2 index (8 fp8 channels)
  int e0 = rs[w], e1 = rs[w + 1];
  floatx4 aA0 = {0,0,0,0}, aB0 = {0,0,0,0};
  floatx4 aA1 = {0,0,0,0}, aB1 = {0,0,0,0};
  int e = e0 + grp;
  for (; e + 4 < e1; e += 8) {
    int o0 = (csr_src[e] << 4) | ch2;
    int o1 = (csr_src[e + 4] << 4) | ch2;
    uint2 p0 = xq[o0];
    uint2 p1 = xq[o1];
    aA0 += unpk4_fp8(p0.x); aB0 += unpk4_fp8(p0.y);
    aA1 += unpk4_fp8(p1.x); aB1 += unpk4_fp8(p1.y);
  }
  for (; e < e1; e += 4) {
    uint2 p = xq[(csr_src[e] << 4) | ch2];
    aA0 += unpk4_fp8(p.x); aB0 += unpk4_fp8(p.y);
  }
  floatx4 aA = aA0 + aA1;
  floatx4 aB = aB0 + aB1;
#pragma unroll
  for (int m = 16; m <= 32; m <<= 1) {
    aA.x += __shfl_xor(aA.x, m); aA.y += __shfl_xor(aA.y, m);
    aA.z += __shfl_xor(aA.z, m); aA.w += __shfl_xor(aA.w, m);
    aB.x += __shfl_xor(aB.x, m); aB.y += __shfl_xor(aB.y, m);
    aB.z += __shfl_xor(aB.z, m); aB.w += __shfl_xor(aB.w, m);
  }
  if (grp == 0) {
    int d = e1 - e0; if (d < 1) d = 1;
    float sc = 1.0f / (float)d;
    unsigned short r[8] = { f2bf(aA.x * sc), f2bf(aA.y * sc), f2bf(aA.z * sc), f2bf(aA.w * sc),
                            f2bf(aB.x * sc), f2bf(aB.y * sc), f2bf(aB.z * sc), f2bf(aB.w * sc) };
    *reinterpret_cast<uint4*>(A1 + (size_t)w * 256 + ch2 * 8) =
        *reinterpret_cast<uint4*>(r);
  }
}

// ---------- fused MLP (64-row tiles, 4 blocks/CU, fragment-major weights) ----------
#define LDSW 264   // padded row stride in shorts (528 B)
__global__ __launch_bounds__(256, 4) void gemm_fused(const unsigned short* __restrict__ A1,
                                                     const unsigned short* __restrict__ W1p,
                                                     const unsigned short* __restrict__ W2p,
                                                     const float* __restrict__ b1,
                                                     unsigned char* __restrict__ zq,
                                                     unsigned short* __restrict__ rb,
                                                     int M) {
  __shared__ unsigned short smem[64 * LDSW];   // 33792 B -> 4 blocks/CU
  const int tid = threadIdx.x;
  const int lane = tid & 63;
  const int wave = tid >> 6;
  const int m0 = blockIdx.x * 64;
  const int fm = lane & 15;
  const int fq = lane >> 4;
  const short8* __restrict__ W1v = reinterpret_cast<const short8*>(W1p);
  const short8* __restrict__ W2v = reinterpret_cast<const short8*>(W2p);

#pragma unroll
  for (int j = 0; j < 8; j++) {
    int c = j * 256 + tid;
    int row = c >> 5, ch = c & 31;
    int gr = m0 + row; if (gr >= M) gr = M - 1;
    int4 v = *reinterpret_cast<const int4*>(A1 + (size_t)gr * 256 + ch * 8);
    *reinterpret_cast<int4*>(&smem[row * LDSW + ch * 8]) = v;
  }

  float bb[4];
#pragma unroll
  for (int ni = 0; ni < 4; ni++) bb[ni] = b1[wave * 64 + ni * 16 + fm];

  __syncthreads();

  // ---- gemm1: coalesced weight frags, 1 KB per load inst ----
  floatx4 acc1[4][4] = {};
#pragma unroll 2
  for (int kk = 0; kk < 8; kk++) {
    short8 af[4], bfr[4];
#pragma unroll
    for (int mi = 0; mi < 4; mi++)
      af[mi] = *reinterpret_cast<const short8*>(
          &smem[(mi * 16 + fm) * LDSW + kk * 32 + fq * 8]);
#pragma unroll
    for (int ni = 0; ni < 4; ni++)
      bfr[ni] = W1v[((wave * 8 + kk) * 4 + ni) * 64 + lane];
#pragma unroll
    for (int mi = 0; mi < 4; mi++)
#pragma unroll
      for (int ni = 0; ni < 4; ni++)
        acc1[mi][ni] = __builtin_amdgcn_mfma_f32_16x16x32_bf16(af[mi], bfr[ni],
                                                               acc1[mi][ni], 0, 0, 0);
  }

  __syncthreads();

#pragma unroll
  for (int mi = 0; mi < 4; mi++)
#pragma unroll
    for (int ni = 0; ni < 4; ni++)
#pragma unroll
      for (int r = 0; r < 4; r++) {
        float v = acc1[mi][ni][r] + bb[ni];
        v = v > 0.f ? v : 0.f;
        smem[(mi * 16 + fq * 4 + r) * LDSW + wave * 64 + ni * 16 + fm] = f2bf(v);
      }
  __syncthreads();

  floatx4 acc2[4][2] = {};
#pragma unroll 2
  for (int kk = 0; kk < 8; kk++) {
    short8 hf[4], wf[2];
#pragma unroll
    for (int mi = 0; mi < 4; mi++)
      hf[mi] = *reinterpret_cast<const short8*>(
          &smem[(mi * 16 + fm) * LDSW + kk * 32 + fq * 8]);
#pragma unroll
    for (int ni = 0; ni < 2; ni++)
      wf[ni] = W2v[((wave * 8 + kk) * 2 + ni) * 64 + lane];
#pragma unroll
    for (int mi = 0; mi < 4; mi++)
#pragma unroll
      for (int ni = 0; ni < 2; ni++)
        acc2[mi][ni] = __builtin_amdgcn_mfma_f32_16x16x32_bf16(hf[mi], wf[ni],
                                                               acc2[mi][ni], 0, 0, 0);
  }

#pragma unroll
  for (int mi = 0; mi < 4; mi++)
#pragma unroll
    for (int ni = 0; ni < 2; ni++)
#pragma unroll
      for (int r = 0; r < 4; r++) {
        int grow = m0 + mi * 16 + fq * 4 + r;
        if (grow < M) {
          float v = acc2[mi][ni][r];
          int col = (wave & 1) * 32 + ni * 16 + fm;
          if (wave < 2) {
            int b8 = __builtin_amdgcn_cvt_pk_fp8_f32(v, v, 0, false);
            zq[grow * 64 + col] = (unsigned char)(b8 & 0xff);
          } else {
            rb[grow * 64 + col] = f2bf(v);
          }
        }
      }
}

// ---------- layer-2 aggregation + epilogue: 8 edges/wave-iter, x2 unroll ----------
// 8 lanes per edge, uint2 per lane; 32-bit offsets.
__global__ __launch_bounds__(256) void agg2_final(const uint2* __restrict__ zq,
                                                  const unsigned short* __restrict__ rb,
                                                  const int* __restrict__ csr_src,
                                                  const int* __restrict__ rs,
                                                  const float* __restrict__ b2,
                                                  float* __restrict__ out, int n_nodes) {
  int w = blockIdx.x * 4 + (threadIdx.x >> 6);
  if (w >= n_nodes) return;
  int lane = threadIdx.x & 63;
  int grp = lane >> 3;          // edge slot 0..7
  int ch2 = lane & 7;           // uint2 index (8 fp8 channels of 64)
  int e0 = rs[w], e1 = rs[w + 1];
  floatx4 aA0 = {0,0,0,0}, aB0 = {0,0,0,0};
  floatx4 aA1 = {0,0,0,0}, aB1 = {0,0,0,0};
  int e = e0 + grp;
  for (; e + 8 < e1; e += 16) {
    int o0 = (csr_src[e] << 3) | ch2;
    int o1 = (csr_src[e + 8] << 3) | ch2;
    uint2 p0 = zq[o0];
    uint2 p1 = zq[o1];
    aA0 += unpk4_fp8(p0.x); aB0 += unpk4_fp8(p0.y);
    aA1 += unpk4_fp8(p1.x); aB1 += unpk4_fp8(p1.y);
  }
  for (; e < e1; e += 8) {
    uint2 p = zq[(csr_src[e] << 3) | ch2];
    aA0 += unpk4_fp8(p.x); aB0 += unpk4_fp8(p.y);
  }
  floatx4 aA = aA0 + aA1;
  floatx4 aB = aB0 + aB1;
#pragma unroll
  for (int m = 8; m <= 32; m <<= 1) {
    aA.x += __shfl_xor(aA.x, m); aA.y += __shfl_xor(aA.y, m);
    aA.z += __shfl_xor(aA.z, m); aA.w += __shfl_xor(aA.w, m);
    aB.x += __shfl_xor(aB.x, m); aB.y += __shfl_xor(aB.y, m);
    aB.z += __shfl_xor(aB.z, m); aB.w += __shfl_xor(aB.w, m);
  }
  if (grp == 0) {
    int d = e1 - e0; if (d < 1) d = 1;
    float sc = 1.0f / (float)d;
    uint4 rr = *reinterpret_cast<const uint4*>(rb + w * 64 + ch2 * 8);
    float4 bv0 = *reinterpret_cast<const float4*>(b2 + ch2 * 8);
    float4 bv1 = *reinterpret_cast<const float4*>(b2 + ch2 * 8 + 4);
    float r0 = bf2f((unsigned short)(rr.x & 0xffff)), r1 = bf2f((unsigned short)(rr.x >> 16));
    float r2 = bf2f((unsigned short)(rr.y & 0xffff)), r3 = bf2f((unsigned short)(rr.y >> 16));
    float r4 = bf2f((unsigned short)(rr.z & 0xffff)), r5 = bf2f((unsigned short)(rr.z >> 16));
    float r6 = bf2f((unsigned short)(rr.w & 0xffff)), r7 = bf2f((unsigned short)(rr.w >> 16));
    float4 o0, o1;
    o0.x = 1.0f / (1.0f + __expf(-(aA.x * sc + r0 + bv0.x)));
    o0.y = 1.0f / (1.0f + __expf(-(aA.y * sc + r1 + bv0.y)));
    o0.z = 1.0f / (1.0f + __expf(-(aA.z * sc + r2 + bv0.z)));
    o0.w = 1.0f / (1.0f + __expf(-(aA.w * sc + r3 + bv0.w)));
    o1.x = 1.0f / (1.0f + __expf(-(aB.x * sc + r4 + bv1.x)));
    o1.y = 1.0f / (1.0f + __expf(-(aB.y * sc + r5 + bv1.y)));
    o1.z = 1.0f / (1.0f + __expf(-(aB.z * sc + r6 + bv1.z)));
    o1.w = 1.0f / (1.0f + __expf(-(aB.w * sc + r7 + bv1.w)));
    *reinterpret_cast<float4*>(out + (size_t)w * 64 + ch2 * 8) = o0;
    *reinterpret_cast<float4*>(out + (size_t)w * 64 + ch2 * 8 + 4) = o1;
  }
}

// ---------- launch ----------
extern "C" void kernel_launch(void* const* d_in, const int* in_sizes, int n_in,
                              void* d_out, int out_size, void* d_ws, size_t ws_size,
                              hipStream_t stream) {
  const float* x   = (const float*)d_in[0];
  const int*   ei  = (const int*)d_in[1];
  const float* W1l = (const float*)d_in[2];
  const float* W1r = (const float*)d_in[3];
  const float* b1  = (const float*)d_in[4];
  const float* W2l = (const float*)d_in[5];
  const float* W2r = (const float*)d_in[6];
  const float* b2  = (const float*)d_in[7];
  float* out = (float*)d_out;

  const int N = in_sizes[0] / 128;     // 100000
  const int E = in_sizes[1] / 2;       // 1600000
  const int* src = ei;
  const int* dst = ei + E;

  // workspace layout (512B aligned blocks)
  char* wsb = (char*)d_ws;
  size_t off = 0;
  auto alloc = [&](size_t bytes) -> void* {
    void* p = wsb + off;
    off += (bytes + 511) & ~(size_t)511;
    return p;
  };
  int* rs       = (int*)alloc((size_t)(N + 1) * 4);
  int* csr_src  = (int*)alloc((size_t)E * 4 + 64);
  int* bcnt     = (int*)alloc(NBUCK * 4);
  int* bbase    = (int*)alloc(NBUCK * 4);
  int* bcur     = (int*)alloc(NBUCK * 4);
  unsigned int* staging = (unsigned int*)alloc((size_t)E * 4);
  unsigned short* W1p = (unsigned short*)alloc(256 * 256 * 2);
  unsigned short* W2p = (unsigned short*)alloc(128 * 256 * 2);
  unsigned short* A1  = (unsigned short*)alloc((size_t)N * 256 * 2);
  unsigned int* xq    = (unsigned int*)alloc((size_t)N * 128);      // fp8 x, 128 B/row
  unsigned char* zq   = (unsigned char*)alloc((size_t)N * 64);      // fp8 z, 64 B/row
  unsigned short* rb  = (unsigned short*)alloc((size_t)N * 64 * 2); // bf16 r
  (void)ws_size; (void)n_in; (void)out_size;

  const int nbuckReal = (N + 1023) / 1024;             // 98
  const int nchunks = (E + BIN_CHUNK - 1) / BIN_CHUNK; // 196

  hipMemsetAsync(bcnt, 0, NBUCK * 4, stream);
  bhist<<<256, 256, 0, stream>>>(dst, bcnt, E);
  bscan<<<1, 128, 0, stream>>>(bcnt, bbase, bcur, rs, N, E);
  binscatter<<<nchunks, 256, 0, stream>>>(src, dst, bcur, staging, E);
  bucketfinal<<<nbuckReal, 256, 0, stream>>>(staging, bbase, bcnt, rs, csr_src, N);

  convw<<<(8192 + 4096 + 255) / 256, 256, 0, stream>>>(W1l, W1r, W2l, W2r, W1p, W2p);
  convx<<<(N * 32 + 255) / 256, 256, 0, stream>>>(x, A1, xq, N);

  agg1_kernel<<<(N + 3) / 4, 256, 0, stream>>>(csr_src, rs, (const uint2*)xq, A1, N);

  gemm_fused<<<(N + 63) / 64, 256, 0, stream>>>(A1, W1p, W2p, b1, zq, rb, N);

  agg2_final<<<(N + 3) / 4, 256, 0, stream>>>((const uint2*)zq, rb, csr_src, rs, b2, out, N);
}

// Round 9
// 300.396 us; speedup vs baseline: 2.3820x; 1.0694x over previous
//
#include <hip/hip_runtime.h>

// ---------- helpers ----------
typedef __attribute__((ext_vector_type(8))) short short8;   // 8 x bf16 fragment (4 VGPRs)
typedef __attribute__((ext_vector_type(4))) float floatx4;  // MFMA accumulator
typedef __attribute__((ext_vector_type(2))) float floatx2;

static __device__ __forceinline__ unsigned short f2bf(float f) {
  unsigned int u = __builtin_bit_cast(unsigned int, f);
  u += 0x7FFFu + ((u >> 16) & 1u);   // RNE (finite inputs only)
  return (unsigned short)(u >> 16);
}
static __device__ __forceinline__ float bf2f(unsigned short s) {
  unsigned int u = ((unsigned int)s) << 16;
  return __builtin_bit_cast(float, u);
}
// fp8 e4m3 (OCP on gfx950) via HW cvt — encode/decode both on-device, self-consistent
static __device__ __forceinline__ unsigned int pk4_fp8(float a, float b, float c, float d) {
  int lo = __builtin_amdgcn_cvt_pk_fp8_f32(a, b, 0, false);
  int hi = __builtin_amdgcn_cvt_pk_fp8_f32(c, d, 0, false);
  return (unsigned int)((lo & 0xffff) | ((hi & 0xffff) << 16));
}
static __device__ __forceinline__ floatx4 unpk4_fp8(unsigned int p) {
  floatx2 lo = __builtin_amdgcn_cvt_pk_f32_fp8((int)p, false);
  floatx2 hi = __builtin_amdgcn_cvt_pk_f32_fp8((int)p, true);
  floatx4 r = {lo.x, lo.y, hi.x, hi.y};
  return r;
}

#define NBUCK 128        // padded bucket count; real buckets = ceil(N/1024) = 98
#define BIN_CHUNK 8192   // edges per binscatter workgroup

// ---------- CSR build via two-level binning (avoids 16x write amplification) ----------

__global__ __launch_bounds__(256) void bhist(const int* __restrict__ dst,
                                             int* __restrict__ bcnt, int E) {
  __shared__ int h[NBUCK];
  for (int i = threadIdx.x; i < NBUCK; i += 256) h[i] = 0;
  __syncthreads();
  int stride = gridDim.x * 256;
  for (int i = blockIdx.x * 256 + threadIdx.x; i < E; i += stride)
    atomicAdd(&h[dst[i] >> 10], 1);
  __syncthreads();
  for (int i = threadIdx.x; i < NBUCK; i += 256)
    if (h[i]) atomicAdd(&bcnt[i], h[i]);
}

__global__ __launch_bounds__(128) void bscan(const int* __restrict__ bcnt,
                                             int* __restrict__ bbase,
                                             int* __restrict__ bcur,
                                             int* __restrict__ rs, int N, int E) {
  __shared__ int s[NBUCK];
  int t = threadIdx.x;
  int v = bcnt[t];
  s[t] = v;
  __syncthreads();
  for (int off = 1; off < NBUCK; off <<= 1) {
    int x = (t >= off) ? s[t - off] : 0;
    __syncthreads();
    s[t] += x;
    __syncthreads();
  }
  int excl = s[t] - v;
  bbase[t] = excl;
  bcur[t] = excl;
  if (t == 0) rs[N] = E;
}

__global__ __launch_bounds__(256) void binscatter(const int* __restrict__ src,
                                                  const int* __restrict__ dst,
                                                  int* __restrict__ bcur,
                                                  unsigned int* __restrict__ staging,
                                                  int E) {
  __shared__ int h[NBUCK];
  __shared__ int cur[NBUCK];
  for (int i = threadIdx.x; i < NBUCK; i += 256) h[i] = 0;
  __syncthreads();
  int base = blockIdx.x * BIN_CHUNK;
  int end = base + BIN_CHUNK; if (end > E) end = E;
  for (int i = base + threadIdx.x; i < end; i += 256)
    atomicAdd(&h[dst[i] >> 10], 1);
  __syncthreads();
  for (int i = threadIdx.x; i < NBUCK; i += 256)
    cur[i] = h[i] ? atomicAdd(&bcur[i], h[i]) : 0;
  __syncthreads();
  for (int i = base + threadIdx.x; i < end; i += 256) {
    int d = dst[i], s = src[i];
    int b = d >> 10;
    int pos = atomicAdd(&cur[b], 1);
    staging[pos] = ((unsigned int)(d & 1023) << 17) | (unsigned int)s;
  }
}

__global__ __launch_bounds__(256) void bucketfinal(const unsigned int* __restrict__ staging,
                                                   const int* __restrict__ bbase,
                                                   const int* __restrict__ bcnt,
                                                   int* __restrict__ rs,
                                                   int* __restrict__ csr_src, int N) {
  int b = blockIdx.x;
  int base = bbase[b], cnt = bcnt[b];
  __shared__ int h[1024];
  __shared__ int ps[256];
  __shared__ int cur[1024];
  int t = threadIdx.x;
  for (int i = t; i < 1024; i += 256) h[i] = 0;
  __syncthreads();
  for (int i = t; i < cnt; i += 256)
    atomicAdd(&h[staging[base + i] >> 17], 1);
  __syncthreads();
  int a0 = h[4 * t], a1 = h[4 * t + 1], a2 = h[4 * t + 2], a3 = h[4 * t + 3];
  int tsum = a0 + a1 + a2 + a3;
  ps[t] = tsum;
  __syncthreads();
  for (int off = 1; off < 256; off <<= 1) {
    int x = (t >= off) ? ps[t - off] : 0;
    __syncthreads();
    ps[t] += x;
    __syncthreads();
  }
  int run = base + ps[t] - tsum;
  int node0 = b << 10;
  int va[4] = {a0, a1, a2, a3};
#pragma unroll
  for (int j = 0; j < 4; j++) {
    int w = node0 + 4 * t + j;
    cur[4 * t + j] = run;
    if (w < N) rs[w] = run;
    run += va[j];
  }
  __syncthreads();
  for (int i = t; i < cnt; i += 256) {
    unsigned int v = staging[base + i];
    int pos = atomicAdd(&cur[v >> 17], 1);
    csr_src[pos] = (int)(v & 0x1FFFFu);
  }
}

// ---------- weight conversion: fragment-major packing ----------
// W1p granule index: ((wave*8 + kk)*4 + ni)*64 + lane  (short8 each)
// W2p granule index: ((wave*8 + kk)*2 + ni)*64 + lane
__global__ void convw(const float* __restrict__ W1l, const float* __restrict__ W1r,
                      const float* __restrict__ W2l, const float* __restrict__ W2r,
                      unsigned short* __restrict__ W1p, unsigned short* __restrict__ W2p) {
  int i = blockIdx.x * blockDim.x + threadIdx.x;
  if (i < 8192) {
    int lane = i & 63, ni = (i >> 6) & 3, kk = (i >> 8) & 7, w = i >> 11;
    int fm = lane & 15, fq = lane >> 4;
    int n = w * 64 + ni * 16 + fm;
    int k0 = kk * 32 + fq * 8;
    unsigned short r[8];
#pragma unroll
    for (int j = 0; j < 8; j++) {
      int k = k0 + j;
      float v = (k < 128) ? W1l[k * 256 + n] : W1r[(k - 128) * 256 + n];
      r[j] = f2bf(v);
    }
    *reinterpret_cast<uint4*>(W1p + (size_t)i * 8) = *reinterpret_cast<uint4*>(r);
  } else if (i < 8192 + 4096) {
    int j2 = i - 8192;
    int lane = j2 & 63, ni = (j2 >> 6) & 1, kk = (j2 >> 7) & 7, w = j2 >> 10;
    int fm = lane & 15, fq = lane >> 4;
    int n = w * 32 + ni * 16 + fm;
    int k0 = kk * 32 + fq * 8;
    unsigned short r[8];
#pragma unroll
    for (int j = 0; j < 8; j++) {
      int k = k0 + j;
      float v = (n < 64) ? W2l[k * 64 + n] : W2r[k * 64 + (n - 64)];
      r[j] = f2bf(v);
    }
    *reinterpret_cast<uint4*>(W2p + (size_t)j2 * 8) = *reinterpret_cast<uint4*>(r);
  }
}

// x (fp32, [N][128]) -> bf16 right half of A1 (self path) + fp8 xq (gather path)
__global__ void convx(const float* __restrict__ x, unsigned short* __restrict__ A1,
                      unsigned int* __restrict__ xq, int n_nodes) {
  int i = blockIdx.x * blockDim.x + threadIdx.x;
  if (i < n_nodes * 32) {
    int node = i >> 5, c4 = (i & 31) * 4;
    float4 v = *reinterpret_cast<const float4*>(x + (size_t)node * 128 + c4);
    unsigned short r[4] = { f2bf(v.x), f2bf(v.y), f2bf(v.z), f2bf(v.w) };
    *reinterpret_cast<uint2*>(A1 + (size_t)node * 256 + 128 + c4) =
        *reinterpret_cast<uint2*>(r);
    xq[node * 32 + (i & 31)] = pk4_fp8(v.x, v.y, v.z, v.w);
  }
}

// ---------- layer-1 aggregation: 16 lanes per node (4 nodes/wave), in-lane accumulate ----------
// lane = 8 fp8 channels (uint2); each group walks its own node's edges; no cross-lane reduce.
__global__ __launch_bounds__(256) void agg1_kernel(const int* __restrict__ csr_src,
                                                   const int* __restrict__ rs,
                                                   const uint2* __restrict__ xq,
                                                   unsigned short* __restrict__ A1,
                                                   int n_nodes) {
  int lane = threadIdx.x & 63;
  int wave = threadIdx.x >> 6;
  int grp = lane >> 4;           // node slot 0..3 within wave
  int ch2 = lane & 15;           // uint2 index (8 fp8 channels)
  int w = blockIdx.x * 16 + wave * 4 + grp;
  if (w >= n_nodes) return;
  int e0 = rs[w], e1 = rs[w + 1];
  floatx4 aA0 = {0,0,0,0}, aB0 = {0,0,0,0};
  floatx4 aA1 = {0,0,0,0}, aB1 = {0,0,0,0};
  int e = e0;
  for (; e + 1 < e1; e += 2) {
    uint2 p0 = xq[(csr_src[e] << 4) | ch2];
    uint2 p1 = xq[(csr_src[e + 1] << 4) | ch2];
    aA0 += unpk4_fp8(p0.x); aB0 += unpk4_fp8(p0.y);
    aA1 += unpk4_fp8(p1.x); aB1 += unpk4_fp8(p1.y);
  }
  if (e < e1) {
    uint2 p = xq[(csr_src[e] << 4) | ch2];
    aA0 += unpk4_fp8(p.x); aB0 += unpk4_fp8(p.y);
  }
  floatx4 aA = aA0 + aA1;
  floatx4 aB = aB0 + aB1;
  int d = e1 - e0; if (d < 1) d = 1;
  float sc = 1.0f / (float)d;
  unsigned short r[8] = { f2bf(aA.x * sc), f2bf(aA.y * sc), f2bf(aA.z * sc), f2bf(aA.w * sc),
                          f2bf(aB.x * sc), f2bf(aB.y * sc), f2bf(aB.z * sc), f2bf(aB.w * sc) };
  *reinterpret_cast<uint4*>(A1 + (size_t)w * 256 + ch2 * 8) =
      *reinterpret_cast<uint4*>(r);
}

// ---------- fused MLP (64-row tiles, 4 blocks/CU, fragment-major weights) ----------
#define LDSW 264   // padded row stride in shorts (528 B)
__global__ __launch_bounds__(256, 4) void gemm_fused(const unsigned short* __restrict__ A1,
                                                     const unsigned short* __restrict__ W1p,
                                                     const unsigned short* __restrict__ W2p,
                                                     const float* __restrict__ b1,
                                                     unsigned char* __restrict__ zq,
                                                     unsigned short* __restrict__ rb,
                                                     int M) {
  __shared__ unsigned short smem[64 * LDSW];   // 33792 B -> 4 blocks/CU
  const int tid = threadIdx.x;
  const int lane = tid & 63;
  const int wave = tid >> 6;
  const int m0 = blockIdx.x * 64;
  const int fm = lane & 15;
  const int fq = lane >> 4;
  const short8* __restrict__ W1v = reinterpret_cast<const short8*>(W1p);
  const short8* __restrict__ W2v = reinterpret_cast<const short8*>(W2p);

#pragma unroll
  for (int j = 0; j < 8; j++) {
    int c = j * 256 + tid;
    int row = c >> 5, ch = c & 31;
    int gr = m0 + row; if (gr >= M) gr = M - 1;
    int4 v = *reinterpret_cast<const int4*>(A1 + (size_t)gr * 256 + ch * 8);
    *reinterpret_cast<int4*>(&smem[row * LDSW + ch * 8]) = v;
  }

  float bb[4];
#pragma unroll
  for (int ni = 0; ni < 4; ni++) bb[ni] = b1[wave * 64 + ni * 16 + fm];

  __syncthreads();

  floatx4 acc1[4][4] = {};
#pragma unroll 2
  for (int kk = 0; kk < 8; kk++) {
    short8 af[4], bfr[4];
#pragma unroll
    for (int mi = 0; mi < 4; mi++)
      af[mi] = *reinterpret_cast<const short8*>(
          &smem[(mi * 16 + fm) * LDSW + kk * 32 + fq * 8]);
#pragma unroll
    for (int ni = 0; ni < 4; ni++)
      bfr[ni] = W1v[((wave * 8 + kk) * 4 + ni) * 64 + lane];
#pragma unroll
    for (int mi = 0; mi < 4; mi++)
#pragma unroll
      for (int ni = 0; ni < 4; ni++)
        acc1[mi][ni] = __builtin_amdgcn_mfma_f32_16x16x32_bf16(af[mi], bfr[ni],
                                                               acc1[mi][ni], 0, 0, 0);
  }

  __syncthreads();

#pragma unroll
  for (int mi = 0; mi < 4; mi++)
#pragma unroll
    for (int ni = 0; ni < 4; ni++)
#pragma unroll
      for (int r = 0; r < 4; r++) {
        float v = acc1[mi][ni][r] + bb[ni];
        v = v > 0.f ? v : 0.f;
        smem[(mi * 16 + fq * 4 + r) * LDSW + wave * 64 + ni * 16 + fm] = f2bf(v);
      }
  __syncthreads();

  floatx4 acc2[4][2] = {};
#pragma unroll 2
  for (int kk = 0; kk < 8; kk++) {
    short8 hf[4], wf[2];
#pragma unroll
    for (int mi = 0; mi < 4; mi++)
      hf[mi] = *reinterpret_cast<const short8*>(
          &smem[(mi * 16 + fm) * LDSW + kk * 32 + fq * 8]);
#pragma unroll
    for (int ni = 0; ni < 2; ni++)
      wf[ni] = W2v[((wave * 8 + kk) * 2 + ni) * 64 + lane];
#pragma unroll
    for (int mi = 0; mi < 4; mi++)
#pragma unroll
      for (int ni = 0; ni < 2; ni++)
        acc2[mi][ni] = __builtin_amdgcn_mfma_f32_16x16x32_bf16(hf[mi], wf[ni],
                                                               acc2[mi][ni], 0, 0, 0);
  }

#pragma unroll
  for (int mi = 0; mi < 4; mi++)
#pragma unroll
    for (int ni = 0; ni < 2; ni++)
#pragma unroll
      for (int r = 0; r < 4; r++) {
        int grow = m0 + mi * 16 + fq * 4 + r;
        if (grow < M) {
          float v = acc2[mi][ni][r];
          int col = (wave & 1) * 32 + ni * 16 + fm;
          if (wave < 2) {
            int b8 = __builtin_amdgcn_cvt_pk_fp8_f32(v, v, 0, false);
            zq[grow * 64 + col] = (unsigned char)(b8 & 0xff);
          } else {
            rb[grow * 64 + col] = f2bf(v);
          }
        }
      }
}

// ---------- layer-2 aggregation + epilogue: 16 lanes per node, in-lane accumulate ----------
// lane = 4 fp8 channels (uint); no cross-lane reduce; lane writes float4 of out.
__global__ __launch_bounds__(256) void agg2_final(const unsigned int* __restrict__ zq,
                                                  const unsigned short* __restrict__ rb,
                                                  const int* __restrict__ csr_src,
                                                  const int* __restrict__ rs,
                                                  const float* __restrict__ b2,
                                                  float* __restrict__ out, int n_nodes) {
  int lane = threadIdx.x & 63;
  int wave = threadIdx.x >> 6;
  int grp = lane >> 4;           // node slot 0..3
  int ch = lane & 15;            // uint index (4 fp8 channels of 64)
  int w = blockIdx.x * 16 + wave * 4 + grp;
  if (w >= n_nodes) return;
  int e0 = rs[w], e1 = rs[w + 1];
  floatx4 a0 = {0,0,0,0}, a1 = {0,0,0,0};
  int e = e0;
  for (; e + 1 < e1; e += 2) {
    unsigned int p0 = zq[(csr_src[e] << 4) | ch];
    unsigned int p1 = zq[(csr_src[e + 1] << 4) | ch];
    a0 += unpk4_fp8(p0);
    a1 += unpk4_fp8(p1);
  }
  if (e < e1) a0 += unpk4_fp8(zq[(csr_src[e] << 4) | ch]);
  floatx4 acc = a0 + a1;
  int d = e1 - e0; if (d < 1) d = 1;
  float sc = 1.0f / (float)d;
  uint2 rr = *reinterpret_cast<const uint2*>(rb + w * 64 + ch * 4);
  float4 bv = *reinterpret_cast<const float4*>(b2 + ch * 4);
  float r0 = bf2f((unsigned short)(rr.x & 0xffff));
  float r1 = bf2f((unsigned short)(rr.x >> 16));
  float r2 = bf2f((unsigned short)(rr.y & 0xffff));
  float r3 = bf2f((unsigned short)(rr.y >> 16));
  float4 o;
  o.x = 1.0f / (1.0f + __expf(-(acc.x * sc + r0 + bv.x)));
  o.y = 1.0f / (1.0f + __expf(-(acc.y * sc + r1 + bv.y)));
  o.z = 1.0f / (1.0f + __expf(-(acc.z * sc + r2 + bv.z)));
  o.w = 1.0f / (1.0f + __expf(-(acc.w * sc + r3 + bv.w)));
  *reinterpret_cast<float4*>(out + (size_t)w * 64 + ch * 4) = o;
}

// ---------- launch ----------
extern "C" void kernel_launch(void* const* d_in, const int* in_sizes, int n_in,
                              void* d_out, int out_size, void* d_ws, size_t ws_size,
                              hipStream_t stream) {
  const float* x   = (const float*)d_in[0];
  const int*   ei  = (const int*)d_in[1];
  const float* W1l = (const float*)d_in[2];
  const float* W1r = (const float*)d_in[3];
  const float* b1  = (const float*)d_in[4];
  const float* W2l = (const float*)d_in[5];
  const float* W2r = (const float*)d_in[6];
  const float* b2  = (const float*)d_in[7];
  float* out = (float*)d_out;

  const int N = in_sizes[0] / 128;     // 100000
  const int E = in_sizes[1] / 2;       // 1600000
  const int* src = ei;
  const int* dst = ei + E;

  // workspace layout (512B aligned blocks)
  char* wsb = (char*)d_ws;
  size_t off = 0;
  auto alloc = [&](size_t bytes) -> void* {
    void* p = wsb + off;
    off += (bytes + 511) & ~(size_t)511;
    return p;
  };
  int* rs       = (int*)alloc((size_t)(N + 1) * 4);
  int* csr_src  = (int*)alloc((size_t)E * 4 + 64);
  int* bcnt     = (int*)alloc(NBUCK * 4);
  int* bbase    = (int*)alloc(NBUCK * 4);
  int* bcur     = (int*)alloc(NBUCK * 4);
  unsigned int* staging = (unsigned int*)alloc((size_t)E * 4);
  unsigned short* W1p = (unsigned short*)alloc(256 * 256 * 2);
  unsigned short* W2p = (unsigned short*)alloc(128 * 256 * 2);
  unsigned short* A1  = (unsigned short*)alloc((size_t)N * 256 * 2);
  unsigned int* xq    = (unsigned int*)alloc((size_t)N * 128);      // fp8 x, 128 B/row
  unsigned char* zq   = (unsigned char*)alloc((size_t)N * 64);      // fp8 z, 64 B/row
  unsigned short* rb  = (unsigned short*)alloc((size_t)N * 64 * 2); // bf16 r
  (void)ws_size; (void)n_in; (void)out_size;

  const int nbuckReal = (N + 1023) / 1024;             // 98
  const int nchunks = (E + BIN_CHUNK - 1) / BIN_CHUNK; // 196

  hipMemsetAsync(bcnt, 0, NBUCK * 4, stream);
  bhist<<<256, 256, 0, stream>>>(dst, bcnt, E);
  bscan<<<1, 128, 0, stream>>>(bcnt, bbase, bcur, rs, N, E);
  binscatter<<<nchunks, 256, 0, stream>>>(src, dst, bcur, staging, E);
  bucketfinal<<<nbuckReal, 256, 0, stream>>>(staging, bbase, bcnt, rs, csr_src, N);

  convw<<<(8192 + 4096 + 255) / 256, 256, 0, stream>>>(W1l, W1r, W2l, W2r, W1p, W2p);
  convx<<<(N * 32 + 255) / 256, 256, 0, stream>>>(x, A1, xq, N);

  agg1_kernel<<<(N + 15) / 16, 256, 0, stream>>>(csr_src, rs, (const uint2*)xq, A1, N);

  gemm_fused<<<(N + 63) / 64, 256, 0, stream>>>(A1, W1p, W2p, b1, zq, rb, N);

  agg2_final<<<(N + 15) / 16, 256, 0, stream>>>((const unsigned int*)zq, rb, csr_src, rs, b2, out, N);
}

// Round 10
// 261.593 us; speedup vs baseline: 2.7354x; 1.1483x over previous
//
#include <hip/hip_runtime.h>

// ---------- helpers ----------
typedef __attribute__((ext_vector_type(8))) short short8;   // 8 x bf16 fragment (4 VGPRs)
typedef __attribute__((ext_vector_type(4))) float floatx4;  // MFMA accumulator
typedef __attribute__((ext_vector_type(2))) float floatx2;

static __device__ __forceinline__ unsigned short f2bf(float f) {
  unsigned int u = __builtin_bit_cast(unsigned int, f);
  u += 0x7FFFu + ((u >> 16) & 1u);   // RNE (finite inputs only)
  return (unsigned short)(u >> 16);
}
static __device__ __forceinline__ float bf2f(unsigned short s) {
  unsigned int u = ((unsigned int)s) << 16;
  return __builtin_bit_cast(float, u);
}
// fp8 e4m3 (OCP on gfx950) via HW cvt — encode/decode both on-device, self-consistent
static __device__ __forceinline__ unsigned int pk4_fp8(float a, float b, float c, float d) {
  int lo = __builtin_amdgcn_cvt_pk_fp8_f32(a, b, 0, false);
  int hi = __builtin_amdgcn_cvt_pk_fp8_f32(c, d, 0, false);
  return (unsigned int)((lo & 0xffff) | ((hi & 0xffff) << 16));
}
static __device__ __forceinline__ floatx4 unpk4_fp8(unsigned int p) {
  floatx2 lo = __builtin_amdgcn_cvt_pk_f32_fp8((int)p, false);
  floatx2 hi = __builtin_amdgcn_cvt_pk_f32_fp8((int)p, true);
  floatx4 r = {lo.x, lo.y, hi.x, hi.y};
  return r;
}

#define NBUCK 512        // padded bucket count; real buckets = ceil(N/256) = 391
#define BIN_CHUNK 8192   // edges per binscatter workgroup

// ---------- CSR build via two-level binning (256-node buckets) ----------

__global__ __launch_bounds__(256) void bhist(const int* __restrict__ dst,
                                             int* __restrict__ bcnt, int E) {
  __shared__ int h[NBUCK];
  for (int i = threadIdx.x; i < NBUCK; i += 256) h[i] = 0;
  __syncthreads();
  int stride = gridDim.x * 256;
  for (int i = blockIdx.x * 256 + threadIdx.x; i < E; i += stride)
    atomicAdd(&h[dst[i] >> 8], 1);
  __syncthreads();
  for (int i = threadIdx.x; i < NBUCK; i += 256)
    if (h[i]) atomicAdd(&bcnt[i], h[i]);
}

// single-WG scan of 512 bucket counts (2 per thread) -> bases + cursors; rs[N] = E
__global__ __launch_bounds__(256) void bscan(const int* __restrict__ bcnt,
                                             int* __restrict__ bbase,
                                             int* __restrict__ bcur,
                                             int* __restrict__ rs, int N, int E) {
  __shared__ int ps[256];
  int t = threadIdx.x;
  int v0 = bcnt[2 * t], v1 = bcnt[2 * t + 1];
  int tsum = v0 + v1;
  ps[t] = tsum;
  __syncthreads();
  for (int off = 1; off < 256; off <<= 1) {
    int x = (t >= off) ? ps[t - off] : 0;
    __syncthreads();
    ps[t] += x;
    __syncthreads();
  }
  int excl = ps[t] - tsum;
  bbase[2 * t] = excl;     bcur[2 * t] = excl;
  bbase[2 * t + 1] = excl + v0; bcur[2 * t + 1] = excl + v0;
  if (t == 0) rs[N] = E;
}

// bin edges into bucket-grouped staging; packed word = (dst&255)<<17 | src
__global__ __launch_bounds__(256) void binscatter(const int* __restrict__ src,
                                                  const int* __restrict__ dst,
                                                  int* __restrict__ bcur,
                                                  unsigned int* __restrict__ staging,
                                                  int E) {
  __shared__ int h[NBUCK];
  __shared__ int cur[NBUCK];
  for (int i = threadIdx.x; i < NBUCK; i += 256) h[i] = 0;
  __syncthreads();
  int base = blockIdx.x * BIN_CHUNK;
  int end = base + BIN_CHUNK; if (end > E) end = E;
  for (int i = base + threadIdx.x; i < end; i += 256)
    atomicAdd(&h[dst[i] >> 8], 1);
  __syncthreads();
  for (int i = threadIdx.x; i < NBUCK; i += 256)
    cur[i] = h[i] ? atomicAdd(&bcur[i], h[i]) : 0;
  __syncthreads();
  for (int i = base + threadIdx.x; i < end; i += 256) {
    int d = dst[i], s = src[i];
    int b = d >> 8;
    int pos = atomicAdd(&cur[b], 1);
    staging[pos] = ((unsigned int)(d & 255) << 17) | (unsigned int)s;
  }
}

// one WG per 256-node bucket: node histogram + scan (writes rs) + scatter into csr.
__global__ __launch_bounds__(256) void bucketfinal(const unsigned int* __restrict__ staging,
                                                   const int* __restrict__ bbase,
                                                   const int* __restrict__ bcnt,
                                                   int* __restrict__ rs,
                                                   int* __restrict__ csr_src, int N) {
  int b = blockIdx.x;
  int base = bbase[b], cnt = bcnt[b];
  __shared__ int h[256];
  __shared__ int ps[256];
  __shared__ int cur[256];
  int t = threadIdx.x;
  h[t] = 0;
  __syncthreads();
  for (int i = t; i < cnt; i += 256)
    atomicAdd(&h[staging[base + i] >> 17], 1);
  __syncthreads();
  int hv = h[t];
  ps[t] = hv;
  __syncthreads();
  for (int off = 1; off < 256; off <<= 1) {
    int x = (t >= off) ? ps[t - off] : 0;
    __syncthreads();
    ps[t] += x;
    __syncthreads();
  }
  int run = base + ps[t] - hv;
  int w = (b << 8) + t;
  cur[t] = run;
  if (w < N) rs[w] = run;
  __syncthreads();
  for (int i = t; i < cnt; i += 256) {
    unsigned int v = staging[base + i];
    int pos = atomicAdd(&cur[v >> 17], 1);
    csr_src[pos] = (int)(v & 0x1FFFFu);
  }
}

// ---------- weight conversion: fragment-major packing ----------
// W1p granule index: ((wave*8 + kk)*4 + ni)*64 + lane  (short8 each)
// W2p granule index: ((wave*8 + kk)*2 + ni)*64 + lane
__global__ void convw(const float* __restrict__ W1l, const float* __restrict__ W1r,
                      const float* __restrict__ W2l, const float* __restrict__ W2r,
                      unsigned short* __restrict__ W1p, unsigned short* __restrict__ W2p) {
  int i = blockIdx.x * blockDim.x + threadIdx.x;
  if (i < 8192) {
    int lane = i & 63, ni = (i >> 6) & 3, kk = (i >> 8) & 7, w = i >> 11;
    int fm = lane & 15, fq = lane >> 4;
    int n = w * 64 + ni * 16 + fm;
    int k0 = kk * 32 + fq * 8;
    unsigned short r[8];
#pragma unroll
    for (int j = 0; j < 8; j++) {
      int k = k0 + j;
      float v = (k < 128) ? W1l[k * 256 + n] : W1r[(k - 128) * 256 + n];
      r[j] = f2bf(v);
    }
    *reinterpret_cast<uint4*>(W1p + (size_t)i * 8) = *reinterpret_cast<uint4*>(r);
  } else if (i < 8192 + 4096) {
    int j2 = i - 8192;
    int lane = j2 & 63, ni = (j2 >> 6) & 1, kk = (j2 >> 7) & 7, w = j2 >> 10;
    int fm = lane & 15, fq = lane >> 4;
    int n = w * 32 + ni * 16 + fm;
    int k0 = kk * 32 + fq * 8;
    unsigned short r[8];
#pragma unroll
    for (int j = 0; j < 8; j++) {
      int k = k0 + j;
      float v = (n < 64) ? W2l[k * 64 + n] : W2r[k * 64 + (n - 64)];
      r[j] = f2bf(v);
    }
    *reinterpret_cast<uint4*>(W2p + (size_t)j2 * 8) = *reinterpret_cast<uint4*>(r);
  }
}

// x (fp32, [N][128]) -> bf16 right half of A1 (self path) + fp8 xq (gather path)
__global__ void convx(const float* __restrict__ x, unsigned short* __restrict__ A1,
                      unsigned int* __restrict__ xq, int n_nodes) {
  int i = blockIdx.x * blockDim.x + threadIdx.x;
  if (i < n_nodes * 32) {
    int node = i >> 5, c4 = (i & 31) * 4;
    float4 v = *reinterpret_cast<const float4*>(x + (size_t)node * 128 + c4);
    unsigned short r[4] = { f2bf(v.x), f2bf(v.y), f2bf(v.z), f2bf(v.w) };
    *reinterpret_cast<uint2*>(A1 + (size_t)node * 256 + 128 + c4) =
        *reinterpret_cast<uint2*>(r);
    xq[node * 32 + (i & 31)] = pk4_fp8(v.x, v.y, v.z, v.w);
  }
}

// ---------- layer-1 aggregation: 8 lanes/node (8 nodes/wave), uint4 loads, in-lane acc ----------
__global__ __launch_bounds__(256) void agg1_kernel(const int* __restrict__ csr_src,
                                                   const int* __restrict__ rs,
                                                   const uint4* __restrict__ xq,
                                                   unsigned short* __restrict__ A1,
                                                   int n_nodes) {
  int lane = threadIdx.x & 63;
  int wave = threadIdx.x >> 6;
  int grp = lane >> 3;           // node slot 0..7
  int ch4 = lane & 7;            // uint4 index (16 fp8 channels)
  int w = blockIdx.x * 32 + wave * 8 + grp;
  if (w >= n_nodes) return;
  int e0 = rs[w], e1 = rs[w + 1];
  floatx4 a0[4] = {{0,0,0,0},{0,0,0,0},{0,0,0,0},{0,0,0,0}};
  floatx4 a1[4] = {{0,0,0,0},{0,0,0,0},{0,0,0,0},{0,0,0,0}};
  int e = e0;
  for (; e + 1 < e1; e += 2) {
    uint4 p0 = xq[(csr_src[e] << 3) | ch4];
    uint4 p1 = xq[(csr_src[e + 1] << 3) | ch4];
    a0[0] += unpk4_fp8(p0.x); a0[1] += unpk4_fp8(p0.y);
    a0[2] += unpk4_fp8(p0.z); a0[3] += unpk4_fp8(p0.w);
    a1[0] += unpk4_fp8(p1.x); a1[1] += unpk4_fp8(p1.y);
    a1[2] += unpk4_fp8(p1.z); a1[3] += unpk4_fp8(p1.w);
  }
  if (e < e1) {
    uint4 p = xq[(csr_src[e] << 3) | ch4];
    a0[0] += unpk4_fp8(p.x); a0[1] += unpk4_fp8(p.y);
    a0[2] += unpk4_fp8(p.z); a0[3] += unpk4_fp8(p.w);
  }
  int d = e1 - e0; if (d < 1) d = 1;
  float sc = 1.0f / (float)d;
  unsigned short r[16];
#pragma unroll
  for (int j = 0; j < 4; j++) {
    floatx4 a = a0[j] + a1[j];
    r[4 * j + 0] = f2bf(a.x * sc); r[4 * j + 1] = f2bf(a.y * sc);
    r[4 * j + 2] = f2bf(a.z * sc); r[4 * j + 3] = f2bf(a.w * sc);
  }
  unsigned short* dst = A1 + (size_t)w * 256 + ch4 * 16;
  *reinterpret_cast<uint4*>(dst) = *reinterpret_cast<uint4*>(r);
  *reinterpret_cast<uint4*>(dst + 8) = *reinterpret_cast<uint4*>(r + 8);
}

// ---------- fused MLP (64-row tiles, 4 blocks/CU, fragment-major weights) ----------
#define LDSW 264   // padded row stride in shorts (528 B)
__global__ __launch_bounds__(256, 4) void gemm_fused(const unsigned short* __restrict__ A1,
                                                     const unsigned short* __restrict__ W1p,
                                                     const unsigned short* __restrict__ W2p,
                                                     const float* __restrict__ b1,
                                                     unsigned char* __restrict__ zq,
                                                     unsigned short* __restrict__ rb,
                                                     int M) {
  __shared__ unsigned short smem[64 * LDSW];   // 33792 B -> 4 blocks/CU
  const int tid = threadIdx.x;
  const int lane = tid & 63;
  const int wave = tid >> 6;
  const int m0 = blockIdx.x * 64;
  const int fm = lane & 15;
  const int fq = lane >> 4;
  const short8* __restrict__ W1v = reinterpret_cast<const short8*>(W1p);
  const short8* __restrict__ W2v = reinterpret_cast<const short8*>(W2p);

#pragma unroll
  for (int j = 0; j < 8; j++) {
    int c = j * 256 + tid;
    int row = c >> 5, ch = c & 31;
    int gr = m0 + row; if (gr >= M) gr = M - 1;
    int4 v = *reinterpret_cast<const int4*>(A1 + (size_t)gr * 256 + ch * 8);
    *reinterpret_cast<int4*>(&smem[row * LDSW + ch * 8]) = v;
  }

  float bb[4];
#pragma unroll
  for (int ni = 0; ni < 4; ni++) bb[ni] = b1[wave * 64 + ni * 16 + fm];

  __syncthreads();

  floatx4 acc1[4][4] = {};
#pragma unroll 2
  for (int kk = 0; kk < 8; kk++) {
    short8 af[4], bfr[4];
#pragma unroll
    for (int mi = 0; mi < 4; mi++)
      af[mi] = *reinterpret_cast<const short8*>(
          &smem[(mi * 16 + fm) * LDSW + kk * 32 + fq * 8]);
#pragma unroll
    for (int ni = 0; ni < 4; ni++)
      bfr[ni] = W1v[((wave * 8 + kk) * 4 + ni) * 64 + lane];
#pragma unroll
    for (int mi = 0; mi < 4; mi++)
#pragma unroll
      for (int ni = 0; ni < 4; ni++)
        acc1[mi][ni] = __builtin_amdgcn_mfma_f32_16x16x32_bf16(af[mi], bfr[ni],
                                                               acc1[mi][ni], 0, 0, 0);
  }

  __syncthreads();

#pragma unroll
  for (int mi = 0; mi < 4; mi++)
#pragma unroll
    for (int ni = 0; ni < 4; ni++)
#pragma unroll
      for (int r = 0; r < 4; r++) {
        float v = acc1[mi][ni][r] + bb[ni];
        v = v > 0.f ? v : 0.f;
        smem[(mi * 16 + fq * 4 + r) * LDSW + wave * 64 + ni * 16 + fm] = f2bf(v);
      }
  __syncthreads();

  floatx4 acc2[4][2] = {};
#pragma unroll 2
  for (int kk = 0; kk < 8; kk++) {
    short8 hf[4], wf[2];
#pragma unroll
    for (int mi = 0; mi < 4; mi++)
      hf[mi] = *reinterpret_cast<const short8*>(
          &smem[(mi * 16 + fm) * LDSW + kk * 32 + fq * 8]);
#pragma unroll
    for (int ni = 0; ni < 2; ni++)
      wf[ni] = W2v[((wave * 8 + kk) * 2 + ni) * 64 + lane];
#pragma unroll
    for (int mi = 0; mi < 4; mi++)
#pragma unroll
      for (int ni = 0; ni < 2; ni++)
        acc2[mi][ni] = __builtin_amdgcn_mfma_f32_16x16x32_bf16(hf[mi], wf[ni],
                                                               acc2[mi][ni], 0, 0, 0);
  }

#pragma unroll
  for (int mi = 0; mi < 4; mi++)
#pragma unroll
    for (int ni = 0; ni < 2; ni++)
#pragma unroll
      for (int r = 0; r < 4; r++) {
        int grow = m0 + mi * 16 + fq * 4 + r;
        if (grow < M) {
          float v = acc2[mi][ni][r];
          int col = (wave & 1) * 32 + ni * 16 + fm;
          if (wave < 2) {
            int b8 = __builtin_amdgcn_cvt_pk_fp8_f32(v, v, 0, false);
            zq[grow * 64 + col] = (unsigned char)(b8 & 0xff);
          } else {
            rb[grow * 64 + col] = f2bf(v);
          }
        }
      }
}

// ---------- layer-2 aggregation + epilogue: 4 lanes/node (16 nodes/wave), uint4 loads ----------
__global__ __launch_bounds__(256) void agg2_final(const uint4* __restrict__ zq,
                                                  const unsigned short* __restrict__ rb,
                                                  const int* __restrict__ csr_src,
                                                  const int* __restrict__ rs,
                                                  const float* __restrict__ b2,
                                                  float* __restrict__ out, int n_nodes) {
  int lane = threadIdx.x & 63;
  int wave = threadIdx.x >> 6;
  int grp = lane >> 2;           // node slot 0..15
  int ch = lane & 3;             // uint4 index (16 fp8 channels of 64)
  int w = blockIdx.x * 64 + wave * 16 + grp;
  if (w >= n_nodes) return;
  int e0 = rs[w], e1 = rs[w + 1];
  floatx4 a0[4] = {{0,0,0,0},{0,0,0,0},{0,0,0,0},{0,0,0,0}};
  floatx4 a1[4] = {{0,0,0,0},{0,0,0,0},{0,0,0,0},{0,0,0,0}};
  int e = e0;
  for (; e + 1 < e1; e += 2) {
    uint4 p0 = zq[(csr_src[e] << 2) | ch];
    uint4 p1 = zq[(csr_src[e + 1] << 2) | ch];
    a0[0] += unpk4_fp8(p0.x); a0[1] += unpk4_fp8(p0.y);
    a0[2] += unpk4_fp8(p0.z); a0[3] += unpk4_fp8(p0.w);
    a1[0] += unpk4_fp8(p1.x); a1[1] += unpk4_fp8(p1.y);
    a1[2] += unpk4_fp8(p1.z); a1[3] += unpk4_fp8(p1.w);
  }
  if (e < e1) {
    uint4 p = zq[(csr_src[e] << 2) | ch];
    a0[0] += unpk4_fp8(p.x); a0[1] += unpk4_fp8(p.y);
    a0[2] += unpk4_fp8(p.z); a0[3] += unpk4_fp8(p.w);
  }
  int d = e1 - e0; if (d < 1) d = 1;
  float sc = 1.0f / (float)d;
  // 16 output channels: base = ch*16
  const unsigned short* rbp = rb + w * 64 + ch * 16;
  const float* b2p = b2 + ch * 16;
  float* op = out + (size_t)w * 64 + ch * 16;
#pragma unroll
  for (int j = 0; j < 4; j++) {
    floatx4 a = a0[j] + a1[j];
    uint2 rr = *reinterpret_cast<const uint2*>(rbp + 4 * j);
    float4 bv = *reinterpret_cast<const float4*>(b2p + 4 * j);
    float r0 = bf2f((unsigned short)(rr.x & 0xffff));
    float r1 = bf2f((unsigned short)(rr.x >> 16));
    float r2 = bf2f((unsigned short)(rr.y & 0xffff));
    float r3 = bf2f((unsigned short)(rr.y >> 16));
    float4 o;
    o.x = 1.0f / (1.0f + __expf(-(a.x * sc + r0 + bv.x)));
    o.y = 1.0f / (1.0f + __expf(-(a.y * sc + r1 + bv.y)));
    o.z = 1.0f / (1.0f + __expf(-(a.z * sc + r2 + bv.z)));
    o.w = 1.0f / (1.0f + __expf(-(a.w * sc + r3 + bv.w)));
    *reinterpret_cast<float4*>(op + 4 * j) = o;
  }
}

// ---------- launch ----------
extern "C" void kernel_launch(void* const* d_in, const int* in_sizes, int n_in,
                              void* d_out, int out_size, void* d_ws, size_t ws_size,
                              hipStream_t stream) {
  const float* x   = (const float*)d_in[0];
  const int*   ei  = (const int*)d_in[1];
  const float* W1l = (const float*)d_in[2];
  const float* W1r = (const float*)d_in[3];
  const float* b1  = (const float*)d_in[4];
  const float* W2l = (const float*)d_in[5];
  const float* W2r = (const float*)d_in[6];
  const float* b2  = (const float*)d_in[7];
  float* out = (float*)d_out;

  const int N = in_sizes[0] / 128;     // 100000
  const int E = in_sizes[1] / 2;       // 1600000
  const int* src = ei;
  const int* dst = ei + E;

  // workspace layout (512B aligned blocks)
  char* wsb = (char*)d_ws;
  size_t off = 0;
  auto alloc = [&](size_t bytes) -> void* {
    void* p = wsb + off;
    off += (bytes + 511) & ~(size_t)511;
    return p;
  };
  int* rs       = (int*)alloc((size_t)(N + 1) * 4);
  int* csr_src  = (int*)alloc((size_t)E * 4 + 64);
  int* bcnt     = (int*)alloc(NBUCK * 4);
  int* bbase    = (int*)alloc(NBUCK * 4);
  int* bcur     = (int*)alloc(NBUCK * 4);
  unsigned int* staging = (unsigned int*)alloc((size_t)E * 4);
  unsigned short* W1p = (unsigned short*)alloc(256 * 256 * 2);
  unsigned short* W2p = (unsigned short*)alloc(128 * 256 * 2);
  unsigned short* A1  = (unsigned short*)alloc((size_t)N * 256 * 2);
  unsigned int* xq    = (unsigned int*)alloc((size_t)N * 128);      // fp8 x, 128 B/row
  unsigned char* zq   = (unsigned char*)alloc((size_t)N * 64);      // fp8 z, 64 B/row
  unsigned short* rb  = (unsigned short*)alloc((size_t)N * 64 * 2); // bf16 r
  (void)ws_size; (void)n_in; (void)out_size;

  const int nbuckReal = (N + 255) / 256;               // 391
  const int nchunks = (E + BIN_CHUNK - 1) / BIN_CHUNK; // 196

  hipMemsetAsync(bcnt, 0, NBUCK * 4, stream);
  bhist<<<256, 256, 0, stream>>>(dst, bcnt, E);
  bscan<<<1, 256, 0, stream>>>(bcnt, bbase, bcur, rs, N, E);
  binscatter<<<nchunks, 256, 0, stream>>>(src, dst, bcur, staging, E);
  bucketfinal<<<nbuckReal, 256, 0, stream>>>(staging, bbase, bcnt, rs, csr_src, N);

  convw<<<(8192 + 4096 + 255) / 256, 256, 0, stream>>>(W1l, W1r, W2l, W2r, W1p, W2p);
  convx<<<(N * 32 + 255) / 256, 256, 0, stream>>>(x, A1, xq, N);

  agg1_kernel<<<(N + 31) / 32, 256, 0, stream>>>(csr_src, rs, (const uint4*)xq, A1, N);

  gemm_fused<<<(N + 63) / 64, 256, 0, stream>>>(A1, W1p, W2p, b1, zq, rb, N);

  agg2_final<<<(N + 63) / 64, 256, 0, stream>>>((const uint4*)zq, rb, csr_src, rs, b2, out, N);
}